// Round 6
// baseline (1820.036 us; speedup 1.0000x reference)
//
#include <hip/hip_runtime.h>

// ---------------------------------------------------------------------------
// Problem constants
// ---------------------------------------------------------------------------
#define NB    128
#define HD    100
#define NU    20000
#define NTG   10000
#define NTREE 30000
#define NG    30000
#define TT    20
#define EG    200000
#define ET    60000
#define VOC   50000

#define ESTR2 448   // interleaved Etab row stride in u16: [112 cols][4] (r,z,n,pad)
#define WROWS 336   // GRU weight rows: 3 gates x 112 (gate stride 112)
#define LOG2E  1.4426950408889634f
#define LOG2E2 2.8853900817779268f

typedef unsigned short u16;
typedef unsigned int   u32;
typedef __attribute__((ext_vector_type(8))) short short8;
typedef __attribute__((ext_vector_type(4))) float floatx4;

// gate pre-activations arrive PRE-SCALED by log2e (r,z) / 2log2e (n)
__device__ __forceinline__ float sigmoid2_(float y) {
    return __fdividef(1.f, 1.f + __builtin_amdgcn_exp2f(-y));
}
__device__ __forceinline__ float tanh2_(float y) {
    return 1.f - __fdividef(2.f, __builtin_amdgcn_exp2f(y) + 1.f);
}
__device__ __forceinline__ u16 f2bf(float f) {
    u32 u = __float_as_uint(f);
    u32 r = (u + 0x7fffu + ((u >> 16) & 1u)) >> 16;
    return (u16)r;
}
__device__ __forceinline__ u16 f2bf_c(float f) {
    u32 r;
    asm("v_cvt_pk_bf16_f32 %0, %1, %2" : "=v"(r) : "v"(f), "v"(f));
    return (u16)r;
}
__device__ __forceinline__ float bf2f(u16 h) {
    return __uint_as_float(((u32)h) << 16);
}

// ---------------------------------------------------------------------------
// Fused 2-layer GRU v11: 448 threads (7 waves) / 64 rows / TT steps.
// vs v10: 64 rows per block (rt = 0..3). Cycle accounting showed ~11K of the
// 13.8K cycles/region are FIXED (barrier drain + skew + gather latency paid
// by all lockstep waves); doubling work per region amortizes it and halves
// the serial block rounds (4.9 -> 2.4). LDS 69KB, ~250 VGPR peak (2 w/SIMD).
// ---------------------------------------------------------------------------
struct GruProb {
    const u16*   Etab;     // [VOC][112][4] interleaved, pre-scaled
    const int*   nodes;    // [M][TT]
    const float* h0;       // [2][M][100] fp32
    const u16*   Whh0;     // [336][128] gate-padded, scaled (col100 = bhh0)
    const u16*   Wih1;
    const u16*   Whh1;
    u16*         hout;     // [M][128]
    int          M;
};

__global__ __launch_bounds__(448, 2) void gru_fused11(GruProb Pg, GruProb Pt, int gblocks)
{
    const bool isg = (int)blockIdx.x < gblocks;
    const GruProb P = isg ? Pg : Pt;
    const int bx = isg ? blockIdx.x : blockIdx.x - gblocks;
    const int M  = P.M;
    const int m0 = bx * 64;

    __shared__ u16 H0[2][64 * 128];
    __shared__ u16 H1[2][64 * 128];
    __shared__ int NID[TT * 64];

    const int tid  = threadIdx.x;
    const int w    = tid >> 6, lane = tid & 63;
    const int fr   = lane & 15, quad = lane >> 4;
    const int c    = w * 16 + fr;
    const bool cok = (c < HD);

    short8 Bh0[3][4], Bx1[3][4], Bh1[3][4];
#pragma unroll
    for (int g = 0; g < 3; ++g) {
        const size_t rb = (size_t)((g * 7 + w) * 16 + fr) * 128 + quad * 8;
#pragma unroll
        for (int kk = 0; kk < 4; ++kk) {
            Bh0[g][kk] = *(const short8*)(P.Whh0 + rb + kk * 32);
            Bx1[g][kk] = *(const short8*)(P.Wih1 + rb + kk * 32);
            Bh1[g][kk] = *(const short8*)(P.Whh1 + rb + kk * 32);
        }
    }

    for (int i = tid; i < 64 * 128; i += 448) {
        H0[0][i] = 0; H0[1][i] = 0; H1[0][i] = 0; H1[1][i] = 0;
    }
    for (int i = tid; i < 64 * TT; i += 448) {
        int row = i / TT, t = i - row * TT;
        int gm = m0 + row;
        NID[t * 64 + row] = (gm < M) ? P.nodes[(size_t)gm * TT + t] : 0;
    }
    __syncthreads();
    if (tid < 64) {
        int off = 200 ^ ((tid & 7) << 4);
        *(u16*)((char*)&H0[0][0] + tid * 256 + off) = 0x3F80;
        *(u16*)((char*)&H0[1][0] + tid * 256 + off) = 0x3F80;
        *(u16*)((char*)&H1[0][0] + tid * 256 + off) = 0x3F80;
        *(u16*)((char*)&H1[1][0] + tid * 256 + off) = 0x3F80;
    }

    float h0f[4][4] = {};
    float h1f[4][4] = {};
    if (cok) {
#pragma unroll
        for (int rt = 0; rt < 4; ++rt)
#pragma unroll
        for (int r = 0; r < 4; ++r) {
            int row = rt * 16 + quad * 4 + r;
            int gm  = m0 + row;
            float v0 = 0.f, v1 = 0.f;
            if (gm < M) {
                v0 = P.h0[(size_t)gm * HD + c];
                v1 = P.h0[(size_t)(M + gm) * HD + c];
            }
            h0f[rt][r] = v0; h1f[rt][r] = v1;
            int off = (2 * c) ^ ((row & 7) << 4);
            *(u16*)((char*)&H0[0][0] + row * 256 + off) = f2bf_c(v0);
            *(u16*)((char*)&H1[0][0] + row * 256 + off) = f2bf_c(v1);
        }
    }

    // x-gate prefetch: one dwordx2 per (rt,r) -> (r,z) lo, (n,pad) hi
    u32 xlo[4][4], xhi[4][4];
    auto xpref = [&](int tn) {
        if (cok) {
#pragma unroll
            for (int rt = 0; rt < 4; ++rt)
#pragma unroll
            for (int r = 0; r < 4; ++r) {
                int row = rt * 16 + quad * 4 + r;
                int nd  = NID[tn * 64 + row];
                uint2 v = *(const uint2*)(P.Etab + (size_t)nd * ESTR2 + c * 4);
                xlo[rt][r] = v.x; xhi[rt][r] = v.y;
            }
        }
    };
    __syncthreads();
    xpref(0);

    // ---- prologue: A(0) ----
#pragma unroll
    for (int rt = 0; rt < 4; ++rt) {
        short8 a[4];
#pragma unroll
        for (int kk = 0; kk < 4; ++kk) {
            int row = rt * 16 + fr;
            int off = (kk * 64 + quad * 16) ^ ((row & 7) << 4);
            a[kk] = *(const short8*)((const char*)&H0[0][0] + row * 256 + off);
        }
        floatx4 ag[3];
#pragma unroll
        for (int g = 0; g < 3; ++g) ag[g] = (floatx4){0.f, 0.f, 0.f, 0.f};
#pragma unroll
        for (int g = 0; g < 3; ++g)
#pragma unroll
            for (int kk = 0; kk < 4; ++kk)
                ag[g] = __builtin_amdgcn_mfma_f32_16x16x32_bf16(a[kk], Bh0[g][kk], ag[g], 0, 0, 0);
        if (cok) {
#pragma unroll
            for (int r = 0; r < 4; ++r) {
                int row = rt * 16 + quad * 4 + r;
                float rr = sigmoid2_(bf2f((u16)xlo[rt][r]) + ag[0][r]);
                float zz = sigmoid2_(bf2f((u16)(xlo[rt][r] >> 16)) + ag[1][r]);
                float nn = tanh2_(bf2f((u16)xhi[rt][r]) + rr * ag[2][r]);
                float o  = nn + zz * (h0f[rt][r] - nn);
                h0f[rt][r] = o;
                *(u16*)((char*)&H0[1][0] + row * 256 + ((2 * c) ^ ((row & 7) << 4))) = f2bf_c(o);
            }
        }
    }
    __syncthreads();

    // ---- regions r = 0..TT-1: B(r) + A(r+1) ----
    for (int r = 0; r < TT; ++r) {
        const bool doA = (r + 1 < TT);
        if (doA) xpref(r + 1);

        const char* rd0 = (const char*)&H0[(r + 1) & 1][0];
        const char* rd1 = (const char*)&H1[r & 1][0];
        char*       wr0 = (char*)&H0[r & 1][0];
        char*       wr1 = (char*)&H1[(r + 1) & 1][0];

#pragma unroll
        for (int rt = 0; rt < 4; ++rt) {
            short8 a0[4], a1[4];
#pragma unroll
            for (int kk = 0; kk < 4; ++kk) {
                int row = rt * 16 + fr;
                int off = (kk * 64 + quad * 16) ^ ((row & 7) << 4);
                a0[kk] = *(const short8*)(rd0 + row * 256 + off);
                a1[kk] = *(const short8*)(rd1 + row * 256 + off);
            }
            floatx4 rz0 = {0.f,0.f,0.f,0.f}, rz1 = {0.f,0.f,0.f,0.f};
            floatx4 xnv = {0.f,0.f,0.f,0.f}, hnv = {0.f,0.f,0.f,0.f};
#pragma unroll
            for (int kk = 0; kk < 4; ++kk)
                rz0 = __builtin_amdgcn_mfma_f32_16x16x32_bf16(a0[kk], Bx1[0][kk], rz0, 0, 0, 0);
#pragma unroll
            for (int kk = 0; kk < 4; ++kk)
                rz0 = __builtin_amdgcn_mfma_f32_16x16x32_bf16(a1[kk], Bh1[0][kk], rz0, 0, 0, 0);
#pragma unroll
            for (int kk = 0; kk < 4; ++kk)
                rz1 = __builtin_amdgcn_mfma_f32_16x16x32_bf16(a0[kk], Bx1[1][kk], rz1, 0, 0, 0);
#pragma unroll
            for (int kk = 0; kk < 4; ++kk)
                rz1 = __builtin_amdgcn_mfma_f32_16x16x32_bf16(a1[kk], Bh1[1][kk], rz1, 0, 0, 0);
#pragma unroll
            for (int kk = 0; kk < 4; ++kk)
                xnv = __builtin_amdgcn_mfma_f32_16x16x32_bf16(a0[kk], Bx1[2][kk], xnv, 0, 0, 0);
#pragma unroll
            for (int kk = 0; kk < 4; ++kk)
                hnv = __builtin_amdgcn_mfma_f32_16x16x32_bf16(a1[kk], Bh1[2][kk], hnv, 0, 0, 0);
            floatx4 ag[3];
#pragma unroll
            for (int g = 0; g < 3; ++g) ag[g] = (floatx4){0.f, 0.f, 0.f, 0.f};
            if (doA) {
#pragma unroll
                for (int g = 0; g < 3; ++g)
#pragma unroll
                    for (int kk = 0; kk < 4; ++kk)
                        ag[g] = __builtin_amdgcn_mfma_f32_16x16x32_bf16(a0[kk], Bh0[g][kk], ag[g], 0, 0, 0);
            }
            if (cok) {
#pragma unroll
                for (int r4 = 0; r4 < 4; ++r4) {
                    int row = rt * 16 + quad * 4 + r4;
                    float rr = sigmoid2_(rz0[r4]);
                    float zz = sigmoid2_(rz1[r4]);
                    float nn = tanh2_(xnv[r4] + rr * hnv[r4]);
                    float o  = nn + zz * (h1f[rt][r4] - nn);
                    h1f[rt][r4] = o;
                    *(u16*)(wr1 + row * 256 + ((2 * c) ^ ((row & 7) << 4))) = f2bf_c(o);
                }
                if (doA) {
#pragma unroll
                    for (int r4 = 0; r4 < 4; ++r4) {
                        int row = rt * 16 + quad * 4 + r4;
                        float rr = sigmoid2_(bf2f((u16)xlo[rt][r4]) + ag[0][r4]);
                        float zz = sigmoid2_(bf2f((u16)(xlo[rt][r4] >> 16)) + ag[1][r4]);
                        float nn = tanh2_(bf2f((u16)xhi[rt][r4]) + rr * ag[2][r4]);
                        float o  = nn + zz * (h0f[rt][r4] - nn);
                        h0f[rt][r4] = o;
                        *(u16*)(wr0 + row * 256 + ((2 * c) ^ ((row & 7) << 4))) = f2bf_c(o);
                    }
                }
            }
        }
        __syncthreads();
    }

    for (int i = tid; i < 64 * 128; i += 448) {
        int row = i >> 7, cc = i & 127;
        int gm = m0 + row;
        if (gm < M) {
            int off = (2 * cc) ^ ((row & 7) << 4);
            P.hout[(size_t)gm * 128 + cc] = *(const u16*)((const char*)&H1[0][0] + row * 256 + off);
        }
    }
}

// ---------------------------------------------------------------------------
// bf16 MFMA GEMM (GAT feature GEMMs)
// ---------------------------------------------------------------------------
#define LDST 40
__global__ __launch_bounds__(256) void gemm_mfma(
    const u16* __restrict__ A, const u16* __restrict__ B,
    float* __restrict__ Cf, u16* __restrict__ Cb,
    int M, int N, int Kt, int lda, int ldw, int ldc)
{
    const int m0 = blockIdx.x * 64;
    if (m0 >= M) return;
    const int n0 = blockIdx.y * 64;

    __shared__ u16 Als[64 * LDST];
    __shared__ u16 Wls[64 * LDST];

    const int tid  = threadIdx.x;
    const int wave = tid >> 6, lane = tid & 63;
    const int row  = tid >> 2, part = (tid & 3) * 8;
    const int fr   = lane & 15, quad = lane >> 4;

    floatx4 acc[4];
#pragma unroll
    for (int t = 0; t < 4; ++t) acc[t] = (floatx4){0.f, 0.f, 0.f, 0.f};

    const int am = m0 + row;  const bool aok = am < M;
    const int wn = n0 + row;  const bool wok = wn < N;
    const uint4 z4 = {0u, 0u, 0u, 0u};

    for (int kk = 0; kk < Kt; ++kk) {
        uint4 av = aok ? *(const uint4*)(A + (size_t)am * lda + kk * 32 + part) : z4;
        uint4 wv = wok ? *(const uint4*)(B + (size_t)wn * ldw + kk * 32 + part) : z4;
        __syncthreads();
        *(uint4*)&Als[row * LDST + part] = av;
        *(uint4*)&Wls[row * LDST + part] = wv;
        __syncthreads();
        short8 af = *(const short8*)&Als[((wave << 4) + fr) * LDST + quad * 8];
#pragma unroll
        for (int t = 0; t < 4; ++t) {
            short8 bf = *(const short8*)&Wls[((t << 4) + fr) * LDST + quad * 8];
            acc[t] = __builtin_amdgcn_mfma_f32_16x16x32_bf16(af, bf, acc[t], 0, 0, 0);
        }
    }

    const int orow0 = m0 + (wave << 4) + quad * 4;
#pragma unroll
    for (int t = 0; t < 4; ++t) {
        int col = n0 + (t << 4) + fr;
        if (col >= N) continue;
#pragma unroll
        for (int r = 0; r < 4; ++r) {
            int mr = orow0 + r;
            if (mr >= M) continue;
            float v = acc[t][r];
            if (Cf) Cf[(size_t)mr * ldc + col] = v;
            if (Cb) Cb[(size_t)mr * ldc + col] = f2bf(v);
        }
    }
}

// Dual Etab build: z selects (W,C). W rows pre-ordered (r,z,n,pad)-interleaved.
__global__ __launch_bounds__(256) void gemm_etab(
    const u16* __restrict__ A, const u16* __restrict__ W0, const u16* __restrict__ W1,
    u16* __restrict__ C0, u16* __restrict__ C1)
{
    const int m0 = blockIdx.x * 64;
    const int n0 = blockIdx.y * 64;
    const u16* B = blockIdx.z ? W1 : W0;
    u16* Cb = blockIdx.z ? C1 : C0;
    const int N = 400;

    __shared__ u16 Als[64 * LDST];
    __shared__ u16 Wls[64 * LDST];

    const int tid  = threadIdx.x;
    const int wave = tid >> 6, lane = tid & 63;
    const int row  = tid >> 2, part = (tid & 3) * 8;
    const int fr   = lane & 15, quad = lane >> 4;

    floatx4 acc[4];
#pragma unroll
    for (int t = 0; t < 4; ++t) acc[t] = (floatx4){0.f, 0.f, 0.f, 0.f};

    const int am = m0 + row;
    const int wn = n0 + row;  const bool wok = wn < N;
    const uint4 z4 = {0u, 0u, 0u, 0u};

    for (int kk = 0; kk < 4; ++kk) {
        uint4 av = *(const uint4*)(A + (size_t)am * 128 + kk * 32 + part);
        uint4 wv = wok ? *(const uint4*)(B + (size_t)wn * 128 + kk * 32 + part) : z4;
        __syncthreads();
        *(uint4*)&Als[row * LDST + part] = av;
        *(uint4*)&Wls[row * LDST + part] = wv;
        __syncthreads();
        short8 af = *(const short8*)&Als[((wave << 4) + fr) * LDST + quad * 8];
#pragma unroll
        for (int t = 0; t < 4; ++t) {
            short8 bf = *(const short8*)&Wls[((t << 4) + fr) * LDST + quad * 8];
            acc[t] = __builtin_amdgcn_mfma_f32_16x16x32_bf16(af, bf, acc[t], 0, 0, 0);
        }
    }

    const int orow0 = m0 + (wave << 4) + quad * 4;
#pragma unroll
    for (int t = 0; t < 4; ++t) {
        int col = n0 + (t << 4) + fr;
        if (col >= N) continue;
#pragma unroll
        for (int r = 0; r < 4; ++r)
            Cb[(size_t)(orow0 + r) * ESTR2 + col] = f2bf(acc[t][r]);
    }
}

// ---------------------------------------------------------------------------
// fp32 tiled GEMM (user-embed MLP only)
// ---------------------------------------------------------------------------
__global__ __launch_bounds__(256) void gemm_nt(
    const float* __restrict__ A, const float* __restrict__ W,
    const float* __restrict__ bias, float* __restrict__ C,
    int M, int N, int K, int relu)
{
    const int m0 = blockIdx.x * 64;
    const int n0 = blockIdx.y * 64;
    __shared__ float As[20][68];
    __shared__ float Ws[20][68];
    const int tid = threadIdx.x;
    const int r0 = (tid >> 4) * 4;
    const int c0 = (tid & 15) * 4;
    int sr[5], sk[5];
#pragma unroll
    for (int it = 0; it < 5; ++it) {
        int idx = tid + it * 256;
        sr[it] = idx / 20; sk[it] = idx - sr[it] * 20;
    }
    float acc[4][4];
#pragma unroll
    for (int i = 0; i < 4; ++i)
#pragma unroll
        for (int j = 0; j < 4; ++j) acc[i][j] = 0.f;
    const int nch = (K + 19) / 20;
    for (int ch = 0; ch < nch; ++ch) {
        const int k0 = ch * 20;
#pragma unroll
        for (int it = 0; it < 5; ++it) {
            int m = m0 + sr[it], k = k0 + sk[it];
            float va = 0.f, vw = 0.f;
            if (k < K) {
                if (m < M) va = A[(size_t)m * K + k];
                int n = n0 + sr[it];
                if (n < N) vw = W[(size_t)n * K + k];
            }
            As[sk[it]][sr[it]] = va;
            Ws[sk[it]][sr[it]] = vw;
        }
        __syncthreads();
#pragma unroll
        for (int kkk = 0; kkk < 20; ++kkk) {
            float4 a = *(const float4*)&As[kkk][r0];
            float4 w = *(const float4*)&Ws[kkk][c0];
            float av[4] = {a.x, a.y, a.z, a.w};
            float wv[4] = {w.x, w.y, w.z, w.w};
#pragma unroll
            for (int i = 0; i < 4; ++i)
#pragma unroll
                for (int j = 0; j < 4; ++j)
                    acc[i][j] = fmaf(av[i], wv[j], acc[i][j]);
        }
        __syncthreads();
    }
#pragma unroll
    for (int i = 0; i < 4; ++i) {
        int m = m0 + r0 + i;
        if (m >= M) continue;
#pragma unroll
        for (int j = 0; j < 4; ++j) {
            int n = n0 + c0 + j;
            if (n >= N) continue;
            float v = acc[i][j] + (bias ? bias[n] : 0.f);
            if (relu) v = fmaxf(v, 0.f);
            C[(size_t)m * N + n] = v;
        }
    }
}

// fp32 [M][K] -> bf16 [Mp][ldk]; col K..ldk zero, except col 100 gets
// app[n] (if app) or 1.0 (if appone).
__global__ void convert_pad2(const float* __restrict__ src, u16* __restrict__ dst,
                             int M, int Mp, int K, int ldk,
                             const float* __restrict__ app, int appone)
{
    int t = blockIdx.x * blockDim.x + threadIdx.x;
    if (t >= Mp * ldk) return;
    int n = t / ldk, c = t - n * ldk;
    u16 o = 0;
    if (n < M) {
        if (c < K) o = f2bf(src[(size_t)n * K + c]);
        else if (c == 100) {
            if (app) o = f2bf(app[n]);
            else if (appone) o = 0x3F80;
        }
    }
    dst[t] = o;
}

// Batched GRU weight converts: 6 matrices -> gate-padded bf16 [336][128],
// pre-scaled by log2e (r,z) / 2log2e (n) for the exp2 combine path.
struct CvtgBatch {
    const float* src[6];
    const float* bias[6];
    u16*         dst[6];
};
#define CVTG_BLOCKS_PER_MAT 168   // 336*128/256
__global__ void convert_gru_w6(CvtgBatch B)
{
    int mat = blockIdx.x / CVTG_BLOCKS_PER_MAT;
    int t = (blockIdx.x - mat * CVTG_BLOCKS_PER_MAT) * blockDim.x + threadIdx.x;
    int rr = t >> 7, cc = t & 127;
    int g = rr / 112, r2 = rr - g * 112;
    u16 o = 0;
    if (r2 < 100) {
        float sc = (g == 2) ? LOG2E2 : LOG2E;
        int sr = g * 100 + r2;
        if (cc < 100) o = f2bf(B.src[mat][(size_t)sr * 100 + cc] * sc);
        else if (cc == 100) o = f2bf(B.bias[mat][sr] * sc);
    }
    B.dst[mat][t] = o;
}

// Wih0 -> [448][128] with row order (r,z,n,pad) per column, scaled; both
// branches in one launch.
__global__ void convert_ih0(const float* __restrict__ s0, const float* __restrict__ b0,
                            u16* __restrict__ d0,
                            const float* __restrict__ s1, const float* __restrict__ b1,
                            u16* __restrict__ d1)
{
    int t = blockIdx.x * blockDim.x + threadIdx.x;
    if (t >= 2 * 448 * 128) return;
    int which = t / (448 * 128);
    int tt = t - which * (448 * 128);
    const float* s = which ? s1 : s0;
    const float* b = which ? b1 : b0;
    u16* d = which ? d1 : d0;
    int j = tt >> 7, kc = tt & 127;
    int cc = j >> 2, g = j & 3;
    u16 o = 0;
    if (g < 3 && cc < 100) {
        float sc = (g == 2) ? LOG2E2 : LOG2E;
        int sr = g * 100 + cc;
        if (kc < 100) o = f2bf(s[(size_t)sr * 100 + kc] * sc);
        else if (kc == 100) o = f2bf(b[sr] * sc);
    }
    d[tt] = o;
}

// xg (bf16 [NG][128]) = concat(hg[:128], ue, hg[128:])
__global__ void build_xg_bf(const u16* __restrict__ hgb, const float* __restrict__ ue,
                            u16* __restrict__ xgb)
{
    int t = blockIdx.x * blockDim.x + threadIdx.x;
    if (t >= NG * 128) return;
    int n = t >> 7, c = t & 127;
    u16 o = 0;
    if (n < NB)           o = hgb[n * 128 + c];
    else if (n < NB + NU) { if (c < HD) o = f2bf(ue[(size_t)(n - NB) * HD + c]); }
    else                  o = hgb[(size_t)(n - NU) * 128 + c];
    xgb[t] = o;
}

__global__ void set_roots(const float* __restrict__ src, u16* __restrict__ hb)
{
    int t = blockIdx.x * blockDim.x + threadIdx.x;
    if (t >= NB * HD) return;
    int n = t / HD, c = t - n * HD;
    hb[(size_t)n * 128 + c] = f2bf(src[t]);
}

// ---------------------------------------------------------------------------
// CSR build — both graphs fused per phase
// ---------------------------------------------------------------------------
__global__ void csr_count2(const int* __restrict__ gei, const int* __restrict__ tei,
                           int* __restrict__ gcnt, int* __restrict__ tcnt)
{
    int e = blockIdx.x * blockDim.x + threadIdx.x;
    const int GE = EG + NG;
    if (e < GE) {
        int dst = (e < EG) ? gei[EG + e] : e - EG;
        atomicAdd(&gcnt[dst], 1);
    } else {
        int e2 = e - GE;
        if (e2 >= ET + NTREE) return;
        int dst = (e2 < ET) ? tei[ET + e2] : e2 - ET;
        atomicAdd(&tcnt[dst], 1);
    }
}

__global__ void csr_scan2(int* __restrict__ gcnt, int* __restrict__ goff, int* __restrict__ gcur,
                          int* __restrict__ tcnt, int* __restrict__ toff, int* __restrict__ tcur)
{
    const int* cnt = blockIdx.x ? tcnt : gcnt;
    int* off = blockIdx.x ? toff : goff;
    int* cur = blockIdx.x ? tcur : gcur;
    const int N = blockIdx.x ? NTREE : NG;
    __shared__ int part[256];
    const int tid = threadIdx.x;
    const int per = (N + 255) / 256;
    const int i0 = tid * per;
    const int i1 = min(i0 + per, N);
    int s = 0;
    for (int i = i0; i < i1; ++i) s += cnt[i];
    part[tid] = s;
    __syncthreads();
    for (int o = 1; o < 256; o <<= 1) {
        int u = (tid >= o) ? part[tid - o] : 0;
        __syncthreads();
        part[tid] += u;
        __syncthreads();
    }
    int base = part[tid] - s;
    for (int i = i0; i < i1; ++i) {
        off[i] = base; cur[i] = base;
        base += cnt[i];
    }
    if (tid == 255) off[N] = part[255];
}

__global__ void csr_scatter2(const int* __restrict__ gei, const int* __restrict__ tei,
                             int* __restrict__ gcur, int* __restrict__ tcur,
                             int* __restrict__ geidx, int* __restrict__ teidx)
{
    int e = blockIdx.x * blockDim.x + threadIdx.x;
    const int GE = EG + NG;
    if (e < GE) {
        int dst = (e < EG) ? gei[EG + e] : e - EG;
        int pos = atomicAdd(&gcur[dst], 1);
        geidx[pos] = e;
    } else {
        int e2 = e - GE;
        if (e2 >= ET + NTREE) return;
        int dst = (e2 < ET) ? tei[ET + e2] : e2 - ET;
        int pos = atomicAdd(&tcur[dst], 1);
        teidx[pos] = e2;
    }
}

// ---------------------------------------------------------------------------
// GAT pieces (feat is bf16)
// ---------------------------------------------------------------------------
__global__ void gat_es_ed(const u16* __restrict__ feat, const float* __restrict__ asrc,
                          const float* __restrict__ adst, float* __restrict__ es,
                          float* __restrict__ ed, int N, int heads, int C)
{
    int gid = blockIdx.x * blockDim.x + threadIdx.x;
    if (gid >= N * heads) return;
    int n = gid / heads, hd = gid - n * heads;
    const u16* hp = feat + ((size_t)n * heads + hd) * C;
    const float* as = asrc + (size_t)hd * C;
    const float* ad = adst + (size_t)hd * C;
    float s1 = 0.f, s2 = 0.f;
    for (int c = 0; c < C; c += 4) {
        uint2 pk = *(const uint2*)(hp + c);
        float v0 = bf2f((u16)(pk.x & 0xffff)), v1 = bf2f((u16)(pk.x >> 16));
        float v2 = bf2f((u16)(pk.y & 0xffff)), v3 = bf2f((u16)(pk.y >> 16));
        s1 += v0 * as[c] + v1 * as[c + 1] + v2 * as[c + 2] + v3 * as[c + 3];
        s2 += v0 * ad[c] + v1 * ad[c + 1] + v2 * ad[c + 2] + v3 * ad[c + 3];
    }
    es[gid] = s1; ed[gid] = s2;
}

// Per-dst CSR softmax: one wave per dst computes alpha for all its edges in
// three register passes (max / sum / write) — replaces the atomic-based
// logit+expsum pair and their memsets; eb ends up holding alpha directly.
template<int HEADS>
__global__ __launch_bounds__(256) void gat_alpha_csr(
    const int* __restrict__ off, const int* __restrict__ eidx,
    const int* __restrict__ ei, int E,
    const float* __restrict__ es, const float* __restrict__ ed,
    float* __restrict__ eb, int N)
{
    int gt = blockIdx.x * blockDim.x + threadIdx.x;
    int dst = gt >> 6, lane = gt & 63;
    if (dst >= N) return;
    const int hd  = lane & (HEADS - 1);
    const int esl = lane / HEADS;          // edge slot within iteration
    const int EPI = 64 / HEADS;
    const int e0 = off[dst], e1 = off[dst + 1];
    const float edv = ed[(size_t)dst * HEADS + hd];

    float mymax = -3.4e38f;
    for (int p0 = e0; p0 < e1; p0 += EPI) {
        int p = p0 + esl;
        if (p < e1) {
            int j = eidx[p];
            int src = (j < E) ? ei[j] : (j - E);
            float e = es[(size_t)src * HEADS + hd] + edv;
            e = e > 0.f ? e : 0.2f * e;
            mymax = fmaxf(mymax, e);
        }
    }
#pragma unroll
    for (int o = HEADS; o < 64; o <<= 1)
        mymax = fmaxf(mymax, __shfl_xor(mymax, o));

    float ssum = 0.f;
    for (int p0 = e0; p0 < e1; p0 += EPI) {
        int p = p0 + esl;
        if (p < e1) {
            int j = eidx[p];
            int src = (j < E) ? ei[j] : (j - E);
            float e = es[(size_t)src * HEADS + hd] + edv;
            e = e > 0.f ? e : 0.2f * e;
            ssum += __expf(e - mymax);
        }
    }
#pragma unroll
    for (int o = HEADS; o < 64; o <<= 1)
        ssum += __shfl_xor(ssum, o);
    float sinv = __fdividef(1.f, ssum);

    for (int p0 = e0; p0 < e1; p0 += EPI) {
        int p = p0 + esl;
        if (p < e1) {
            int j = eidx[p];
            int src = (j < E) ? ei[j] : (j - E);
            float e = es[(size_t)src * HEADS + hd] + edv;
            e = e > 0.f ? e : 0.2f * e;
            eb[(size_t)j * HEADS + hd] = __expf(e - mymax) * sinv;
        }
    }
}

// accum: eb holds alpha (pre-normalized) — no s read, no divide.
template<int C, int VEC>
__global__ __launch_bounds__(256) void gat_accum_csr(
    const int* __restrict__ off, const int* __restrict__ eidx,
    const int* __restrict__ ei, int E,
    const float* __restrict__ eb,
    const u16* __restrict__ feat, const float* __restrict__ bias,
    float* __restrict__ outf, u16* __restrict__ outb,
    int N, int heads, int HC, int nchunk)
{
    int gt = blockIdx.x * blockDim.x + threadIdx.x;
    int w = gt >> 6, lane = gt & 63;
    int dst = w / nchunk, chunk = w - dst * nchunk;
    if (dst >= N) return;
    int c0 = chunk * 64 * VEC + lane * VEC;
    if (c0 >= HC) return;
    int hh[VEC]; float acc[VEC];
#pragma unroll
    for (int v = 0; v < VEC; ++v) {
        int c = c0 + v;
        hh[v] = c / C;
        acc[v] = 0.f;
    }
    int e0 = off[dst], e1 = off[dst + 1];
    for (int p = e0; p < e1; ++p) {
        int j = eidx[p];
        int src = (j < E) ? ei[j] : (j - E);
        const u16* frp = feat + (size_t)src * HC + c0;
        float fv[VEC];
        if (VEC == 8) {
            uint4 pk = *(const uint4*)frp;
            fv[0] = bf2f((u16)(pk.x & 0xffff)); fv[1] = bf2f((u16)(pk.x >> 16));
            fv[2] = bf2f((u16)(pk.y & 0xffff)); fv[3] = bf2f((u16)(pk.y >> 16));
            fv[4] = bf2f((u16)(pk.z & 0xffff)); fv[5] = bf2f((u16)(pk.z >> 16));
            fv[6] = bf2f((u16)(pk.w & 0xffff)); fv[7] = bf2f((u16)(pk.w >> 16));
        } else if (VEC == 4) {
            uint2 pk = *(const uint2*)frp;
            fv[0] = bf2f((u16)(pk.x & 0xffff)); fv[1] = bf2f((u16)(pk.x >> 16));
            fv[2] = bf2f((u16)(pk.y & 0xffff)); fv[3] = bf2f((u16)(pk.y >> 16));
        } else {
            u32 pk = *(const u32*)frp;
            fv[0] = bf2f((u16)(pk & 0xffff)); fv[1] = bf2f((u16)(pk >> 16));
        }
#pragma unroll
        for (int v = 0; v < VEC; ++v)
            acc[v] += fv[v] * eb[(size_t)j * heads + hh[v]];
    }
#pragma unroll
    for (int v = 0; v < VEC; ++v) {
        int c = c0 + v;
        if (c >= HC) continue;
        float o = fmaxf(acc[v] + bias[c], 0.f);
        if (outf) outf[(size_t)dst * HC + c] = o;
        if (outb) outb[(size_t)dst * HC + c] = f2bf(o);
    }
}

__global__ void scatter_mean_accum(const float* __restrict__ x, const int* __restrict__ idx,
                                   float* __restrict__ ssum, float* __restrict__ cnt)
{
    int t = blockIdx.x * blockDim.x + threadIdx.x;
    if (t >= NTREE * HD) return;
    int n = t / HD, c = t - n * HD;
    int b = idx[n];
    atomicAdd(&ssum[b * HD + c], x[t]);
    if (c == 0) atomicAdd(&cnt[b], 1.f);
}

__global__ void fc_out(const float* __restrict__ ssum, const float* __restrict__ cnt,
                       const float* __restrict__ W, const float* __restrict__ b,
                       float* __restrict__ out)
{
    int t = threadIdx.x;                 // 512 threads
    int bb = t >> 2, j = t & 3;
    float inv = __fdividef(1.f, fmaxf(cnt[bb], 1.f));
    float acc = b[j];
    for (int k = 0; k < HD; ++k) acc += ssum[bb * HD + k] * inv * W[j * HD + k];
    out[t] = acc;
}

// ---------------------------------------------------------------------------
// Host launcher
// ---------------------------------------------------------------------------
extern "C" void kernel_launch(void* const* d_in, const int* in_sizes, int n_in,
                              void* d_out, int out_size, void* d_ws, size_t ws_size,
                              hipStream_t stream)
{
    const float* user_feats = (const float*)d_in[1];
    const int*   gnf        = (const int*)d_in[2];
    const int*   gei        = (const int*)d_in[3];
    const int*   tnf        = (const int*)d_in[4];
    const int*   tei        = (const int*)d_in[5];
    const int*   indices    = (const int*)d_in[6];
    const float* h0g        = (const float*)d_in[7];
    const float* h0t        = (const float*)d_in[8];
    const float* temb       = (const float*)d_in[9];
    const float* gW[2][4] = {{(const float*)d_in[10], (const float*)d_in[11], (const float*)d_in[12], (const float*)d_in[13]},
                             {(const float*)d_in[14], (const float*)d_in[15], (const float*)d_in[16], (const float*)d_in[17]}};
    const float* tW[2][4] = {{(const float*)d_in[18], (const float*)d_in[19], (const float*)d_in[20], (const float*)d_in[21]},
                             {(const float*)d_in[22], (const float*)d_in[23], (const float*)d_in[24], (const float*)d_in[25]}};
    const float* uW1 = (const float*)d_in[26]; const float* ub1 = (const float*)d_in[27];
    const float* uW2 = (const float*)d_in[28]; const float* ub2 = (const float*)d_in[29];
    const float* gc1W = (const float*)d_in[30]; const float* gc1as = (const float*)d_in[31];
    const float* gc1ad = (const float*)d_in[32]; const float* gc1b = (const float*)d_in[33];
    const float* gc2W = (const float*)d_in[34]; const float* gc2as = (const float*)d_in[35];
    const float* gc2ad = (const float*)d_in[36]; const float* gc2b = (const float*)d_in[37];
    const float* tc1W = (const float*)d_in[38]; const float* tc1as = (const float*)d_in[39];
    const float* tc1ad = (const float*)d_in[40]; const float* tc1b = (const float*)d_in[41];
    const float* tc2W = (const float*)d_in[42]; const float* tc2as = (const float*)d_in[43];
    const float* tc2ad = (const float*)d_in[44]; const float* tc2b = (const float*)d_in[45];
    const float* fcW = (const float*)d_in[46]; const float* fcb = (const float*)d_in[47];
    float* out = (float*)d_out;

    char* ws = (char*)d_ws;
    const size_t NEED = 226500000;
    if (ws_size < NEED) return;

    // ---- workspace layout (decimal byte offsets, overlays noted) ----
    float* XGF    = (float*)(ws + 0);            // 12 MB [NG][100] fp32
    u16*   TEMB_B = (u16*)(ws + 12000000);       // 12.8 MB [VOC][128]
    u16*   ETAB_G = (u16*)(ws + 25000000);       // 44.8 MB [VOC][448] interleaved
    u16*   ETAB_T = (u16*)(ws + 70000000);       // 44.8 MB -> 114.8
    u16*   GH1B   = (u16*)(ws + 115000000);      // 2.56 MB [NTG][128]
    u16*   TH1B   = (u16*)(ws + 117600000);      // 7.68 MB [NTREE][128]
    float* UE     = (float*)(ws + 125300000);    // 8 MB
    float* HID    = (float*)(ws + 133400000);    // 8 MB
    u16*   WARENA = (u16*)(ws + 141500000);      // 1.11 MB weight arena
    int*   GOFF   = (int*)(ws + 142700000);
    int*   GCUR   = (int*)(ws + 142900000);
    int*   GCNT   = (int*)(ws + 143100000);      // NG ints
    int*   TCNT   = (int*)(ws + 143220000);      // NTREE ints (adjacent: 1 memset)
    int*   GEIDX  = (int*)(ws + 143400000);      // 0.92 MB
    int*   TOFF   = (int*)(ws + 144400000);
    int*   TCUR   = (int*)(ws + 144600000);
    int*   TEIDX  = (int*)(ws + 144800000);      // 0.36 MB
    float* ESB    = (float*)(ws + 145300000);
    float* EDB    = (float*)(ws + 146300000);
    float* EBB    = (float*)(ws + 149300000);    // 7.36 MB (alpha per edge-head)
    float* SSUM   = (float*)(ws + 156700000);
    float* SCNT   = (float*)(ws + 156800000);
    u16*   XG_B   = (u16*)(ws + 157000000);      // 7.68 MB [NG][128]
    u16*   GFEAT1 = (u16*)(ws + 165000000);      // 30.72 MB [NG][512] -> 195.72
    // overlays (regions dead by the time they're written):
    u16*   GOUT1B = (u16*)(ws + 25000000);       // 30.72 MB (over ETAB_G, dead after GRU)
    u16*   GFEAT2 = (u16*)(ws + 56000000);       // 6 MB [NG][100]
    u16*   TFEAT1 = (u16*)(ws + 25000000);       // 48 MB [NTREE][800] (after graph GATs)
    u16*   TOUT1B = (u16*)(ws + 74000000);       // 48 MB (over ETAB_T/GH1B tail, dead)
    u16*   TFEAT2 = (u16*)(ws + 123000000);      // 6 MB (over TH1B-tail/UE, dead)
    float* XOUT2  = (float*)(ws + 157000000);    // 12 MB (over XG_B/GFEAT1-head, dead)

    // weight arena slots (u16 element offsets)
    u16* gWHH0  = WARENA + 0;        // 6 x [336][128]
    u16* gWIH1  = WARENA + 43008;
    u16* gWHH1  = WARENA + 86016;
    u16* tWHH0  = WARENA + 129024;
    u16* tWIH1  = WARENA + 172032;
    u16* tWHH1  = WARENA + 215040;
    u16* W_IH0A = WARENA + 258048;   // [448][128] interleaved-row Etab weights
    u16* W_IH0B = WARENA + 315392;
    u16* W_G1   = WARENA + 372736;   // up to [800][128]
    u16* W_G2   = WARENA + 475136;   // up to [100][800]

    auto cvt = [&](const float* src, u16* dst, int M, int Mp, int K, int ldk,
                   const float* app = nullptr, int appone = 0) {
        convert_pad2<<<((size_t)Mp * ldk + 255) / 256, 256, 0, stream>>>(
            src, dst, M, Mp, K, ldk, app, appone);
    };
    auto mfma = [&](const u16* A, int lda, const u16* W, int ldw,
                    float* Cf, u16* Cb, int ldc, int M, int N, int Kt) {
        dim3 grid((M + 63) / 64, (N + 63) / 64, 1);
        gemm_mfma<<<grid, 256, 0, stream>>>(A, W, Cf, Cb, M, N, Kt, lda, ldw, ldc);
    };

    // ---- 1. user embed (fp32) ----
    {
        dim3 g1((NU + 63) / 64, (HD + 63) / 64, 1);
        gemm_nt<<<g1, 256, 0, stream>>>(user_feats, uW1, ub1, HID, NU, HD, 9, 1);
        gemm_nt<<<g1, 256, 0, stream>>>(HID, uW2, ub2, UE, NU, HD, HD, 0);
    }

    // ---- 2. converts (scaled) + fused Etab build ----
    cvt(temb, TEMB_B, VOC, VOC, HD, 128, nullptr, 1);           // col100 = 1
    {
        CvtgBatch B;
        B.src[0] = gW[0][1]; B.bias[0] = gW[0][3]; B.dst[0] = gWHH0;
        B.src[1] = gW[1][0]; B.bias[1] = gW[1][2]; B.dst[1] = gWIH1;
        B.src[2] = gW[1][1]; B.bias[2] = gW[1][3]; B.dst[2] = gWHH1;
        B.src[3] = tW[0][1]; B.bias[3] = tW[0][3]; B.dst[3] = tWHH0;
        B.src[4] = tW[1][0]; B.bias[4] = tW[1][2]; B.dst[4] = tWIH1;
        B.src[5] = tW[1][1]; B.bias[5] = tW[1][3]; B.dst[5] = tWHH1;
        convert_gru_w6<<<6 * CVTG_BLOCKS_PER_MAT, 256, 0, stream>>>(B);
    }
    convert_ih0<<<(2 * 448 * 128 + 255) / 256, 256, 0, stream>>>(
        gW[0][0], gW[0][2], W_IH0A, tW[0][0], tW[0][2], W_IH0B);
    {
        dim3 ge((VOC + 63) / 64, 7, 2);
        gemm_etab<<<ge, 256, 0, stream>>>(TEMB_B, W_IH0A, W_IH0B, ETAB_G, ETAB_T);
    }

    // ---- CSR (both graphs, fused phases) ----
    hipMemsetAsync(GCNT, 0, 143400000 - 143100000, stream);   // GCNT + TCNT
    {
        int tot = (EG + NG) + (ET + NTREE);
        csr_count2<<<(tot + 255) / 256, 256, 0, stream>>>(gei, tei, GCNT, TCNT);
        csr_scan2<<<2, 256, 0, stream>>>(GCNT, GOFF, GCUR, TCNT, TOFF, TCUR);
        csr_scatter2<<<(tot + 255) / 256, 256, 0, stream>>>(gei, tei, GCUR, TCUR, GEIDX, TEIDX);
    }

    // ---- 3. combined GRU (both branches, one launch, 64 rows/block) ----
    {
        GruProb Pg = { ETAB_G, gnf, h0g, gWHH0, gWIH1, gWHH1, GH1B, NTG };
        GruProb Pt = { ETAB_T, tnf, h0t, tWHH0, tWIH1, tWHH1, TH1B, NTREE };
        int gblk = (NTG + 63) / 64;      // 157
        int tblk = (NTREE + 63) / 64;    // 469
        gru_fused11<<<gblk + tblk, 448, 0, stream>>>(Pg, Pt, gblk);
    }

    // ---- 4. graph GAT chain ----
    build_xg_bf<<<(NG * 128 + 255) / 256, 256, 0, stream>>>(GH1B, UE, XG_B);
    cvt(gc1W, W_G1, 512, 512, HD, 128);
    cvt(gc2W, W_G2, 100, 100, 512, 512);
    {   // graph GAT1: 8 heads x 64
        mfma(XG_B, 128, W_G1, 128, nullptr, GFEAT1, 512, NG, 512, 4);
        gat_es_ed<<<(NG * 8 + 255) / 256, 256, 0, stream>>>(GFEAT1, gc1as, gc1ad, ESB, EDB, NG, 8, 64);
        gat_alpha_csr<8><<<(NG + 3) / 4, 256, 0, stream>>>(GOFF, GEIDX, gei, EG, ESB, EDB, EBB, NG);
        gat_accum_csr<64, 8><<<(NG + 3) / 4, 256, 0, stream>>>(
            GOFF, GEIDX, gei, EG, EBB, GFEAT1, gc1b, nullptr, GOUT1B, NG, 8, 512, 1);
    }
    {   // graph GAT2: 1 head x 100
        mfma(GOUT1B, 512, W_G2, 512, nullptr, GFEAT2, 100, NG, 100, 16);
        gat_es_ed<<<(NG + 255) / 256, 256, 0, stream>>>(GFEAT2, gc2as, gc2ad, ESB, EDB, NG, 1, 100);
        gat_alpha_csr<1><<<(NG + 3) / 4, 256, 0, stream>>>(GOFF, GEIDX, gei, EG, ESB, EDB, EBB, NG);
        gat_accum_csr<100, 2><<<(NG + 3) / 4, 256, 0, stream>>>(
            GOFF, GEIDX, gei, EG, EBB, GFEAT2, gc2b, XGF, nullptr, NG, 1, 100, 1);
    }

    // ---- 5. tree GAT chain ----
    set_roots<<<(NB * HD + 255) / 256, 256, 0, stream>>>(XGF, TH1B);
    cvt(tc1W, W_G1, 800, 800, HD, 128);
    cvt(tc2W, W_G2, 100, 100, 800, 800);
    {   // tree GAT1: 8 heads x 100
        mfma(TH1B, 128, W_G1, 128, nullptr, TFEAT1, 800, NTREE, 800, 4);
        gat_es_ed<<<(NTREE * 8 + 255) / 256, 256, 0, stream>>>(TFEAT1, tc1as, tc1ad, ESB, EDB, NTREE, 8, 100);
        gat_alpha_csr<8><<<(NTREE + 3) / 4, 256, 0, stream>>>(TOFF, TEIDX, tei, ET, ESB, EDB, EBB, NTREE);
        gat_accum_csr<100, 8><<<(NTREE * 2 + 3) / 4, 256, 0, stream>>>(
            TOFF, TEIDX, tei, ET, EBB, TFEAT1, tc1b, nullptr, TOUT1B, NTREE, 8, 800, 2);
    }
    {   // tree GAT2: 1 head x 100
        mfma(TOUT1B, 800, W_G2, 800, nullptr, TFEAT2, 100, NTREE, 100, 25);
        gat_es_ed<<<(NTREE + 255) / 256, 256, 0, stream>>>(TFEAT2, tc2as, tc2ad, ESB, EDB, NTREE, 1, 100);
        gat_alpha_csr<1><<<(NTREE + 3) / 4, 256, 0, stream>>>(TOFF, TEIDX, tei, ET, ESB, EDB, EBB, NTREE);
        gat_accum_csr<100, 2><<<(NTREE + 3) / 4, 256, 0, stream>>>(
            TOFF, TEIDX, tei, ET, EBB, TFEAT2, tc2b, XOUT2, nullptr, NTREE, 1, 100, 1);
    }

    // ---- 6. scatter_mean + classifier ----
    hipMemsetAsync(SSUM, 0, (size_t)NB * HD * 4, stream);
    hipMemsetAsync(SCNT, 0, (size_t)NB * 4, stream);
    scatter_mean_accum<<<(NTREE * HD + 255) / 256, 256, 0, stream>>>(XOUT2, indices, SSUM, SCNT);
    fc_out<<<1, 512, 0, stream>>>(SSUM, SCNT, fcW, fcb, out);
}

// Round 7
// 1485.335 us; speedup vs baseline: 1.2253x; 1.2253x over previous
//
#include <hip/hip_runtime.h>

// ---------------------------------------------------------------------------
// Problem constants
// ---------------------------------------------------------------------------
#define NB    128
#define HD    100
#define NU    20000
#define NTG   10000
#define NTREE 30000
#define NG    30000
#define TT    20
#define EG    200000
#define ET    60000
#define VOC   50000

#define ESTR2 448   // interleaved Etab row stride in u16: [112 cols][4] (r,z,n,pad)
#define WROWS 336   // GRU weight rows: 3 gates x 112 (gate stride 112)
#define LOG2E  1.4426950408889634f
#define LOG2E2 2.8853900817779268f

typedef unsigned short u16;
typedef unsigned int   u32;
typedef __attribute__((ext_vector_type(8))) short short8;
typedef __attribute__((ext_vector_type(4))) float floatx4;

// gate pre-activations arrive PRE-SCALED by log2e (r,z) / 2log2e (n)
__device__ __forceinline__ float sigmoid2_(float y) {
    return __fdividef(1.f, 1.f + __builtin_amdgcn_exp2f(-y));
}
__device__ __forceinline__ float tanh2_(float y) {
    return 1.f - __fdividef(2.f, __builtin_amdgcn_exp2f(y) + 1.f);
}
__device__ __forceinline__ u16 f2bf(float f) {
    u32 u = __float_as_uint(f);
    u32 r = (u + 0x7fffu + ((u >> 16) & 1u)) >> 16;
    return (u16)r;
}
__device__ __forceinline__ u16 f2bf_c(float f) {
    u32 r;
    asm("v_cvt_pk_bf16_f32 %0, %1, %2" : "=v"(r) : "v"(f), "v"(f));
    return (u16)r;
}
__device__ __forceinline__ float bf2f(u16 h) {
    return __uint_as_float(((u32)h) << 16);
}

// ---------------------------------------------------------------------------
// Fused 2-layer GRU v10 (PROVEN 588.8 µs): 448 threads (7 waves) / 32 rows.
// v11's 64-row variant SPILLED (state 64 regs + 144 weight regs > 256 budget;
// WRITE_SIZE 25->454 MB) — 32 rows is the register-feasible maximum.
// ---------------------------------------------------------------------------
struct GruProb {
    const u16*   Etab;     // [VOC][112][4] interleaved, pre-scaled
    const int*   nodes;    // [M][TT]
    const float* h0;       // [2][M][100] fp32
    const u16*   Whh0;     // [336][128] gate-padded, scaled (col100 = bhh0)
    const u16*   Wih1;
    const u16*   Whh1;
    u16*         hout;     // [M][128]
    int          M;
};

__global__ __launch_bounds__(448, 2) void gru_fused10(GruProb Pg, GruProb Pt, int gblocks)
{
    const bool isg = (int)blockIdx.x < gblocks;
    const GruProb P = isg ? Pg : Pt;
    const int bx = isg ? blockIdx.x : blockIdx.x - gblocks;
    const int M  = P.M;
    const int m0 = bx * 32;

    __shared__ u16 H0[2][32 * 128];
    __shared__ u16 H1[2][32 * 128];
    __shared__ int NID[TT * 32];

    const int tid  = threadIdx.x;
    const int w    = tid >> 6, lane = tid & 63;
    const int fr   = lane & 15, quad = lane >> 4;
    const int c    = w * 16 + fr;
    const bool cok = (c < HD);

    short8 Bh0[3][4], Bx1[3][4], Bh1[3][4];
#pragma unroll
    for (int g = 0; g < 3; ++g) {
        const size_t rb = (size_t)((g * 7 + w) * 16 + fr) * 128 + quad * 8;
#pragma unroll
        for (int kk = 0; kk < 4; ++kk) {
            Bh0[g][kk] = *(const short8*)(P.Whh0 + rb + kk * 32);
            Bx1[g][kk] = *(const short8*)(P.Wih1 + rb + kk * 32);
            Bh1[g][kk] = *(const short8*)(P.Whh1 + rb + kk * 32);
        }
    }

    for (int i = tid; i < 32 * 128; i += 448) {
        H0[0][i] = 0; H0[1][i] = 0; H1[0][i] = 0; H1[1][i] = 0;
    }
    for (int i = tid; i < 32 * TT; i += 448) {
        int row = i / TT, t = i - row * TT;
        int gm = m0 + row;
        NID[t * 32 + row] = (gm < M) ? P.nodes[(size_t)gm * TT + t] : 0;
    }
    __syncthreads();
    if (tid < 32) {
        int off = 200 ^ ((tid & 7) << 4);
        *(u16*)((char*)&H0[0][0] + tid * 256 + off) = 0x3F80;
        *(u16*)((char*)&H0[1][0] + tid * 256 + off) = 0x3F80;
        *(u16*)((char*)&H1[0][0] + tid * 256 + off) = 0x3F80;
        *(u16*)((char*)&H1[1][0] + tid * 256 + off) = 0x3F80;
    }

    float h0f[2][4] = {{0.f,0.f,0.f,0.f},{0.f,0.f,0.f,0.f}};
    float h1f[2][4] = {{0.f,0.f,0.f,0.f},{0.f,0.f,0.f,0.f}};
    if (cok) {
#pragma unroll
        for (int rt = 0; rt < 2; ++rt)
#pragma unroll
        for (int r = 0; r < 4; ++r) {
            int row = rt * 16 + quad * 4 + r;
            int gm  = m0 + row;
            float v0 = 0.f, v1 = 0.f;
            if (gm < M) {
                v0 = P.h0[(size_t)gm * HD + c];
                v1 = P.h0[(size_t)(M + gm) * HD + c];
            }
            h0f[rt][r] = v0; h1f[rt][r] = v1;
            int off = (2 * c) ^ ((row & 7) << 4);
            *(u16*)((char*)&H0[0][0] + row * 256 + off) = f2bf_c(v0);
            *(u16*)((char*)&H1[0][0] + row * 256 + off) = f2bf_c(v1);
        }
    }

    // x-gate prefetch: one dwordx2 per (rt,r) -> (r,z) in lo, (n,pad) in hi
    u32 xlo[2][4], xhi[2][4];
    auto xpref = [&](int tn) {
        if (cok) {
#pragma unroll
            for (int rt = 0; rt < 2; ++rt)
#pragma unroll
            for (int r = 0; r < 4; ++r) {
                int row = rt * 16 + quad * 4 + r;
                int nd  = NID[tn * 32 + row];
                uint2 v = *(const uint2*)(P.Etab + (size_t)nd * ESTR2 + c * 4);
                xlo[rt][r] = v.x; xhi[rt][r] = v.y;
            }
        }
    };
    __syncthreads();
    xpref(0);

    // ---- prologue: A(0) ----
#pragma unroll
    for (int rt = 0; rt < 2; ++rt) {
        short8 a[4];
#pragma unroll
        for (int kk = 0; kk < 4; ++kk) {
            int row = rt * 16 + fr;
            int off = (kk * 64 + quad * 16) ^ ((row & 7) << 4);
            a[kk] = *(const short8*)((const char*)&H0[0][0] + row * 256 + off);
        }
        floatx4 ag[3];
#pragma unroll
        for (int g = 0; g < 3; ++g) ag[g] = (floatx4){0.f, 0.f, 0.f, 0.f};
#pragma unroll
        for (int g = 0; g < 3; ++g)
#pragma unroll
            for (int kk = 0; kk < 4; ++kk)
                ag[g] = __builtin_amdgcn_mfma_f32_16x16x32_bf16(a[kk], Bh0[g][kk], ag[g], 0, 0, 0);
        if (cok) {
#pragma unroll
            for (int r = 0; r < 4; ++r) {
                int row = rt * 16 + quad * 4 + r;
                float rr = sigmoid2_(bf2f((u16)xlo[rt][r]) + ag[0][r]);
                float zz = sigmoid2_(bf2f((u16)(xlo[rt][r] >> 16)) + ag[1][r]);
                float nn = tanh2_(bf2f((u16)xhi[rt][r]) + rr * ag[2][r]);
                float o  = nn + zz * (h0f[rt][r] - nn);
                h0f[rt][r] = o;
                *(u16*)((char*)&H0[1][0] + row * 256 + ((2 * c) ^ ((row & 7) << 4))) = f2bf_c(o);
            }
        }
    }
    __syncthreads();

    // ---- regions r = 0..TT-1: B(r) + A(r+1) ----
    for (int r = 0; r < TT; ++r) {
        const bool doA = (r + 1 < TT);
        if (doA) xpref(r + 1);

        const char* rd0 = (const char*)&H0[(r + 1) & 1][0];
        const char* rd1 = (const char*)&H1[r & 1][0];
        char*       wr0 = (char*)&H0[r & 1][0];
        char*       wr1 = (char*)&H1[(r + 1) & 1][0];

#pragma unroll
        for (int rt = 0; rt < 2; ++rt) {
            short8 a0[4], a1[4];
#pragma unroll
            for (int kk = 0; kk < 4; ++kk) {
                int row = rt * 16 + fr;
                int off = (kk * 64 + quad * 16) ^ ((row & 7) << 4);
                a0[kk] = *(const short8*)(rd0 + row * 256 + off);
                a1[kk] = *(const short8*)(rd1 + row * 256 + off);
            }
            floatx4 rz0 = {0.f,0.f,0.f,0.f}, rz1 = {0.f,0.f,0.f,0.f};
            floatx4 xnv = {0.f,0.f,0.f,0.f}, hnv = {0.f,0.f,0.f,0.f};
#pragma unroll
            for (int kk = 0; kk < 4; ++kk)
                rz0 = __builtin_amdgcn_mfma_f32_16x16x32_bf16(a0[kk], Bx1[0][kk], rz0, 0, 0, 0);
#pragma unroll
            for (int kk = 0; kk < 4; ++kk)
                rz0 = __builtin_amdgcn_mfma_f32_16x16x32_bf16(a1[kk], Bh1[0][kk], rz0, 0, 0, 0);
#pragma unroll
            for (int kk = 0; kk < 4; ++kk)
                rz1 = __builtin_amdgcn_mfma_f32_16x16x32_bf16(a0[kk], Bx1[1][kk], rz1, 0, 0, 0);
#pragma unroll
            for (int kk = 0; kk < 4; ++kk)
                rz1 = __builtin_amdgcn_mfma_f32_16x16x32_bf16(a1[kk], Bh1[1][kk], rz1, 0, 0, 0);
#pragma unroll
            for (int kk = 0; kk < 4; ++kk)
                xnv = __builtin_amdgcn_mfma_f32_16x16x32_bf16(a0[kk], Bx1[2][kk], xnv, 0, 0, 0);
#pragma unroll
            for (int kk = 0; kk < 4; ++kk)
                hnv = __builtin_amdgcn_mfma_f32_16x16x32_bf16(a1[kk], Bh1[2][kk], hnv, 0, 0, 0);
            floatx4 ag[3];
#pragma unroll
            for (int g = 0; g < 3; ++g) ag[g] = (floatx4){0.f, 0.f, 0.f, 0.f};
            if (doA) {
#pragma unroll
                for (int g = 0; g < 3; ++g)
#pragma unroll
                    for (int kk = 0; kk < 4; ++kk)
                        ag[g] = __builtin_amdgcn_mfma_f32_16x16x32_bf16(a0[kk], Bh0[g][kk], ag[g], 0, 0, 0);
            }
            if (cok) {
#pragma unroll
                for (int r4 = 0; r4 < 4; ++r4) {
                    int row = rt * 16 + quad * 4 + r4;
                    float rr = sigmoid2_(rz0[r4]);
                    float zz = sigmoid2_(rz1[r4]);
                    float nn = tanh2_(xnv[r4] + rr * hnv[r4]);
                    float o  = nn + zz * (h1f[rt][r4] - nn);
                    h1f[rt][r4] = o;
                    *(u16*)(wr1 + row * 256 + ((2 * c) ^ ((row & 7) << 4))) = f2bf_c(o);
                }
                if (doA) {
#pragma unroll
                    for (int r4 = 0; r4 < 4; ++r4) {
                        int row = rt * 16 + quad * 4 + r4;
                        float rr = sigmoid2_(bf2f((u16)xlo[rt][r4]) + ag[0][r4]);
                        float zz = sigmoid2_(bf2f((u16)(xlo[rt][r4] >> 16)) + ag[1][r4]);
                        float nn = tanh2_(bf2f((u16)xhi[rt][r4]) + rr * ag[2][r4]);
                        float o  = nn + zz * (h0f[rt][r4] - nn);
                        h0f[rt][r4] = o;
                        *(u16*)(wr0 + row * 256 + ((2 * c) ^ ((row & 7) << 4))) = f2bf_c(o);
                    }
                }
            }
        }
        __syncthreads();
    }

    for (int i = tid; i < 32 * 128; i += 448) {
        int row = i >> 7, cc = i & 127;
        int gm = m0 + row;
        if (gm < M) {
            int off = (2 * cc) ^ ((row & 7) << 4);
            P.hout[(size_t)gm * 128 + cc] = *(const u16*)((const char*)&H1[0][0] + row * 256 + off);
        }
    }
}

// ---------------------------------------------------------------------------
// bf16 MFMA GEMM (GAT feature GEMMs)
// ---------------------------------------------------------------------------
#define LDST 40
__global__ __launch_bounds__(256) void gemm_mfma(
    const u16* __restrict__ A, const u16* __restrict__ B,
    float* __restrict__ Cf, u16* __restrict__ Cb,
    int M, int N, int Kt, int lda, int ldw, int ldc)
{
    const int m0 = blockIdx.x * 64;
    if (m0 >= M) return;
    const int n0 = blockIdx.y * 64;

    __shared__ u16 Als[64 * LDST];
    __shared__ u16 Wls[64 * LDST];

    const int tid  = threadIdx.x;
    const int wave = tid >> 6, lane = tid & 63;
    const int row  = tid >> 2, part = (tid & 3) * 8;
    const int fr   = lane & 15, quad = lane >> 4;

    floatx4 acc[4];
#pragma unroll
    for (int t = 0; t < 4; ++t) acc[t] = (floatx4){0.f, 0.f, 0.f, 0.f};

    const int am = m0 + row;  const bool aok = am < M;
    const int wn = n0 + row;  const bool wok = wn < N;
    const uint4 z4 = {0u, 0u, 0u, 0u};

    for (int kk = 0; kk < Kt; ++kk) {
        uint4 av = aok ? *(const uint4*)(A + (size_t)am * lda + kk * 32 + part) : z4;
        uint4 wv = wok ? *(const uint4*)(B + (size_t)wn * ldw + kk * 32 + part) : z4;
        __syncthreads();
        *(uint4*)&Als[row * LDST + part] = av;
        *(uint4*)&Wls[row * LDST + part] = wv;
        __syncthreads();
        short8 af = *(const short8*)&Als[((wave << 4) + fr) * LDST + quad * 8];
#pragma unroll
        for (int t = 0; t < 4; ++t) {
            short8 bf = *(const short8*)&Wls[((t << 4) + fr) * LDST + quad * 8];
            acc[t] = __builtin_amdgcn_mfma_f32_16x16x32_bf16(af, bf, acc[t], 0, 0, 0);
        }
    }

    const int orow0 = m0 + (wave << 4) + quad * 4;
#pragma unroll
    for (int t = 0; t < 4; ++t) {
        int col = n0 + (t << 4) + fr;
        if (col >= N) continue;
#pragma unroll
        for (int r = 0; r < 4; ++r) {
            int mr = orow0 + r;
            if (mr >= M) continue;
            float v = acc[t][r];
            if (Cf) Cf[(size_t)mr * ldc + col] = v;
            if (Cb) Cb[(size_t)mr * ldc + col] = f2bf(v);
        }
    }
}

// Dual Etab build: z selects (W,C). W rows pre-ordered (r,z,n,pad)-interleaved.
__global__ __launch_bounds__(256) void gemm_etab(
    const u16* __restrict__ A, const u16* __restrict__ W0, const u16* __restrict__ W1,
    u16* __restrict__ C0, u16* __restrict__ C1)
{
    const int m0 = blockIdx.x * 64;
    const int n0 = blockIdx.y * 64;
    const u16* B = blockIdx.z ? W1 : W0;
    u16* Cb = blockIdx.z ? C1 : C0;
    const int N = 400;

    __shared__ u16 Als[64 * LDST];
    __shared__ u16 Wls[64 * LDST];

    const int tid  = threadIdx.x;
    const int wave = tid >> 6, lane = tid & 63;
    const int row  = tid >> 2, part = (tid & 3) * 8;
    const int fr   = lane & 15, quad = lane >> 4;

    floatx4 acc[4];
#pragma unroll
    for (int t = 0; t < 4; ++t) acc[t] = (floatx4){0.f, 0.f, 0.f, 0.f};

    const int am = m0 + row;
    const int wn = n0 + row;  const bool wok = wn < N;
    const uint4 z4 = {0u, 0u, 0u, 0u};

    for (int kk = 0; kk < 4; ++kk) {
        uint4 av = *(const uint4*)(A + (size_t)am * 128 + kk * 32 + part);
        uint4 wv = wok ? *(const uint4*)(B + (size_t)wn * 128 + kk * 32 + part) : z4;
        __syncthreads();
        *(uint4*)&Als[row * LDST + part] = av;
        *(uint4*)&Wls[row * LDST + part] = wv;
        __syncthreads();
        short8 af = *(const short8*)&Als[((wave << 4) + fr) * LDST + quad * 8];
#pragma unroll
        for (int t = 0; t < 4; ++t) {
            short8 bf = *(const short8*)&Wls[((t << 4) + fr) * LDST + quad * 8];
            acc[t] = __builtin_amdgcn_mfma_f32_16x16x32_bf16(af, bf, acc[t], 0, 0, 0);
        }
    }

    const int orow0 = m0 + (wave << 4) + quad * 4;
#pragma unroll
    for (int t = 0; t < 4; ++t) {
        int col = n0 + (t << 4) + fr;
        if (col >= N) continue;
#pragma unroll
        for (int r = 0; r < 4; ++r)
            Cb[(size_t)(orow0 + r) * ESTR2 + col] = f2bf(acc[t][r]);
    }
}

// ---------------------------------------------------------------------------
// fp32 tiled GEMM (user-embed MLP only)
// ---------------------------------------------------------------------------
__global__ __launch_bounds__(256) void gemm_nt(
    const float* __restrict__ A, const float* __restrict__ W,
    const float* __restrict__ bias, float* __restrict__ C,
    int M, int N, int K, int relu)
{
    const int m0 = blockIdx.x * 64;
    const int n0 = blockIdx.y * 64;
    __shared__ float As[20][68];
    __shared__ float Ws[20][68];
    const int tid = threadIdx.x;
    const int r0 = (tid >> 4) * 4;
    const int c0 = (tid & 15) * 4;
    int sr[5], sk[5];
#pragma unroll
    for (int it = 0; it < 5; ++it) {
        int idx = tid + it * 256;
        sr[it] = idx / 20; sk[it] = idx - sr[it] * 20;
    }
    float acc[4][4];
#pragma unroll
    for (int i = 0; i < 4; ++i)
#pragma unroll
        for (int j = 0; j < 4; ++j) acc[i][j] = 0.f;
    const int nch = (K + 19) / 20;
    for (int ch = 0; ch < nch; ++ch) {
        const int k0 = ch * 20;
#pragma unroll
        for (int it = 0; it < 5; ++it) {
            int m = m0 + sr[it], k = k0 + sk[it];
            float va = 0.f, vw = 0.f;
            if (k < K) {
                if (m < M) va = A[(size_t)m * K + k];
                int n = n0 + sr[it];
                if (n < N) vw = W[(size_t)n * K + k];
            }
            As[sk[it]][sr[it]] = va;
            Ws[sk[it]][sr[it]] = vw;
        }
        __syncthreads();
#pragma unroll
        for (int kkk = 0; kkk < 20; ++kkk) {
            float4 a = *(const float4*)&As[kkk][r0];
            float4 w = *(const float4*)&Ws[kkk][c0];
            float av[4] = {a.x, a.y, a.z, a.w};
            float wv[4] = {w.x, w.y, w.z, w.w};
#pragma unroll
            for (int i = 0; i < 4; ++i)
#pragma unroll
                for (int j = 0; j < 4; ++j)
                    acc[i][j] = fmaf(av[i], wv[j], acc[i][j]);
        }
        __syncthreads();
    }
#pragma unroll
    for (int i = 0; i < 4; ++i) {
        int m = m0 + r0 + i;
        if (m >= M) continue;
#pragma unroll
        for (int j = 0; j < 4; ++j) {
            int n = n0 + c0 + j;
            if (n >= N) continue;
            float v = acc[i][j] + (bias ? bias[n] : 0.f);
            if (relu) v = fmaxf(v, 0.f);
            C[(size_t)m * N + n] = v;
        }
    }
}

// fp32 [M][K] -> bf16 [Mp][ldk]; col K..ldk zero, except col 100 gets
// app[n] (if app) or 1.0 (if appone).
__global__ void convert_pad2(const float* __restrict__ src, u16* __restrict__ dst,
                             int M, int Mp, int K, int ldk,
                             const float* __restrict__ app, int appone)
{
    int t = blockIdx.x * blockDim.x + threadIdx.x;
    if (t >= Mp * ldk) return;
    int n = t / ldk, c = t - n * ldk;
    u16 o = 0;
    if (n < M) {
        if (c < K) o = f2bf(src[(size_t)n * K + c]);
        else if (c == 100) {
            if (app) o = f2bf(app[n]);
            else if (appone) o = 0x3F80;
        }
    }
    dst[t] = o;
}

// Batched GRU weight converts: 6 matrices -> gate-padded bf16 [336][128],
// pre-scaled by log2e (r,z) / 2log2e (n) for the exp2 combine path.
struct CvtgBatch {
    const float* src[6];
    const float* bias[6];
    u16*         dst[6];
};
#define CVTG_BLOCKS_PER_MAT 168   // 336*128/256
__global__ void convert_gru_w6(CvtgBatch B)
{
    int mat = blockIdx.x / CVTG_BLOCKS_PER_MAT;
    int t = (blockIdx.x - mat * CVTG_BLOCKS_PER_MAT) * blockDim.x + threadIdx.x;
    int rr = t >> 7, cc = t & 127;
    int g = rr / 112, r2 = rr - g * 112;
    u16 o = 0;
    if (r2 < 100) {
        float sc = (g == 2) ? LOG2E2 : LOG2E;
        int sr = g * 100 + r2;
        if (cc < 100) o = f2bf(B.src[mat][(size_t)sr * 100 + cc] * sc);
        else if (cc == 100) o = f2bf(B.bias[mat][sr] * sc);
    }
    B.dst[mat][t] = o;
}

// Wih0 -> [448][128] with row order (r,z,n,pad) per column, scaled; both
// branches in one launch.
__global__ void convert_ih0(const float* __restrict__ s0, const float* __restrict__ b0,
                            u16* __restrict__ d0,
                            const float* __restrict__ s1, const float* __restrict__ b1,
                            u16* __restrict__ d1)
{
    int t = blockIdx.x * blockDim.x + threadIdx.x;
    if (t >= 2 * 448 * 128) return;
    int which = t / (448 * 128);
    int tt = t - which * (448 * 128);
    const float* s = which ? s1 : s0;
    const float* b = which ? b1 : b0;
    u16* d = which ? d1 : d0;
    int j = tt >> 7, kc = tt & 127;
    int cc = j >> 2, g = j & 3;
    u16 o = 0;
    if (g < 3 && cc < 100) {
        float sc = (g == 2) ? LOG2E2 : LOG2E;
        int sr = g * 100 + cc;
        if (kc < 100) o = f2bf(s[(size_t)sr * 100 + kc] * sc);
        else if (kc == 100) o = f2bf(b[sr] * sc);
    }
    d[tt] = o;
}

// xg (bf16 [NG][128]) = concat(hg[:128], ue, hg[128:])
__global__ void build_xg_bf(const u16* __restrict__ hgb, const float* __restrict__ ue,
                            u16* __restrict__ xgb)
{
    int t = blockIdx.x * blockDim.x + threadIdx.x;
    if (t >= NG * 128) return;
    int n = t >> 7, c = t & 127;
    u16 o = 0;
    if (n < NB)           o = hgb[n * 128 + c];
    else if (n < NB + NU) { if (c < HD) o = f2bf(ue[(size_t)(n - NB) * HD + c]); }
    else                  o = hgb[(size_t)(n - NU) * 128 + c];
    xgb[t] = o;
}

__global__ void set_roots(const float* __restrict__ src, u16* __restrict__ hb)
{
    int t = blockIdx.x * blockDim.x + threadIdx.x;
    if (t >= NB * HD) return;
    int n = t / HD, c = t - n * HD;
    hb[(size_t)n * 128 + c] = f2bf(src[t]);
}

// ---------------------------------------------------------------------------
// CSR build — both graphs fused per phase
// ---------------------------------------------------------------------------
__global__ void csr_count2(const int* __restrict__ gei, const int* __restrict__ tei,
                           int* __restrict__ gcnt, int* __restrict__ tcnt)
{
    int e = blockIdx.x * blockDim.x + threadIdx.x;
    const int GE = EG + NG;
    if (e < GE) {
        int dst = (e < EG) ? gei[EG + e] : e - EG;
        atomicAdd(&gcnt[dst], 1);
    } else {
        int e2 = e - GE;
        if (e2 >= ET + NTREE) return;
        int dst = (e2 < ET) ? tei[ET + e2] : e2 - ET;
        atomicAdd(&tcnt[dst], 1);
    }
}

__global__ void csr_scan2(int* __restrict__ gcnt, int* __restrict__ goff, int* __restrict__ gcur,
                          int* __restrict__ tcnt, int* __restrict__ toff, int* __restrict__ tcur)
{
    const int* cnt = blockIdx.x ? tcnt : gcnt;
    int* off = blockIdx.x ? toff : goff;
    int* cur = blockIdx.x ? tcur : gcur;
    const int N = blockIdx.x ? NTREE : NG;
    __shared__ int part[256];
    const int tid = threadIdx.x;
    const int per = (N + 255) / 256;
    const int i0 = tid * per;
    const int i1 = min(i0 + per, N);
    int s = 0;
    for (int i = i0; i < i1; ++i) s += cnt[i];
    part[tid] = s;
    __syncthreads();
    for (int o = 1; o < 256; o <<= 1) {
        int u = (tid >= o) ? part[tid - o] : 0;
        __syncthreads();
        part[tid] += u;
        __syncthreads();
    }
    int base = part[tid] - s;
    for (int i = i0; i < i1; ++i) {
        off[i] = base; cur[i] = base;
        base += cnt[i];
    }
    if (tid == 255) off[N] = part[255];
}

__global__ void csr_scatter2(const int* __restrict__ gei, const int* __restrict__ tei,
                             int* __restrict__ gcur, int* __restrict__ tcur,
                             int* __restrict__ geidx, int* __restrict__ teidx)
{
    int e = blockIdx.x * blockDim.x + threadIdx.x;
    const int GE = EG + NG;
    if (e < GE) {
        int dst = (e < EG) ? gei[EG + e] : e - EG;
        int pos = atomicAdd(&gcur[dst], 1);
        geidx[pos] = e;
    } else {
        int e2 = e - GE;
        if (e2 >= ET + NTREE) return;
        int dst = (e2 < ET) ? tei[ET + e2] : e2 - ET;
        int pos = atomicAdd(&tcur[dst], 1);
        teidx[pos] = e2;
    }
}

// ---------------------------------------------------------------------------
// GAT pieces (feat is bf16)
// ---------------------------------------------------------------------------
__global__ void gat_es_ed(const u16* __restrict__ feat, const float* __restrict__ asrc,
                          const float* __restrict__ adst, float* __restrict__ es,
                          float* __restrict__ ed, int N, int heads, int C)
{
    int gid = blockIdx.x * blockDim.x + threadIdx.x;
    if (gid >= N * heads) return;
    int n = gid / heads, hd = gid - n * heads;
    const u16* hp = feat + ((size_t)n * heads + hd) * C;
    const float* as = asrc + (size_t)hd * C;
    const float* ad = adst + (size_t)hd * C;
    float s1 = 0.f, s2 = 0.f;
    for (int c = 0; c < C; c += 4) {
        uint2 pk = *(const uint2*)(hp + c);
        float v0 = bf2f((u16)(pk.x & 0xffff)), v1 = bf2f((u16)(pk.x >> 16));
        float v2 = bf2f((u16)(pk.y & 0xffff)), v3 = bf2f((u16)(pk.y >> 16));
        s1 += v0 * as[c] + v1 * as[c + 1] + v2 * as[c + 2] + v3 * as[c + 3];
        s2 += v0 * ad[c] + v1 * ad[c + 1] + v2 * ad[c + 2] + v3 * ad[c + 3];
    }
    es[gid] = s1; ed[gid] = s2;
}

// Per-dst CSR softmax: one wave per dst computes alpha for all its edges in
// three register passes (max / sum / write) — no atomics, no memsets.
template<int HEADS>
__global__ __launch_bounds__(256) void gat_alpha_csr(
    const int* __restrict__ off, const int* __restrict__ eidx,
    const int* __restrict__ ei, int E,
    const float* __restrict__ es, const float* __restrict__ ed,
    float* __restrict__ eb, int N)
{
    int gt = blockIdx.x * blockDim.x + threadIdx.x;
    int dst = gt >> 6, lane = gt & 63;
    if (dst >= N) return;
    const int hd  = lane & (HEADS - 1);
    const int esl = lane / HEADS;          // edge slot within iteration
    const int EPI = 64 / HEADS;
    const int e0 = off[dst], e1 = off[dst + 1];
    const float edv = ed[(size_t)dst * HEADS + hd];

    float mymax = -3.4e38f;
    for (int p0 = e0; p0 < e1; p0 += EPI) {
        int p = p0 + esl;
        if (p < e1) {
            int j = eidx[p];
            int src = (j < E) ? ei[j] : (j - E);
            float e = es[(size_t)src * HEADS + hd] + edv;
            e = e > 0.f ? e : 0.2f * e;
            mymax = fmaxf(mymax, e);
        }
    }
#pragma unroll
    for (int o = HEADS; o < 64; o <<= 1)
        mymax = fmaxf(mymax, __shfl_xor(mymax, o));

    float ssum = 0.f;
    for (int p0 = e0; p0 < e1; p0 += EPI) {
        int p = p0 + esl;
        if (p < e1) {
            int j = eidx[p];
            int src = (j < E) ? ei[j] : (j - E);
            float e = es[(size_t)src * HEADS + hd] + edv;
            e = e > 0.f ? e : 0.2f * e;
            ssum += __expf(e - mymax);
        }
    }
#pragma unroll
    for (int o = HEADS; o < 64; o <<= 1)
        ssum += __shfl_xor(ssum, o);
    float sinv = __fdividef(1.f, ssum);

    for (int p0 = e0; p0 < e1; p0 += EPI) {
        int p = p0 + esl;
        if (p < e1) {
            int j = eidx[p];
            int src = (j < E) ? ei[j] : (j - E);
            float e = es[(size_t)src * HEADS + hd] + edv;
            e = e > 0.f ? e : 0.2f * e;
            eb[(size_t)j * HEADS + hd] = __expf(e - mymax) * sinv;
        }
    }
}

// accum: eb holds alpha (pre-normalized) — no s read, no divide.
template<int C, int VEC>
__global__ __launch_bounds__(256) void gat_accum_csr(
    const int* __restrict__ off, const int* __restrict__ eidx,
    const int* __restrict__ ei, int E,
    const float* __restrict__ eb,
    const u16* __restrict__ feat, const float* __restrict__ bias,
    float* __restrict__ outf, u16* __restrict__ outb,
    int N, int heads, int HC, int nchunk)
{
    int gt = blockIdx.x * blockDim.x + threadIdx.x;
    int w = gt >> 6, lane = gt & 63;
    int dst = w / nchunk, chunk = w - dst * nchunk;
    if (dst >= N) return;
    int c0 = chunk * 64 * VEC + lane * VEC;
    if (c0 >= HC) return;
    int hh[VEC]; float acc[VEC];
#pragma unroll
    for (int v = 0; v < VEC; ++v) {
        int c = c0 + v;
        hh[v] = c / C;
        acc[v] = 0.f;
    }
    int e0 = off[dst], e1 = off[dst + 1];
    for (int p = e0; p < e1; ++p) {
        int j = eidx[p];
        int src = (j < E) ? ei[j] : (j - E);
        const u16* frp = feat + (size_t)src * HC + c0;
        float fv[VEC];
        if (VEC == 8) {
            uint4 pk = *(const uint4*)frp;
            fv[0] = bf2f((u16)(pk.x & 0xffff)); fv[1] = bf2f((u16)(pk.x >> 16));
            fv[2] = bf2f((u16)(pk.y & 0xffff)); fv[3] = bf2f((u16)(pk.y >> 16));
            fv[4] = bf2f((u16)(pk.z & 0xffff)); fv[5] = bf2f((u16)(pk.z >> 16));
            fv[6] = bf2f((u16)(pk.w & 0xffff)); fv[7] = bf2f((u16)(pk.w >> 16));
        } else if (VEC == 4) {
            uint2 pk = *(const uint2*)frp;
            fv[0] = bf2f((u16)(pk.x & 0xffff)); fv[1] = bf2f((u16)(pk.x >> 16));
            fv[2] = bf2f((u16)(pk.y & 0xffff)); fv[3] = bf2f((u16)(pk.y >> 16));
        } else {
            u32 pk = *(const u32*)frp;
            fv[0] = bf2f((u16)(pk & 0xffff)); fv[1] = bf2f((u16)(pk >> 16));
        }
#pragma unroll
        for (int v = 0; v < VEC; ++v)
            acc[v] += fv[v] * eb[(size_t)j * heads + hh[v]];
    }
#pragma unroll
    for (int v = 0; v < VEC; ++v) {
        int c = c0 + v;
        if (c >= HC) continue;
        float o = fmaxf(acc[v] + bias[c], 0.f);
        if (outf) outf[(size_t)dst * HC + c] = o;
        if (outb) outb[(size_t)dst * HC + c] = f2bf(o);
    }
}

__global__ void scatter_mean_accum(const float* __restrict__ x, const int* __restrict__ idx,
                                   float* __restrict__ ssum, float* __restrict__ cnt)
{
    int t = blockIdx.x * blockDim.x + threadIdx.x;
    if (t >= NTREE * HD) return;
    int n = t / HD, c = t - n * HD;
    int b = idx[n];
    atomicAdd(&ssum[b * HD + c], x[t]);
    if (c == 0) atomicAdd(&cnt[b], 1.f);
}

__global__ void fc_out(const float* __restrict__ ssum, const float* __restrict__ cnt,
                       const float* __restrict__ W, const float* __restrict__ b,
                       float* __restrict__ out)
{
    int t = threadIdx.x;                 // 512 threads
    int bb = t >> 2, j = t & 3;
    float inv = __fdividef(1.f, fmaxf(cnt[bb], 1.f));
    float acc = b[j];
    for (int k = 0; k < HD; ++k) acc += ssum[bb * HD + k] * inv * W[j * HD + k];
    out[t] = acc;
}

// ---------------------------------------------------------------------------
// Host launcher
// ---------------------------------------------------------------------------
extern "C" void kernel_launch(void* const* d_in, const int* in_sizes, int n_in,
                              void* d_out, int out_size, void* d_ws, size_t ws_size,
                              hipStream_t stream)
{
    const float* user_feats = (const float*)d_in[1];
    const int*   gnf        = (const int*)d_in[2];
    const int*   gei        = (const int*)d_in[3];
    const int*   tnf        = (const int*)d_in[4];
    const int*   tei        = (const int*)d_in[5];
    const int*   indices    = (const int*)d_in[6];
    const float* h0g        = (const float*)d_in[7];
    const float* h0t        = (const float*)d_in[8];
    const float* temb       = (const float*)d_in[9];
    const float* gW[2][4] = {{(const float*)d_in[10], (const float*)d_in[11], (const float*)d_in[12], (const float*)d_in[13]},
                             {(const float*)d_in[14], (const float*)d_in[15], (const float*)d_in[16], (const float*)d_in[17]}};
    const float* tW[2][4] = {{(const float*)d_in[18], (const float*)d_in[19], (const float*)d_in[20], (const float*)d_in[21]},
                             {(const float*)d_in[22], (const float*)d_in[23], (const float*)d_in[24], (const float*)d_in[25]}};
    const float* uW1 = (const float*)d_in[26]; const float* ub1 = (const float*)d_in[27];
    const float* uW2 = (const float*)d_in[28]; const float* ub2 = (const float*)d_in[29];
    const float* gc1W = (const float*)d_in[30]; const float* gc1as = (const float*)d_in[31];
    const float* gc1ad = (const float*)d_in[32]; const float* gc1b = (const float*)d_in[33];
    const float* gc2W = (const float*)d_in[34]; const float* gc2as = (const float*)d_in[35];
    const float* gc2ad = (const float*)d_in[36]; const float* gc2b = (const float*)d_in[37];
    const float* tc1W = (const float*)d_in[38]; const float* tc1as = (const float*)d_in[39];
    const float* tc1ad = (const float*)d_in[40]; const float* tc1b = (const float*)d_in[41];
    const float* tc2W = (const float*)d_in[42]; const float* tc2as = (const float*)d_in[43];
    const float* tc2ad = (const float*)d_in[44]; const float* tc2b = (const float*)d_in[45];
    const float* fcW = (const float*)d_in[46]; const float* fcb = (const float*)d_in[47];
    float* out = (float*)d_out;

    char* ws = (char*)d_ws;
    const size_t NEED = 226500000;
    if (ws_size < NEED) return;

    // ---- workspace layout (decimal byte offsets, overlays noted) ----
    float* XGF    = (float*)(ws + 0);            // 12 MB [NG][100] fp32
    u16*   TEMB_B = (u16*)(ws + 12000000);       // 12.8 MB [VOC][128]
    u16*   ETAB_G = (u16*)(ws + 25000000);       // 44.8 MB [VOC][448] interleaved
    u16*   ETAB_T = (u16*)(ws + 70000000);       // 44.8 MB -> 114.8
    u16*   GH1B   = (u16*)(ws + 115000000);      // 2.56 MB [NTG][128]
    u16*   TH1B   = (u16*)(ws + 117600000);      // 7.68 MB [NTREE][128]
    float* UE     = (float*)(ws + 125300000);    // 8 MB
    float* HID    = (float*)(ws + 133400000);    // 8 MB
    u16*   WARENA = (u16*)(ws + 141500000);      // 1.11 MB weight arena
    int*   GOFF   = (int*)(ws + 142700000);
    int*   GCUR   = (int*)(ws + 142900000);
    int*   GCNT   = (int*)(ws + 143100000);      // NG ints
    int*   TCNT   = (int*)(ws + 143220000);      // NTREE ints (adjacent: 1 memset)
    int*   GEIDX  = (int*)(ws + 143400000);      // 0.92 MB
    int*   TOFF   = (int*)(ws + 144400000);
    int*   TCUR   = (int*)(ws + 144600000);
    int*   TEIDX  = (int*)(ws + 144800000);      // 0.36 MB
    float* ESB    = (float*)(ws + 145300000);
    float* EDB    = (float*)(ws + 146300000);
    float* EBB    = (float*)(ws + 149300000);    // 7.36 MB (alpha per edge-head)
    float* SSUM   = (float*)(ws + 156700000);
    float* SCNT   = (float*)(ws + 156800000);
    u16*   XG_B   = (u16*)(ws + 157000000);      // 7.68 MB [NG][128]
    u16*   GFEAT1 = (u16*)(ws + 165000000);      // 30.72 MB [NG][512] -> 195.72
    // overlays (regions dead by the time they're written):
    u16*   GOUT1B = (u16*)(ws + 25000000);       // 30.72 MB (over ETAB_G, dead after GRU)
    u16*   GFEAT2 = (u16*)(ws + 56000000);       // 6 MB [NG][100]
    u16*   TFEAT1 = (u16*)(ws + 25000000);       // 48 MB [NTREE][800] (after graph GATs)
    u16*   TOUT1B = (u16*)(ws + 74000000);       // 48 MB (over ETAB_T/GH1B tail, dead)
    u16*   TFEAT2 = (u16*)(ws + 123000000);      // 6 MB (over TH1B-tail/UE, dead)
    float* XOUT2  = (float*)(ws + 157000000);    // 12 MB (over XG_B/GFEAT1-head, dead)

    // weight arena slots (u16 element offsets)
    u16* gWHH0  = WARENA + 0;        // 6 x [336][128]
    u16* gWIH1  = WARENA + 43008;
    u16* gWHH1  = WARENA + 86016;
    u16* tWHH0  = WARENA + 129024;
    u16* tWIH1  = WARENA + 172032;
    u16* tWHH1  = WARENA + 215040;
    u16* W_IH0A = WARENA + 258048;   // [448][128] interleaved-row Etab weights
    u16* W_IH0B = WARENA + 315392;
    u16* W_G1   = WARENA + 372736;   // up to [800][128]
    u16* W_G2   = WARENA + 475136;   // up to [100][800]

    auto cvt = [&](const float* src, u16* dst, int M, int Mp, int K, int ldk,
                   const float* app = nullptr, int appone = 0) {
        convert_pad2<<<((size_t)Mp * ldk + 255) / 256, 256, 0, stream>>>(
            src, dst, M, Mp, K, ldk, app, appone);
    };
    auto mfma = [&](const u16* A, int lda, const u16* W, int ldw,
                    float* Cf, u16* Cb, int ldc, int M, int N, int Kt) {
        dim3 grid((M + 63) / 64, (N + 63) / 64, 1);
        gemm_mfma<<<grid, 256, 0, stream>>>(A, W, Cf, Cb, M, N, Kt, lda, ldw, ldc);
    };

    // ---- 1. user embed (fp32) ----
    {
        dim3 g1((NU + 63) / 64, (HD + 63) / 64, 1);
        gemm_nt<<<g1, 256, 0, stream>>>(user_feats, uW1, ub1, HID, NU, HD, 9, 1);
        gemm_nt<<<g1, 256, 0, stream>>>(HID, uW2, ub2, UE, NU, HD, HD, 0);
    }

    // ---- 2. converts (scaled) + fused Etab build ----
    cvt(temb, TEMB_B, VOC, VOC, HD, 128, nullptr, 1);           // col100 = 1
    {
        CvtgBatch B;
        B.src[0] = gW[0][1]; B.bias[0] = gW[0][3]; B.dst[0] = gWHH0;
        B.src[1] = gW[1][0]; B.bias[1] = gW[1][2]; B.dst[1] = gWIH1;
        B.src[2] = gW[1][1]; B.bias[2] = gW[1][3]; B.dst[2] = gWHH1;
        B.src[3] = tW[0][1]; B.bias[3] = tW[0][3]; B.dst[3] = tWHH0;
        B.src[4] = tW[1][0]; B.bias[4] = tW[1][2]; B.dst[4] = tWIH1;
        B.src[5] = tW[1][1]; B.bias[5] = tW[1][3]; B.dst[5] = tWHH1;
        convert_gru_w6<<<6 * CVTG_BLOCKS_PER_MAT, 256, 0, stream>>>(B);
    }
    convert_ih0<<<(2 * 448 * 128 + 255) / 256, 256, 0, stream>>>(
        gW[0][0], gW[0][2], W_IH0A, tW[0][0], tW[0][2], W_IH0B);
    {
        dim3 ge((VOC + 63) / 64, 7, 2);
        gemm_etab<<<ge, 256, 0, stream>>>(TEMB_B, W_IH0A, W_IH0B, ETAB_G, ETAB_T);
    }

    // ---- CSR (both graphs, fused phases) ----
    hipMemsetAsync(GCNT, 0, 143400000 - 143100000, stream);   // GCNT + TCNT
    {
        int tot = (EG + NG) + (ET + NTREE);
        csr_count2<<<(tot + 255) / 256, 256, 0, stream>>>(gei, tei, GCNT, TCNT);
        csr_scan2<<<2, 256, 0, stream>>>(GCNT, GOFF, GCUR, TCNT, TOFF, TCUR);
        csr_scatter2<<<(tot + 255) / 256, 256, 0, stream>>>(gei, tei, GCUR, TCUR, GEIDX, TEIDX);
    }

    // ---- 3. combined GRU (both branches, one launch, 32 rows/block) ----
    {
        GruProb Pg = { ETAB_G, gnf, h0g, gWHH0, gWIH1, gWHH1, GH1B, NTG };
        GruProb Pt = { ETAB_T, tnf, h0t, tWHH0, tWIH1, tWHH1, TH1B, NTREE };
        int gblk = (NTG + 31) / 32;      // 313
        int tblk = (NTREE + 31) / 32;    // 938
        gru_fused10<<<gblk + tblk, 448, 0, stream>>>(Pg, Pt, gblk);
    }

    // ---- 4. graph GAT chain ----
    build_xg_bf<<<(NG * 128 + 255) / 256, 256, 0, stream>>>(GH1B, UE, XG_B);
    cvt(gc1W, W_G1, 512, 512, HD, 128);
    cvt(gc2W, W_G2, 100, 100, 512, 512);
    {   // graph GAT1: 8 heads x 64
        mfma(XG_B, 128, W_G1, 128, nullptr, GFEAT1, 512, NG, 512, 4);
        gat_es_ed<<<(NG * 8 + 255) / 256, 256, 0, stream>>>(GFEAT1, gc1as, gc1ad, ESB, EDB, NG, 8, 64);
        gat_alpha_csr<8><<<(NG + 3) / 4, 256, 0, stream>>>(GOFF, GEIDX, gei, EG, ESB, EDB, EBB, NG);
        gat_accum_csr<64, 8><<<(NG + 3) / 4, 256, 0, stream>>>(
            GOFF, GEIDX, gei, EG, EBB, GFEAT1, gc1b, nullptr, GOUT1B, NG, 8, 512, 1);
    }
    {   // graph GAT2: 1 head x 100
        mfma(GOUT1B, 512, W_G2, 512, nullptr, GFEAT2, 100, NG, 100, 16);
        gat_es_ed<<<(NG + 255) / 256, 256, 0, stream>>>(GFEAT2, gc2as, gc2ad, ESB, EDB, NG, 1, 100);
        gat_alpha_csr<1><<<(NG + 3) / 4, 256, 0, stream>>>(GOFF, GEIDX, gei, EG, ESB, EDB, EBB, NG);
        gat_accum_csr<100, 2><<<(NG + 3) / 4, 256, 0, stream>>>(
            GOFF, GEIDX, gei, EG, EBB, GFEAT2, gc2b, XGF, nullptr, NG, 1, 100, 1);
    }

    // ---- 5. tree GAT chain ----
    set_roots<<<(NB * HD + 255) / 256, 256, 0, stream>>>(XGF, TH1B);
    cvt(tc1W, W_G1, 800, 800, HD, 128);
    cvt(tc2W, W_G2, 100, 100, 800, 800);
    {   // tree GAT1: 8 heads x 100
        mfma(TH1B, 128, W_G1, 128, nullptr, TFEAT1, 800, NTREE, 800, 4);
        gat_es_ed<<<(NTREE * 8 + 255) / 256, 256, 0, stream>>>(TFEAT1, tc1as, tc1ad, ESB, EDB, NTREE, 8, 100);
        gat_alpha_csr<8><<<(NTREE + 3) / 4, 256, 0, stream>>>(TOFF, TEIDX, tei, ET, ESB, EDB, EBB, NTREE);
        gat_accum_csr<100, 8><<<(NTREE * 2 + 3) / 4, 256, 0, stream>>>(
            TOFF, TEIDX, tei, ET, EBB, TFEAT1, tc1b, nullptr, TOUT1B, NTREE, 8, 800, 2);
    }
    {   // tree GAT2: 1 head x 100
        mfma(TOUT1B, 800, W_G2, 800, nullptr, TFEAT2, 100, NTREE, 100, 25);
        gat_es_ed<<<(NTREE + 255) / 256, 256, 0, stream>>>(TFEAT2, tc2as, tc2ad, ESB, EDB, NTREE, 1, 100);
        gat_alpha_csr<1><<<(NTREE + 3) / 4, 256, 0, stream>>>(TOFF, TEIDX, tei, ET, ESB, EDB, EBB, NTREE);
        gat_accum_csr<100, 2><<<(NTREE + 3) / 4, 256, 0, stream>>>(
            TOFF, TEIDX, tei, ET, EBB, TFEAT2, tc2b, XOUT2, nullptr, NTREE, 1, 100, 1);
    }

    // ---- 6. scatter_mean + classifier ----
    hipMemsetAsync(SSUM, 0, (size_t)NB * HD * 4, stream);
    hipMemsetAsync(SCNT, 0, (size_t)NB * 4, stream);
    scatter_mean_accum<<<(NTREE * HD + 255) / 256, 256, 0, stream>>>(XOUT2, indices, SSUM, SCNT);
    fc_out<<<1, 512, 0, stream>>>(SSUM, SCNT, fcW, fcb, out);
}

// Round 8
// 1440.350 us; speedup vs baseline: 1.2636x; 1.0312x over previous
//
#include <hip/hip_runtime.h>

// ---------------------------------------------------------------------------
// Problem constants
// ---------------------------------------------------------------------------
#define NB    128
#define HD    100
#define NU    20000
#define NTG   10000
#define NTREE 30000
#define NG    30000
#define TT    20
#define EG    200000
#define ET    60000
#define VOC   50000

#define ESTR2 448   // interleaved Etab row stride in u16: [112 cols][4] (r,z,n,pad)
#define LOG2E  1.4426950408889634f
#define LOG2E2 2.8853900817779268f

typedef unsigned short u16;
typedef unsigned int   u32;
typedef __attribute__((ext_vector_type(8))) short short8;
typedef __attribute__((ext_vector_type(4))) float floatx4;

// gate pre-activations arrive PRE-SCALED by log2e (r,z) / 2log2e (n)
__device__ __forceinline__ float sigmoid2_(float y) {
    return __fdividef(1.f, 1.f + __builtin_amdgcn_exp2f(-y));
}
__device__ __forceinline__ float tanh2_(float y) {
    return 1.f - __fdividef(2.f, __builtin_amdgcn_exp2f(y) + 1.f);
}
__device__ __forceinline__ u16 f2bf(float f) {
    u32 u = __float_as_uint(f);
    u32 r = (u + 0x7fffu + ((u >> 16) & 1u)) >> 16;
    return (u16)r;
}
__device__ __forceinline__ u16 f2bf_c(float f) {
    u32 r;
    asm("v_cvt_pk_bf16_f32 %0, %1, %2" : "=v"(r) : "v"(f), "v"(f));
    return (u16)r;
}
__device__ __forceinline__ float bf2f(u16 h) {
    return __uint_as_float(((u32)h) << 16);
}

// ---------------------------------------------------------------------------
// Fused 2-layer GRU v10 (PROVEN 588-592 µs): 448 threads (7 waves) / 32 rows.
// 64-row variant spills (state + 144 weight regs > 256 budget) — do not retry.
// ---------------------------------------------------------------------------
struct GruProb {
    const u16*   Etab;     // [VOC][112][4] interleaved, pre-scaled
    const int*   nodes;    // [M][TT]
    const float* h0;       // [2][M][100] fp32
    const u16*   Whh0;     // [336][128] gate-padded, scaled (col100 = bhh0)
    const u16*   Wih1;
    const u16*   Whh1;
    u16*         hout;     // [M][128]
    int          M;
};

__global__ __launch_bounds__(448, 2) void gru_fused10(GruProb Pg, GruProb Pt, int gblocks)
{
    const bool isg = (int)blockIdx.x < gblocks;
    const GruProb P = isg ? Pg : Pt;
    const int bx = isg ? blockIdx.x : blockIdx.x - gblocks;
    const int M  = P.M;
    const int m0 = bx * 32;

    __shared__ u16 H0[2][32 * 128];
    __shared__ u16 H1[2][32 * 128];
    __shared__ int NID[TT * 32];

    const int tid  = threadIdx.x;
    const int w    = tid >> 6, lane = tid & 63;
    const int fr   = lane & 15, quad = lane >> 4;
    const int c    = w * 16 + fr;
    const bool cok = (c < HD);

    short8 Bh0[3][4], Bx1[3][4], Bh1[3][4];
#pragma unroll
    for (int g = 0; g < 3; ++g) {
        const size_t rb = (size_t)((g * 7 + w) * 16 + fr) * 128 + quad * 8;
#pragma unroll
        for (int kk = 0; kk < 4; ++kk) {
            Bh0[g][kk] = *(const short8*)(P.Whh0 + rb + kk * 32);
            Bx1[g][kk] = *(const short8*)(P.Wih1 + rb + kk * 32);
            Bh1[g][kk] = *(const short8*)(P.Whh1 + rb + kk * 32);
        }
    }

    for (int i = tid; i < 32 * 128; i += 448) {
        H0[0][i] = 0; H0[1][i] = 0; H1[0][i] = 0; H1[1][i] = 0;
    }
    for (int i = tid; i < 32 * TT; i += 448) {
        int row = i / TT, t = i - row * TT;
        int gm = m0 + row;
        NID[t * 32 + row] = (gm < M) ? P.nodes[(size_t)gm * TT + t] : 0;
    }
    __syncthreads();
    if (tid < 32) {
        int off = 200 ^ ((tid & 7) << 4);
        *(u16*)((char*)&H0[0][0] + tid * 256 + off) = 0x3F80;
        *(u16*)((char*)&H0[1][0] + tid * 256 + off) = 0x3F80;
        *(u16*)((char*)&H1[0][0] + tid * 256 + off) = 0x3F80;
        *(u16*)((char*)&H1[1][0] + tid * 256 + off) = 0x3F80;
    }

    float h0f[2][4] = {{0.f,0.f,0.f,0.f},{0.f,0.f,0.f,0.f}};
    float h1f[2][4] = {{0.f,0.f,0.f,0.f},{0.f,0.f,0.f,0.f}};
    if (cok) {
#pragma unroll
        for (int rt = 0; rt < 2; ++rt)
#pragma unroll
        for (int r = 0; r < 4; ++r) {
            int row = rt * 16 + quad * 4 + r;
            int gm  = m0 + row;
            float v0 = 0.f, v1 = 0.f;
            if (gm < M) {
                v0 = P.h0[(size_t)gm * HD + c];
                v1 = P.h0[(size_t)(M + gm) * HD + c];
            }
            h0f[rt][r] = v0; h1f[rt][r] = v1;
            int off = (2 * c) ^ ((row & 7) << 4);
            *(u16*)((char*)&H0[0][0] + row * 256 + off) = f2bf_c(v0);
            *(u16*)((char*)&H1[0][0] + row * 256 + off) = f2bf_c(v1);
        }
    }

    u32 xlo[2][4], xhi[2][4];
    auto xpref = [&](int tn) {
        if (cok) {
#pragma unroll
            for (int rt = 0; rt < 2; ++rt)
#pragma unroll
            for (int r = 0; r < 4; ++r) {
                int row = rt * 16 + quad * 4 + r;
                int nd  = NID[tn * 32 + row];
                uint2 v = *(const uint2*)(P.Etab + (size_t)nd * ESTR2 + c * 4);
                xlo[rt][r] = v.x; xhi[rt][r] = v.y;
            }
        }
    };
    __syncthreads();
    xpref(0);

    // ---- prologue: A(0) ----
#pragma unroll
    for (int rt = 0; rt < 2; ++rt) {
        short8 a[4];
#pragma unroll
        for (int kk = 0; kk < 4; ++kk) {
            int row = rt * 16 + fr;
            int off = (kk * 64 + quad * 16) ^ ((row & 7) << 4);
            a[kk] = *(const short8*)((const char*)&H0[0][0] + row * 256 + off);
        }
        floatx4 ag[3];
#pragma unroll
        for (int g = 0; g < 3; ++g) ag[g] = (floatx4){0.f, 0.f, 0.f, 0.f};
#pragma unroll
        for (int g = 0; g < 3; ++g)
#pragma unroll
            for (int kk = 0; kk < 4; ++kk)
                ag[g] = __builtin_amdgcn_mfma_f32_16x16x32_bf16(a[kk], Bh0[g][kk], ag[g], 0, 0, 0);
        if (cok) {
#pragma unroll
            for (int r = 0; r < 4; ++r) {
                int row = rt * 16 + quad * 4 + r;
                float rr = sigmoid2_(bf2f((u16)xlo[rt][r]) + ag[0][r]);
                float zz = sigmoid2_(bf2f((u16)(xlo[rt][r] >> 16)) + ag[1][r]);
                float nn = tanh2_(bf2f((u16)xhi[rt][r]) + rr * ag[2][r]);
                float o  = nn + zz * (h0f[rt][r] - nn);
                h0f[rt][r] = o;
                *(u16*)((char*)&H0[1][0] + row * 256 + ((2 * c) ^ ((row & 7) << 4))) = f2bf_c(o);
            }
        }
    }
    __syncthreads();

    // ---- regions r = 0..TT-1: B(r) + A(r+1) ----
    for (int r = 0; r < TT; ++r) {
        const bool doA = (r + 1 < TT);
        if (doA) xpref(r + 1);

        const char* rd0 = (const char*)&H0[(r + 1) & 1][0];
        const char* rd1 = (const char*)&H1[r & 1][0];
        char*       wr0 = (char*)&H0[r & 1][0];
        char*       wr1 = (char*)&H1[(r + 1) & 1][0];

#pragma unroll
        for (int rt = 0; rt < 2; ++rt) {
            short8 a0[4], a1[4];
#pragma unroll
            for (int kk = 0; kk < 4; ++kk) {
                int row = rt * 16 + fr;
                int off = (kk * 64 + quad * 16) ^ ((row & 7) << 4);
                a0[kk] = *(const short8*)(rd0 + row * 256 + off);
                a1[kk] = *(const short8*)(rd1 + row * 256 + off);
            }
            floatx4 rz0 = {0.f,0.f,0.f,0.f}, rz1 = {0.f,0.f,0.f,0.f};
            floatx4 xnv = {0.f,0.f,0.f,0.f}, hnv = {0.f,0.f,0.f,0.f};
#pragma unroll
            for (int kk = 0; kk < 4; ++kk)
                rz0 = __builtin_amdgcn_mfma_f32_16x16x32_bf16(a0[kk], Bx1[0][kk], rz0, 0, 0, 0);
#pragma unroll
            for (int kk = 0; kk < 4; ++kk)
                rz0 = __builtin_amdgcn_mfma_f32_16x16x32_bf16(a1[kk], Bh1[0][kk], rz0, 0, 0, 0);
#pragma unroll
            for (int kk = 0; kk < 4; ++kk)
                rz1 = __builtin_amdgcn_mfma_f32_16x16x32_bf16(a0[kk], Bx1[1][kk], rz1, 0, 0, 0);
#pragma unroll
            for (int kk = 0; kk < 4; ++kk)
                rz1 = __builtin_amdgcn_mfma_f32_16x16x32_bf16(a1[kk], Bh1[1][kk], rz1, 0, 0, 0);
#pragma unroll
            for (int kk = 0; kk < 4; ++kk)
                xnv = __builtin_amdgcn_mfma_f32_16x16x32_bf16(a0[kk], Bx1[2][kk], xnv, 0, 0, 0);
#pragma unroll
            for (int kk = 0; kk < 4; ++kk)
                hnv = __builtin_amdgcn_mfma_f32_16x16x32_bf16(a1[kk], Bh1[2][kk], hnv, 0, 0, 0);
            floatx4 ag[3];
#pragma unroll
            for (int g = 0; g < 3; ++g) ag[g] = (floatx4){0.f, 0.f, 0.f, 0.f};
            if (doA) {
#pragma unroll
                for (int g = 0; g < 3; ++g)
#pragma unroll
                    for (int kk = 0; kk < 4; ++kk)
                        ag[g] = __builtin_amdgcn_mfma_f32_16x16x32_bf16(a0[kk], Bh0[g][kk], ag[g], 0, 0, 0);
            }
            if (cok) {
#pragma unroll
                for (int r4 = 0; r4 < 4; ++r4) {
                    int row = rt * 16 + quad * 4 + r4;
                    float rr = sigmoid2_(rz0[r4]);
                    float zz = sigmoid2_(rz1[r4]);
                    float nn = tanh2_(xnv[r4] + rr * hnv[r4]);
                    float o  = nn + zz * (h1f[rt][r4] - nn);
                    h1f[rt][r4] = o;
                    *(u16*)(wr1 + row * 256 + ((2 * c) ^ ((row & 7) << 4))) = f2bf_c(o);
                }
                if (doA) {
#pragma unroll
                    for (int r4 = 0; r4 < 4; ++r4) {
                        int row = rt * 16 + quad * 4 + r4;
                        float rr = sigmoid2_(bf2f((u16)xlo[rt][r4]) + ag[0][r4]);
                        float zz = sigmoid2_(bf2f((u16)(xlo[rt][r4] >> 16)) + ag[1][r4]);
                        float nn = tanh2_(bf2f((u16)xhi[rt][r4]) + rr * ag[2][r4]);
                        float o  = nn + zz * (h0f[rt][r4] - nn);
                        h0f[rt][r4] = o;
                        *(u16*)(wr0 + row * 256 + ((2 * c) ^ ((row & 7) << 4))) = f2bf_c(o);
                    }
                }
            }
        }
        __syncthreads();
    }

    for (int i = tid; i < 32 * 128; i += 448) {
        int row = i >> 7, cc = i & 127;
        int gm = m0 + row;
        if (gm < M) {
            int off = (2 * cc) ^ ((row & 7) << 4);
            P.hout[(size_t)gm * 128 + cc] = *(const u16*)((const char*)&H1[0][0] + row * 256 + off);
        }
    }
}

// ---------------------------------------------------------------------------
// bf16 MFMA GEMM (GAT feature GEMMs)
// ---------------------------------------------------------------------------
#define LDST 40
__global__ __launch_bounds__(256) void gemm_mfma(
    const u16* __restrict__ A, const u16* __restrict__ B,
    float* __restrict__ Cf, u16* __restrict__ Cb,
    int M, int N, int Kt, int lda, int ldw, int ldc)
{
    const int m0 = blockIdx.x * 64;
    if (m0 >= M) return;
    const int n0 = blockIdx.y * 64;

    __shared__ u16 Als[64 * LDST];
    __shared__ u16 Wls[64 * LDST];

    const int tid  = threadIdx.x;
    const int wave = tid >> 6, lane = tid & 63;
    const int row  = tid >> 2, part = (tid & 3) * 8;
    const int fr   = lane & 15, quad = lane >> 4;

    floatx4 acc[4];
#pragma unroll
    for (int t = 0; t < 4; ++t) acc[t] = (floatx4){0.f, 0.f, 0.f, 0.f};

    const int am = m0 + row;  const bool aok = am < M;
    const int wn = n0 + row;  const bool wok = wn < N;
    const uint4 z4 = {0u, 0u, 0u, 0u};

    for (int kk = 0; kk < Kt; ++kk) {
        uint4 av = aok ? *(const uint4*)(A + (size_t)am * lda + kk * 32 + part) : z4;
        uint4 wv = wok ? *(const uint4*)(B + (size_t)wn * ldw + kk * 32 + part) : z4;
        __syncthreads();
        *(uint4*)&Als[row * LDST + part] = av;
        *(uint4*)&Wls[row * LDST + part] = wv;
        __syncthreads();
        short8 af = *(const short8*)&Als[((wave << 4) + fr) * LDST + quad * 8];
#pragma unroll
        for (int t = 0; t < 4; ++t) {
            short8 bf = *(const short8*)&Wls[((t << 4) + fr) * LDST + quad * 8];
            acc[t] = __builtin_amdgcn_mfma_f32_16x16x32_bf16(af, bf, acc[t], 0, 0, 0);
        }
    }

    const int orow0 = m0 + (wave << 4) + quad * 4;
#pragma unroll
    for (int t = 0; t < 4; ++t) {
        int col = n0 + (t << 4) + fr;
        if (col >= N) continue;
#pragma unroll
        for (int r = 0; r < 4; ++r) {
            int mr = orow0 + r;
            if (mr >= M) continue;
            float v = acc[t][r];
            if (Cf) Cf[(size_t)mr * ldc + col] = v;
            if (Cb) Cb[(size_t)mr * ldc + col] = f2bf(v);
        }
    }
}

// Dual Etab build: z selects (W,C). W rows pre-ordered (r,z,n,pad)-interleaved.
__global__ __launch_bounds__(256) void gemm_etab(
    const u16* __restrict__ A, const u16* __restrict__ W0, const u16* __restrict__ W1,
    u16* __restrict__ C0, u16* __restrict__ C1)
{
    const int m0 = blockIdx.x * 64;
    const int n0 = blockIdx.y * 64;
    const u16* B = blockIdx.z ? W1 : W0;
    u16* Cb = blockIdx.z ? C1 : C0;
    const int N = 400;

    __shared__ u16 Als[64 * LDST];
    __shared__ u16 Wls[64 * LDST];

    const int tid  = threadIdx.x;
    const int wave = tid >> 6, lane = tid & 63;
    const int row  = tid >> 2, part = (tid & 3) * 8;
    const int fr   = lane & 15, quad = lane >> 4;

    floatx4 acc[4];
#pragma unroll
    for (int t = 0; t < 4; ++t) acc[t] = (floatx4){0.f, 0.f, 0.f, 0.f};

    const int am = m0 + row;
    const int wn = n0 + row;  const bool wok = wn < N;
    const uint4 z4 = {0u, 0u, 0u, 0u};

    for (int kk = 0; kk < 4; ++kk) {
        uint4 av = *(const uint4*)(A + (size_t)am * 128 + kk * 32 + part);
        uint4 wv = wok ? *(const uint4*)(B + (size_t)wn * 128 + kk * 32 + part) : z4;
        __syncthreads();
        *(uint4*)&Als[row * LDST + part] = av;
        *(uint4*)&Wls[row * LDST + part] = wv;
        __syncthreads();
        short8 af = *(const short8*)&Als[((wave << 4) + fr) * LDST + quad * 8];
#pragma unroll
        for (int t = 0; t < 4; ++t) {
            short8 bf = *(const short8*)&Wls[((t << 4) + fr) * LDST + quad * 8];
            acc[t] = __builtin_amdgcn_mfma_f32_16x16x32_bf16(af, bf, acc[t], 0, 0, 0);
        }
    }

    const int orow0 = m0 + (wave << 4) + quad * 4;
#pragma unroll
    for (int t = 0; t < 4; ++t) {
        int col = n0 + (t << 4) + fr;
        if (col >= N) continue;
#pragma unroll
        for (int r = 0; r < 4; ++r)
            Cb[(size_t)(orow0 + r) * ESTR2 + col] = f2bf(acc[t][r]);
    }
}

// ---------------------------------------------------------------------------
// fp32 tiled GEMM (user-embed MLP only)
// ---------------------------------------------------------------------------
__global__ __launch_bounds__(256) void gemm_nt(
    const float* __restrict__ A, const float* __restrict__ W,
    const float* __restrict__ bias, float* __restrict__ C,
    int M, int N, int K, int relu)
{
    const int m0 = blockIdx.x * 64;
    const int n0 = blockIdx.y * 64;
    __shared__ float As[20][68];
    __shared__ float Ws[20][68];
    const int tid = threadIdx.x;
    const int r0 = (tid >> 4) * 4;
    const int c0 = (tid & 15) * 4;
    int sr[5], sk[5];
#pragma unroll
    for (int it = 0; it < 5; ++it) {
        int idx = tid + it * 256;
        sr[it] = idx / 20; sk[it] = idx - sr[it] * 20;
    }
    float acc[4][4];
#pragma unroll
    for (int i = 0; i < 4; ++i)
#pragma unroll
        for (int j = 0; j < 4; ++j) acc[i][j] = 0.f;
    const int nch = (K + 19) / 20;
    for (int ch = 0; ch < nch; ++ch) {
        const int k0 = ch * 20;
#pragma unroll
        for (int it = 0; it < 5; ++it) {
            int m = m0 + sr[it], k = k0 + sk[it];
            float va = 0.f, vw = 0.f;
            if (k < K) {
                if (m < M) va = A[(size_t)m * K + k];
                int n = n0 + sr[it];
                if (n < N) vw = W[(size_t)n * K + k];
            }
            As[sk[it]][sr[it]] = va;
            Ws[sk[it]][sr[it]] = vw;
        }
        __syncthreads();
#pragma unroll
        for (int kkk = 0; kkk < 20; ++kkk) {
            float4 a = *(const float4*)&As[kkk][r0];
            float4 w = *(const float4*)&Ws[kkk][c0];
            float av[4] = {a.x, a.y, a.z, a.w};
            float wv[4] = {w.x, w.y, w.z, w.w};
#pragma unroll
            for (int i = 0; i < 4; ++i)
#pragma unroll
                for (int j = 0; j < 4; ++j)
                    acc[i][j] = fmaf(av[i], wv[j], acc[i][j]);
        }
        __syncthreads();
    }
#pragma unroll
    for (int i = 0; i < 4; ++i) {
        int m = m0 + r0 + i;
        if (m >= M) continue;
#pragma unroll
        for (int j = 0; j < 4; ++j) {
            int n = n0 + c0 + j;
            if (n >= N) continue;
            float v = acc[i][j] + (bias ? bias[n] : 0.f);
            if (relu) v = fmaxf(v, 0.f);
            C[(size_t)m * N + n] = v;
        }
    }
}

// ---------------------------------------------------------------------------
// ONE convert kernel for everything weight/table-shaped (was 7 launches).
// Segments (block ranges):
//   [0, 25000)        temb -> TEMB_B [VOC][128], col100 = 1.0
//   [.., +1008)       6 GRU W -> gate-padded [336][128], exp2-scaled
//   [.., +448)        2 ih0 -> [448][128] (r,z,n,pad)-interleaved rows, scaled
//   [.., +1169)       4 GAT W (plain pad convert)
// ---------------------------------------------------------------------------
struct CvtAll {
    const float* temb;  u16* tembB;
    const float* gsrc[6]; const float* gbias[6]; u16* gdst[6];
    const float* is[2];   const float* ib[2];    u16* id_[2];
    const float* wsrc[4]; u16* wdst[4];
    int wK[4]; int wLdk[4]; int wTot[4];
};
#define CB_TEMB 25000
#define CB_GRUW 168
#define CB_IH0  224
#define CB_WTOT 1169   // 256 + 200 + 400 + 313

__global__ void convert_all(CvtAll P)
{
    int b = blockIdx.x;
    const int tid = threadIdx.x;
    if (b < CB_TEMB) {
        int t = b * 256 + tid;
        int n = t >> 7, c = t & 127;
        u16 o = 0;
        if (c < 100) o = f2bf(P.temb[(size_t)n * 100 + c]);
        else if (c == 100) o = 0x3F80;
        P.tembB[t] = o;
        return;
    }
    b -= CB_TEMB;
    if (b < 6 * CB_GRUW) {
        int mat = b / CB_GRUW;
        int t = (b - mat * CB_GRUW) * 256 + tid;
        int rr = t >> 7, cc = t & 127;
        int g = rr / 112, r2 = rr - g * 112;
        u16 o = 0;
        if (r2 < 100) {
            float sc = (g == 2) ? LOG2E2 : LOG2E;
            int sr = g * 100 + r2;
            if (cc < 100) o = f2bf(P.gsrc[mat][(size_t)sr * 100 + cc] * sc);
            else if (cc == 100) o = f2bf(P.gbias[mat][sr] * sc);
        }
        P.gdst[mat][t] = o;
        return;
    }
    b -= 6 * CB_GRUW;
    if (b < 2 * CB_IH0) {
        int which = b / CB_IH0;
        int t = (b - which * CB_IH0) * 256 + tid;
        int j = t >> 7, kc = t & 127;
        int cc = j >> 2, g = j & 3;
        u16 o = 0;
        if (g < 3 && cc < 100) {
            float sc = (g == 2) ? LOG2E2 : LOG2E;
            int sr = g * 100 + cc;
            if (kc < 100) o = f2bf(P.is[which][(size_t)sr * 100 + kc] * sc);
            else if (kc == 100) o = f2bf(P.ib[which][sr] * sc);
        }
        P.id_[which][t] = o;
        return;
    }
    b -= 2 * CB_IH0;
    int seg, t;
    if (b < 256)      { seg = 0; t = b * 256 + tid; }
    else if (b < 456) { seg = 1; t = (b - 256) * 256 + tid; }
    else if (b < 856) { seg = 2; t = (b - 456) * 256 + tid; }
    else              { seg = 3; t = (b - 856) * 256 + tid; }
    if (t >= P.wTot[seg]) return;
    int K = P.wK[seg], ldk = P.wLdk[seg];
    int n = t / ldk, c = t - n * ldk;
    u16 o = (c < K) ? f2bf(P.wsrc[seg][(size_t)n * K + c]) : (u16)0;
    P.wdst[seg][t] = o;
}

// xg (bf16 [NG][128]) = concat(hg[:128], ue, hg[128:])
__global__ void build_xg_bf(const u16* __restrict__ hgb, const float* __restrict__ ue,
                            u16* __restrict__ xgb)
{
    int t = blockIdx.x * blockDim.x + threadIdx.x;
    if (t >= NG * 128) return;
    int n = t >> 7, c = t & 127;
    u16 o = 0;
    if (n < NB)           o = hgb[n * 128 + c];
    else if (n < NB + NU) { if (c < HD) o = f2bf(ue[(size_t)(n - NB) * HD + c]); }
    else                  o = hgb[(size_t)(n - NU) * 128 + c];
    xgb[t] = o;
}

__global__ void set_roots(const float* __restrict__ src, u16* __restrict__ hb)
{
    int t = blockIdx.x * blockDim.x + threadIdx.x;
    if (t >= NB * HD) return;
    int n = t / HD, c = t - n * HD;
    hb[(size_t)n * 128 + c] = f2bf(src[t]);
}

// ---------------------------------------------------------------------------
// CSR build — graph + tree + tree->batch map fused per phase
// ---------------------------------------------------------------------------
__global__ void csr_count2(const int* __restrict__ gei, const int* __restrict__ tei,
                           const int* __restrict__ bmap,
                           int* __restrict__ gcnt, int* __restrict__ tcnt,
                           int* __restrict__ bcnt)
{
    int e = blockIdx.x * blockDim.x + threadIdx.x;
    const int GE = EG + NG, TE = ET + NTREE;
    if (e < GE) {
        int dst = (e < EG) ? gei[EG + e] : e - EG;
        atomicAdd(&gcnt[dst], 1);
    } else if (e < GE + TE) {
        int e2 = e - GE;
        int dst = (e2 < ET) ? tei[ET + e2] : e2 - ET;
        atomicAdd(&tcnt[dst], 1);
    } else {
        int e3 = e - GE - TE;
        if (e3 >= NTREE) return;
        atomicAdd(&bcnt[bmap[e3]], 1);
    }
}

__global__ void csr_scan2(int* __restrict__ gcnt, int* __restrict__ goff, int* __restrict__ gcur,
                          int* __restrict__ tcnt, int* __restrict__ toff, int* __restrict__ tcur,
                          int* __restrict__ bcnt, int* __restrict__ boff, int* __restrict__ bcur)
{
    const int* cnt; int* off; int* cur; int N;
    if (blockIdx.x == 0)      { cnt = gcnt; off = goff; cur = gcur; N = NG; }
    else if (blockIdx.x == 1) { cnt = tcnt; off = toff; cur = tcur; N = NTREE; }
    else                      { cnt = bcnt; off = boff; cur = bcur; N = NB; }
    __shared__ int part[256];
    const int tid = threadIdx.x;
    const int per = (N + 255) / 256;
    const int i0 = tid * per;
    const int i1 = min(i0 + per, N);
    int s = 0;
    for (int i = i0; i < i1; ++i) s += cnt[i];
    part[tid] = s;
    __syncthreads();
    for (int o = 1; o < 256; o <<= 1) {
        int u = (tid >= o) ? part[tid - o] : 0;
        __syncthreads();
        part[tid] += u;
        __syncthreads();
    }
    int base = part[tid] - s;
    for (int i = i0; i < i1; ++i) {
        off[i] = base; cur[i] = base;
        base += cnt[i];
    }
    if (tid == 255) off[N] = part[255];
}

__global__ void csr_scatter2(const int* __restrict__ gei, const int* __restrict__ tei,
                             const int* __restrict__ bmap,
                             int* __restrict__ gcur, int* __restrict__ tcur,
                             int* __restrict__ bcur,
                             int* __restrict__ geidx, int* __restrict__ teidx,
                             int* __restrict__ bidx)
{
    int e = blockIdx.x * blockDim.x + threadIdx.x;
    const int GE = EG + NG, TE = ET + NTREE;
    if (e < GE) {
        int dst = (e < EG) ? gei[EG + e] : e - EG;
        int pos = atomicAdd(&gcur[dst], 1);
        geidx[pos] = e;
    } else if (e < GE + TE) {
        int e2 = e - GE;
        int dst = (e2 < ET) ? tei[ET + e2] : e2 - ET;
        int pos = atomicAdd(&tcur[dst], 1);
        teidx[pos] = e2;
    } else {
        int e3 = e - GE - TE;
        if (e3 >= NTREE) return;
        int pos = atomicAdd(&bcur[bmap[e3]], 1);
        bidx[pos] = e3;
    }
}

// ---------------------------------------------------------------------------
// GAT pieces (feat is bf16)
// ---------------------------------------------------------------------------
__global__ void gat_es_ed(const u16* __restrict__ feat, const float* __restrict__ asrc,
                          const float* __restrict__ adst, float* __restrict__ es,
                          float* __restrict__ ed, int N, int heads, int C)
{
    int gid = blockIdx.x * blockDim.x + threadIdx.x;
    if (gid >= N * heads) return;
    int n = gid / heads, hd = gid - n * heads;
    const u16* hp = feat + ((size_t)n * heads + hd) * C;
    const float* as = asrc + (size_t)hd * C;
    const float* ad = adst + (size_t)hd * C;
    float s1 = 0.f, s2 = 0.f;
    for (int c = 0; c < C; c += 4) {
        uint2 pk = *(const uint2*)(hp + c);
        float v0 = bf2f((u16)(pk.x & 0xffff)), v1 = bf2f((u16)(pk.x >> 16));
        float v2 = bf2f((u16)(pk.y & 0xffff)), v3 = bf2f((u16)(pk.y >> 16));
        s1 += v0 * as[c] + v1 * as[c + 1] + v2 * as[c + 2] + v3 * as[c + 3];
        s2 += v0 * ad[c] + v1 * ad[c + 1] + v2 * ad[c + 2] + v3 * ad[c + 3];
    }
    es[gid] = s1; ed[gid] = s2;
}

// Fused per-dst softmax + accumulate: one wave per (dst, chunk).
// Pass1/2 compute per-head (max, sum) with lane roles (hd = lane & H-1,
// esl = lane/H); per-head stats broadcast via shfl; accum pass recomputes
// alpha inline (1-2 cheap es gathers/edge) — no eb buffer, no extra kernel.
template<int C, int VEC, int HEADS, int NCHUNK>
__global__ __launch_bounds__(256) void gat_fused(
    const int* __restrict__ off, const int* __restrict__ eidx,
    const int* __restrict__ ei, int E,
    const float* __restrict__ es, const float* __restrict__ ed,
    const u16* __restrict__ feat, const float* __restrict__ bias,
    float* __restrict__ outf, u16* __restrict__ outb,
    int N, int HC)
{
    int gt = blockIdx.x * blockDim.x + threadIdx.x;
    int wid = gt >> 6, lane = gt & 63;
    int dst = wid / NCHUNK, chunk = wid - dst * NCHUNK;
    if (dst >= N) return;
    const int e0 = off[dst], e1 = off[dst + 1];

    const int hd  = lane & (HEADS - 1);
    const int esl = lane / HEADS;
    const int EPI = 64 / HEADS;
    float edv = ed[(size_t)dst * HEADS + hd];

    float mymax = -3.4e38f;
    for (int p = e0 + esl; p < e1; p += EPI) {
        int j = eidx[p];
        int src = (j < E) ? ei[j] : (j - E);
        float e = es[(size_t)src * HEADS + hd] + edv;
        e = e > 0.f ? e : 0.2f * e;
        mymax = fmaxf(mymax, e);
    }
#pragma unroll
    for (int o = HEADS; o < 64; o <<= 1)
        mymax = fmaxf(mymax, __shfl_xor(mymax, o));

    float ssum = 0.f;
    for (int p = e0 + esl; p < e1; p += EPI) {
        int j = eidx[p];
        int src = (j < E) ? ei[j] : (j - E);
        float e = es[(size_t)src * HEADS + hd] + edv;
        e = e > 0.f ? e : 0.2f * e;
        ssum += __expf(e - mymax);
    }
#pragma unroll
    for (int o = HEADS; o < 64; o <<= 1)
        ssum += __shfl_xor(ssum, o);
    float sinv = __fdividef(1.f, ssum);

    // per-lane column range; at most 2 heads straddled
    int c0 = chunk * 64 * VEC + lane * VEC;
    int split = (c0 / C + 1) * C - c0;          // first v belonging to hhi
    int hlo = c0 / C;              if (hlo > HEADS - 1) hlo = HEADS - 1;
    int hhi = (c0 + VEC - 1) / C;  if (hhi > HEADS - 1) hhi = HEADS - 1;
    // lanes 0..H-1 hold head=lane stats (hd==lane there); all lanes exec shfl
    float maxlo = __shfl(mymax, hlo), sinvlo = __shfl(sinv, hlo), edlo = __shfl(edv, hlo);
    float maxhi = __shfl(mymax, hhi), sinvhi = __shfl(sinv, hhi), edhi = __shfl(edv, hhi);

    if (c0 >= HC) return;
    float acc[VEC];
#pragma unroll
    for (int v = 0; v < VEC; ++v) acc[v] = 0.f;

    for (int p = e0; p < e1; ++p) {
        int j = eidx[p];
        int src = (j < E) ? ei[j] : (j - E);
        float elo = es[(size_t)src * HEADS + hlo] + edlo;
        elo = elo > 0.f ? elo : 0.2f * elo;
        float alo = __expf(elo - maxlo) * sinvlo;
        float ahi = alo;
        if (hhi != hlo) {
            float ehi = es[(size_t)src * HEADS + hhi] + edhi;
            ehi = ehi > 0.f ? ehi : 0.2f * ehi;
            ahi = __expf(ehi - maxhi) * sinvhi;
        }
        const u16* frp = feat + (size_t)src * HC + c0;
        float fv[VEC];
        if (VEC == 8) {
            uint4 pk = *(const uint4*)frp;
            fv[0] = bf2f((u16)(pk.x & 0xffff)); fv[1] = bf2f((u16)(pk.x >> 16));
            fv[2] = bf2f((u16)(pk.y & 0xffff)); fv[3] = bf2f((u16)(pk.y >> 16));
            fv[4] = bf2f((u16)(pk.z & 0xffff)); fv[5] = bf2f((u16)(pk.z >> 16));
            fv[6] = bf2f((u16)(pk.w & 0xffff)); fv[7] = bf2f((u16)(pk.w >> 16));
        } else {
            u32 pk = *(const u32*)frp;
            fv[0] = bf2f((u16)(pk & 0xffff)); fv[1] = bf2f((u16)(pk >> 16));
        }
#pragma unroll
        for (int v = 0; v < VEC; ++v) {
            float a = (v < split) ? alo : ahi;
            acc[v] += fv[v] * a;
        }
    }
#pragma unroll
    for (int v = 0; v < VEC; ++v) {
        int c = c0 + v;
        if (c >= HC) continue;
        float o = fmaxf(acc[v] + bias[c], 0.f);
        if (outf) outf[(size_t)dst * HC + c] = o;
        if (outb) outb[(size_t)dst * HC + c] = f2bf(o);
    }
}

// Batch-CSR scatter-mean: 1 block per batch, no atomics, no memsets.
__global__ void scatter_mean_csr(const int* __restrict__ boff, const int* __restrict__ bidx,
                                 const float* __restrict__ x, float* __restrict__ meanb)
{
    int b = blockIdx.x;                  // NB blocks, 256 threads
    int tid = threadIdx.x;
    int c = tid & 127, half = tid >> 7;
    __shared__ float partial[256];
    int i0 = boff[b], i1 = boff[b + 1];
    float acc = 0.f;
    if (c < HD) {
        for (int i = i0 + half; i < i1; i += 2)
            acc += x[(size_t)bidx[i] * HD + c];
    }
    partial[tid] = acc;
    __syncthreads();
    if (half == 0 && c < HD) {
        float tot = partial[tid] + partial[tid + 128];
        float cnt = (float)(i1 - i0);
        meanb[b * HD + c] = tot * __fdividef(1.f, fmaxf(cnt, 1.f));
    }
}

__global__ void fc_out2(const float* __restrict__ meanb, const float* __restrict__ W,
                        const float* __restrict__ b, float* __restrict__ out)
{
    int t = threadIdx.x;                 // 512 threads
    int bb = t >> 2, j = t & 3;
    float acc = b[j];
    for (int k = 0; k < HD; ++k) acc += meanb[bb * HD + k] * W[j * HD + k];
    out[t] = acc;
}

// ---------------------------------------------------------------------------
// Host launcher
// ---------------------------------------------------------------------------
extern "C" void kernel_launch(void* const* d_in, const int* in_sizes, int n_in,
                              void* d_out, int out_size, void* d_ws, size_t ws_size,
                              hipStream_t stream)
{
    const float* user_feats = (const float*)d_in[1];
    const int*   gnf        = (const int*)d_in[2];
    const int*   gei        = (const int*)d_in[3];
    const int*   tnf        = (const int*)d_in[4];
    const int*   tei        = (const int*)d_in[5];
    const int*   indices    = (const int*)d_in[6];
    const float* h0g        = (const float*)d_in[7];
    const float* h0t        = (const float*)d_in[8];
    const float* temb       = (const float*)d_in[9];
    const float* gW[2][4] = {{(const float*)d_in[10], (const float*)d_in[11], (const float*)d_in[12], (const float*)d_in[13]},
                             {(const float*)d_in[14], (const float*)d_in[15], (const float*)d_in[16], (const float*)d_in[17]}};
    const float* tW[2][4] = {{(const float*)d_in[18], (const float*)d_in[19], (const float*)d_in[20], (const float*)d_in[21]},
                             {(const float*)d_in[22], (const float*)d_in[23], (const float*)d_in[24], (const float*)d_in[25]}};
    const float* uW1 = (const float*)d_in[26]; const float* ub1 = (const float*)d_in[27];
    const float* uW2 = (const float*)d_in[28]; const float* ub2 = (const float*)d_in[29];
    const float* gc1W = (const float*)d_in[30]; const float* gc1as = (const float*)d_in[31];
    const float* gc1ad = (const float*)d_in[32]; const float* gc1b = (const float*)d_in[33];
    const float* gc2W = (const float*)d_in[34]; const float* gc2as = (const float*)d_in[35];
    const float* gc2ad = (const float*)d_in[36]; const float* gc2b = (const float*)d_in[37];
    const float* tc1W = (const float*)d_in[38]; const float* tc1as = (const float*)d_in[39];
    const float* tc1ad = (const float*)d_in[40]; const float* tc1b = (const float*)d_in[41];
    const float* tc2W = (const float*)d_in[42]; const float* tc2as = (const float*)d_in[43];
    const float* tc2ad = (const float*)d_in[44]; const float* tc2b = (const float*)d_in[45];
    const float* fcW = (const float*)d_in[46]; const float* fcb = (const float*)d_in[47];
    float* out = (float*)d_out;

    char* ws = (char*)d_ws;
    const size_t NEED = 226500000;
    if (ws_size < NEED) return;

    // ---- workspace layout (decimal byte offsets, overlays noted) ----
    float* XGF    = (float*)(ws + 0);            // 12 MB [NG][100] fp32
    u16*   TEMB_B = (u16*)(ws + 12000000);       // 12.8 MB [VOC][128]
    u16*   ETAB_G = (u16*)(ws + 25000000);       // 44.8 MB [VOC][448] interleaved
    u16*   ETAB_T = (u16*)(ws + 70000000);       // 44.8 MB -> 114.8
    u16*   GH1B   = (u16*)(ws + 115000000);      // 2.56 MB [NTG][128]
    u16*   TH1B   = (u16*)(ws + 117600000);      // 7.68 MB [NTREE][128]
    float* UE     = (float*)(ws + 125300000);    // 8 MB
    float* HID    = (float*)(ws + 133400000);    // 8 MB
    u16*   WARENA = (u16*)(ws + 141500000);      // GRU weight arena
    int*   GOFF   = (int*)(ws + 142700000);
    int*   GCUR   = (int*)(ws + 142900000);
    int*   GCNT   = (int*)(ws + 143100000);      // NG ints
    int*   TCNT   = (int*)(ws + 143220000);      // NTREE ints
    int*   BCNT   = (int*)(ws + 143340000);      // NB ints (adjacent: 1 memset)
    int*   GEIDX  = (int*)(ws + 143400000);      // 0.92 MB
    int*   TOFF   = (int*)(ws + 144400000);
    int*   TCUR   = (int*)(ws + 144600000);
    int*   TEIDX  = (int*)(ws + 144800000);      // 0.36 MB -> 145160000
    int*   BOFF   = (int*)(ws + 145160000);
    int*   BCUR   = (int*)(ws + 145170000);
    int*   BIDX   = (int*)(ws + 145180000);      // 0.12 MB -> 145300000
    float* ESB    = (float*)(ws + 145300000);
    float* EDB    = (float*)(ws + 146300000);
    float* MEANB  = (float*)(ws + 156700000);    // [NB][100] fp32
    u16*   XG_B   = (u16*)(ws + 157000000);      // 7.68 MB [NG][128]
    u16*   GFEAT1 = (u16*)(ws + 165000000);      // 30.72 MB [NG][512] -> 195.72
    // GAT weight arena (persistent; converted once up front)
    u16*   W_G1a  = (u16*)(ws + 196000000);      // [512][128]
    u16*   W_G2a  = (u16*)(ws + 196131072);      // [100][512]
    u16*   W_G1b  = (u16*)(ws + 196233472);      // [800][128]
    u16*   W_G2b  = (u16*)(ws + 196438272);      // [100][800] -> 196598272
    // overlays (regions dead by the time they're written):
    u16*   GOUT1B = (u16*)(ws + 25000000);       // 30.72 MB (over ETAB_G, dead after GRU)
    u16*   GFEAT2 = (u16*)(ws + 56000000);       // 6 MB [NG][100]
    u16*   TFEAT1 = (u16*)(ws + 25000000);       // 48 MB [NTREE][800] (after graph GATs)
    u16*   TOUT1B = (u16*)(ws + 74000000);       // 48 MB (over ETAB_T/GH1B tail, dead)
    u16*   TFEAT2 = (u16*)(ws + 123000000);      // 6 MB (over TH1B-tail/UE, dead)
    float* XOUT2  = (float*)(ws + 157000000);    // 12 MB (over XG_B/GFEAT1-head, dead)

    // GRU weight arena slots (u16 element offsets)
    u16* gWHH0  = WARENA + 0;        // 6 x [336][128]
    u16* gWIH1  = WARENA + 43008;
    u16* gWHH1  = WARENA + 86016;
    u16* tWHH0  = WARENA + 129024;
    u16* tWIH1  = WARENA + 172032;
    u16* tWHH1  = WARENA + 215040;
    u16* W_IH0A = WARENA + 258048;   // [448][128] interleaved-row Etab weights
    u16* W_IH0B = WARENA + 315392;   // -> 372736 u16 = 0.745 MB (fits 1.2 MB region)

    auto mfma = [&](const u16* A, int lda, const u16* W, int ldw,
                    float* Cf, u16* Cb, int ldc, int M, int N, int Kt) {
        dim3 grid((M + 63) / 64, (N + 63) / 64, 1);
        gemm_mfma<<<grid, 256, 0, stream>>>(A, W, Cf, Cb, M, N, Kt, lda, ldw, ldc);
    };

    // ---- 1. ALL converts in one launch ----
    {
        CvtAll P;
        P.temb = temb; P.tembB = TEMB_B;
        P.gsrc[0] = gW[0][1]; P.gbias[0] = gW[0][3]; P.gdst[0] = gWHH0;
        P.gsrc[1] = gW[1][0]; P.gbias[1] = gW[1][2]; P.gdst[1] = gWIH1;
        P.gsrc[2] = gW[1][1]; P.gbias[2] = gW[1][3]; P.gdst[2] = gWHH1;
        P.gsrc[3] = tW[0][1]; P.gbias[3] = tW[0][3]; P.gdst[3] = tWHH0;
        P.gsrc[4] = tW[1][0]; P.gbias[4] = tW[1][2]; P.gdst[4] = tWIH1;
        P.gsrc[5] = tW[1][1]; P.gbias[5] = tW[1][3]; P.gdst[5] = tWHH1;
        P.is[0] = gW[0][0]; P.ib[0] = gW[0][2]; P.id_[0] = W_IH0A;
        P.is[1] = tW[0][0]; P.ib[1] = tW[0][2]; P.id_[1] = W_IH0B;
        P.wsrc[0] = gc1W; P.wdst[0] = W_G1a; P.wK[0] = 100; P.wLdk[0] = 128; P.wTot[0] = 512 * 128;
        P.wsrc[1] = gc2W; P.wdst[1] = W_G2a; P.wK[1] = 512; P.wLdk[1] = 512; P.wTot[1] = 100 * 512;
        P.wsrc[2] = tc1W; P.wdst[2] = W_G1b; P.wK[2] = 100; P.wLdk[2] = 128; P.wTot[2] = 800 * 128;
        P.wsrc[3] = tc2W; P.wdst[3] = W_G2b; P.wK[3] = 800; P.wLdk[3] = 800; P.wTot[3] = 100 * 800;
        int grid = CB_TEMB + 6 * CB_GRUW + 2 * CB_IH0 + CB_WTOT;   // 27625
        convert_all<<<grid, 256, 0, stream>>>(P);
    }

    // ---- 2. Etab build (both branches, one launch) ----
    {
        dim3 ge((VOC + 63) / 64, 7, 2);
        gemm_etab<<<ge, 256, 0, stream>>>(TEMB_B, W_IH0A, W_IH0B, ETAB_G, ETAB_T);
    }

    // ---- 3. CSR (graph + tree + batch, fused phases) ----
    hipMemsetAsync(GCNT, 0, 240512, stream);     // GCNT + TCNT + BCNT
    {
        int tot = (EG + NG) + (ET + NTREE) + NTREE;
        csr_count2<<<(tot + 255) / 256, 256, 0, stream>>>(gei, tei, indices, GCNT, TCNT, BCNT);
        csr_scan2<<<3, 256, 0, stream>>>(GCNT, GOFF, GCUR, TCNT, TOFF, TCUR, BCNT, BOFF, BCUR);
        csr_scatter2<<<(tot + 255) / 256, 256, 0, stream>>>(gei, tei, indices,
                                                            GCUR, TCUR, BCUR, GEIDX, TEIDX, BIDX);
    }

    // ---- 4. user embed (fp32) ----
    {
        dim3 g1((NU + 63) / 64, (HD + 63) / 64, 1);
        gemm_nt<<<g1, 256, 0, stream>>>(user_feats, uW1, ub1, HID, NU, HD, 9, 1);
        gemm_nt<<<g1, 256, 0, stream>>>(HID, uW2, ub2, UE, NU, HD, HD, 0);
    }

    // ---- 5. combined GRU (both branches, one launch, 32 rows/block) ----
    {
        GruProb Pg = { ETAB_G, gnf, h0g, gWHH0, gWIH1, gWHH1, GH1B, NTG };
        GruProb Pt = { ETAB_T, tnf, h0t, tWHH0, tWIH1, tWHH1, TH1B, NTREE };
        int gblk = (NTG + 31) / 32;      // 313
        int tblk = (NTREE + 31) / 32;    // 938
        gru_fused10<<<gblk + tblk, 448, 0, stream>>>(Pg, Pt, gblk);
    }

    // ---- 6. graph GAT chain ----
    build_xg_bf<<<(NG * 128 + 255) / 256, 256, 0, stream>>>(GH1B, UE, XG_B);
    {   // graph GAT1: 8 heads x 64
        mfma(XG_B, 128, W_G1a, 128, nullptr, GFEAT1, 512, NG, 512, 4);
        gat_es_ed<<<(NG * 8 + 255) / 256, 256, 0, stream>>>(GFEAT1, gc1as, gc1ad, ESB, EDB, NG, 8, 64);
        gat_fused<64, 8, 8, 1><<<(NG + 3) / 4, 256, 0, stream>>>(
            GOFF, GEIDX, gei, EG, ESB, EDB, GFEAT1, gc1b, nullptr, GOUT1B, NG, 512);
    }
    {   // graph GAT2: 1 head x 100
        mfma(GOUT1B, 512, W_G2a, 512, nullptr, GFEAT2, 100, NG, 100, 16);
        gat_es_ed<<<(NG + 255) / 256, 256, 0, stream>>>(GFEAT2, gc2as, gc2ad, ESB, EDB, NG, 1, 100);
        gat_fused<100, 2, 1, 1><<<(NG + 3) / 4, 256, 0, stream>>>(
            GOFF, GEIDX, gei, EG, ESB, EDB, GFEAT2, gc2b, XGF, nullptr, NG, 100);
    }

    // ---- 7. tree GAT chain ----
    set_roots<<<(NB * HD + 255) / 256, 256, 0, stream>>>(XGF, TH1B);
    {   // tree GAT1: 8 heads x 100
        mfma(TH1B, 128, W_G1b, 128, nullptr, TFEAT1, 800, NTREE, 800, 4);
        gat_es_ed<<<(NTREE * 8 + 255) / 256, 256, 0, stream>>>(TFEAT1, tc1as, tc1ad, ESB, EDB, NTREE, 8, 100);
        gat_fused<100, 8, 8, 2><<<(NTREE * 2 + 3) / 4, 256, 0, stream>>>(
            TOFF, TEIDX, tei, ET, ESB, EDB, TFEAT1, tc1b, nullptr, TOUT1B, NTREE, 800);
    }
    {   // tree GAT2: 1 head x 100
        mfma(TOUT1B, 800, W_G2b, 800, nullptr, TFEAT2, 100, NTREE, 100, 25);
        gat_es_ed<<<(NTREE + 255) / 256, 256, 0, stream>>>(TFEAT2, tc2as, tc2ad, ESB, EDB, NTREE, 1, 100);
        gat_fused<100, 2, 1, 1><<<(NTREE + 3) / 4, 256, 0, stream>>>(
            TOFF, TEIDX, tei, ET, ESB, EDB, TFEAT2, tc2b, XOUT2, nullptr, NTREE, 100);
    }

    // ---- 8. batch-CSR scatter-mean + classifier ----
    scatter_mean_csr<<<NB, 256, 0, stream>>>(BOFF, BIDX, XOUT2, MEANB);
    fc_out2<<<1, 512, 0, stream>>>(MEANB, fcW, fcb, out);
}

// Round 9
// 1423.666 us; speedup vs baseline: 1.2784x; 1.0117x over previous
//
#include <hip/hip_runtime.h>

// ---------------------------------------------------------------------------
// Problem constants
// ---------------------------------------------------------------------------
#define NB    128
#define HD    100
#define NU    20000
#define NTG   10000
#define NTREE 30000
#define NG    30000
#define TT    20
#define EG    200000
#define ET    60000
#define VOC   50000

#define ESTR2 448   // interleaved Etab row stride in u16: [112 cols][4] (r,z,n,pad)
#define LOG2E  1.4426950408889634f
#define LOG2E2 2.8853900817779268f

typedef unsigned short u16;
typedef unsigned int   u32;
typedef __attribute__((ext_vector_type(8))) short short8;
typedef __attribute__((ext_vector_type(4))) float floatx4;

// gate pre-activations arrive PRE-SCALED by log2e (r,z) / 2log2e (n)
__device__ __forceinline__ float sigmoid2_(float y) {
    return __fdividef(1.f, 1.f + __builtin_amdgcn_exp2f(-y));
}
__device__ __forceinline__ float tanh2_(float y) {
    return 1.f - __fdividef(2.f, __builtin_amdgcn_exp2f(y) + 1.f);
}
__device__ __forceinline__ u16 f2bf(float f) {
    u32 u = __float_as_uint(f);
    u32 r = (u + 0x7fffu + ((u >> 16) & 1u)) >> 16;
    return (u16)r;
}
__device__ __forceinline__ u16 f2bf_c(float f) {
    u32 r;
    asm("v_cvt_pk_bf16_f32 %0, %1, %2" : "=v"(r) : "v"(f), "v"(f));
    return (u16)r;
}
__device__ __forceinline__ float bf2f(u16 h) {
    return __uint_as_float(((u32)h) << 16);
}

// ---------------------------------------------------------------------------
// Fused 2-layer GRU v10 (PROVEN 588-602 µs): 448 threads (7 waves) / 32 rows.
// 64-row variant spills (state + 144 weight regs > 256 budget) — do not retry.
// ---------------------------------------------------------------------------
struct GruProb {
    const u16*   Etab;     // [VOC][112][4] interleaved, pre-scaled
    const int*   nodes;    // [M][TT]
    const float* h0;       // [2][M][100] fp32
    const u16*   Whh0;     // [336][128] gate-padded, scaled (col100 = bhh0)
    const u16*   Wih1;
    const u16*   Whh1;
    u16*         hout;     // [M][128]
    int          M;
};

__global__ __launch_bounds__(448, 2) void gru_fused10(GruProb Pg, GruProb Pt, int gblocks)
{
    const bool isg = (int)blockIdx.x < gblocks;
    const GruProb P = isg ? Pg : Pt;
    const int bx = isg ? blockIdx.x : blockIdx.x - gblocks;
    const int M  = P.M;
    const int m0 = bx * 32;

    __shared__ u16 H0[2][32 * 128];
    __shared__ u16 H1[2][32 * 128];
    __shared__ int NID[TT * 32];

    const int tid  = threadIdx.x;
    const int w    = tid >> 6, lane = tid & 63;
    const int fr   = lane & 15, quad = lane >> 4;
    const int c    = w * 16 + fr;
    const bool cok = (c < HD);

    short8 Bh0[3][4], Bx1[3][4], Bh1[3][4];
#pragma unroll
    for (int g = 0; g < 3; ++g) {
        const size_t rb = (size_t)((g * 7 + w) * 16 + fr) * 128 + quad * 8;
#pragma unroll
        for (int kk = 0; kk < 4; ++kk) {
            Bh0[g][kk] = *(const short8*)(P.Whh0 + rb + kk * 32);
            Bx1[g][kk] = *(const short8*)(P.Wih1 + rb + kk * 32);
            Bh1[g][kk] = *(const short8*)(P.Whh1 + rb + kk * 32);
        }
    }

    for (int i = tid; i < 32 * 128; i += 448) {
        H0[0][i] = 0; H0[1][i] = 0; H1[0][i] = 0; H1[1][i] = 0;
    }
    for (int i = tid; i < 32 * TT; i += 448) {
        int row = i / TT, t = i - row * TT;
        int gm = m0 + row;
        NID[t * 32 + row] = (gm < M) ? P.nodes[(size_t)gm * TT + t] : 0;
    }
    __syncthreads();
    if (tid < 32) {
        int off = 200 ^ ((tid & 7) << 4);
        *(u16*)((char*)&H0[0][0] + tid * 256 + off) = 0x3F80;
        *(u16*)((char*)&H0[1][0] + tid * 256 + off) = 0x3F80;
        *(u16*)((char*)&H1[0][0] + tid * 256 + off) = 0x3F80;
        *(u16*)((char*)&H1[1][0] + tid * 256 + off) = 0x3F80;
    }

    float h0f[2][4] = {{0.f,0.f,0.f,0.f},{0.f,0.f,0.f,0.f}};
    float h1f[2][4] = {{0.f,0.f,0.f,0.f},{0.f,0.f,0.f,0.f}};
    if (cok) {
#pragma unroll
        for (int rt = 0; rt < 2; ++rt)
#pragma unroll
        for (int r = 0; r < 4; ++r) {
            int row = rt * 16 + quad * 4 + r;
            int gm  = m0 + row;
            float v0 = 0.f, v1 = 0.f;
            if (gm < M) {
                v0 = P.h0[(size_t)gm * HD + c];
                v1 = P.h0[(size_t)(M + gm) * HD + c];
            }
            h0f[rt][r] = v0; h1f[rt][r] = v1;
            int off = (2 * c) ^ ((row & 7) << 4);
            *(u16*)((char*)&H0[0][0] + row * 256 + off) = f2bf_c(v0);
            *(u16*)((char*)&H1[0][0] + row * 256 + off) = f2bf_c(v1);
        }
    }

    u32 xlo[2][4], xhi[2][4];
    auto xpref = [&](int tn) {
        if (cok) {
#pragma unroll
            for (int rt = 0; rt < 2; ++rt)
#pragma unroll
            for (int r = 0; r < 4; ++r) {
                int row = rt * 16 + quad * 4 + r;
                int nd  = NID[tn * 32 + row];
                uint2 v = *(const uint2*)(P.Etab + (size_t)nd * ESTR2 + c * 4);
                xlo[rt][r] = v.x; xhi[rt][r] = v.y;
            }
        }
    };
    __syncthreads();
    xpref(0);

    // ---- prologue: A(0) ----
#pragma unroll
    for (int rt = 0; rt < 2; ++rt) {
        short8 a[4];
#pragma unroll
        for (int kk = 0; kk < 4; ++kk) {
            int row = rt * 16 + fr;
            int off = (kk * 64 + quad * 16) ^ ((row & 7) << 4);
            a[kk] = *(const short8*)((const char*)&H0[0][0] + row * 256 + off);
        }
        floatx4 ag[3];
#pragma unroll
        for (int g = 0; g < 3; ++g) ag[g] = (floatx4){0.f, 0.f, 0.f, 0.f};
#pragma unroll
        for (int g = 0; g < 3; ++g)
#pragma unroll
            for (int kk = 0; kk < 4; ++kk)
                ag[g] = __builtin_amdgcn_mfma_f32_16x16x32_bf16(a[kk], Bh0[g][kk], ag[g], 0, 0, 0);
        if (cok) {
#pragma unroll
            for (int r = 0; r < 4; ++r) {
                int row = rt * 16 + quad * 4 + r;
                float rr = sigmoid2_(bf2f((u16)xlo[rt][r]) + ag[0][r]);
                float zz = sigmoid2_(bf2f((u16)(xlo[rt][r] >> 16)) + ag[1][r]);
                float nn = tanh2_(bf2f((u16)xhi[rt][r]) + rr * ag[2][r]);
                float o  = nn + zz * (h0f[rt][r] - nn);
                h0f[rt][r] = o;
                *(u16*)((char*)&H0[1][0] + row * 256 + ((2 * c) ^ ((row & 7) << 4))) = f2bf_c(o);
            }
        }
    }
    __syncthreads();

    // ---- regions r = 0..TT-1: B(r) + A(r+1) ----
    for (int r = 0; r < TT; ++r) {
        const bool doA = (r + 1 < TT);
        if (doA) xpref(r + 1);

        const char* rd0 = (const char*)&H0[(r + 1) & 1][0];
        const char* rd1 = (const char*)&H1[r & 1][0];
        char*       wr0 = (char*)&H0[r & 1][0];
        char*       wr1 = (char*)&H1[(r + 1) & 1][0];

#pragma unroll
        for (int rt = 0; rt < 2; ++rt) {
            short8 a0[4], a1[4];
#pragma unroll
            for (int kk = 0; kk < 4; ++kk) {
                int row = rt * 16 + fr;
                int off = (kk * 64 + quad * 16) ^ ((row & 7) << 4);
                a0[kk] = *(const short8*)(rd0 + row * 256 + off);
                a1[kk] = *(const short8*)(rd1 + row * 256 + off);
            }
            floatx4 rz0 = {0.f,0.f,0.f,0.f}, rz1 = {0.f,0.f,0.f,0.f};
            floatx4 xnv = {0.f,0.f,0.f,0.f}, hnv = {0.f,0.f,0.f,0.f};
#pragma unroll
            for (int kk = 0; kk < 4; ++kk)
                rz0 = __builtin_amdgcn_mfma_f32_16x16x32_bf16(a0[kk], Bx1[0][kk], rz0, 0, 0, 0);
#pragma unroll
            for (int kk = 0; kk < 4; ++kk)
                rz0 = __builtin_amdgcn_mfma_f32_16x16x32_bf16(a1[kk], Bh1[0][kk], rz0, 0, 0, 0);
#pragma unroll
            for (int kk = 0; kk < 4; ++kk)
                rz1 = __builtin_amdgcn_mfma_f32_16x16x32_bf16(a0[kk], Bx1[1][kk], rz1, 0, 0, 0);
#pragma unroll
            for (int kk = 0; kk < 4; ++kk)
                rz1 = __builtin_amdgcn_mfma_f32_16x16x32_bf16(a1[kk], Bh1[1][kk], rz1, 0, 0, 0);
#pragma unroll
            for (int kk = 0; kk < 4; ++kk)
                xnv = __builtin_amdgcn_mfma_f32_16x16x32_bf16(a0[kk], Bx1[2][kk], xnv, 0, 0, 0);
#pragma unroll
            for (int kk = 0; kk < 4; ++kk)
                hnv = __builtin_amdgcn_mfma_f32_16x16x32_bf16(a1[kk], Bh1[2][kk], hnv, 0, 0, 0);
            floatx4 ag[3];
#pragma unroll
            for (int g = 0; g < 3; ++g) ag[g] = (floatx4){0.f, 0.f, 0.f, 0.f};
            if (doA) {
#pragma unroll
                for (int g = 0; g < 3; ++g)
#pragma unroll
                    for (int kk = 0; kk < 4; ++kk)
                        ag[g] = __builtin_amdgcn_mfma_f32_16x16x32_bf16(a0[kk], Bh0[g][kk], ag[g], 0, 0, 0);
            }
            if (cok) {
#pragma unroll
                for (int r4 = 0; r4 < 4; ++r4) {
                    int row = rt * 16 + quad * 4 + r4;
                    float rr = sigmoid2_(rz0[r4]);
                    float zz = sigmoid2_(rz1[r4]);
                    float nn = tanh2_(xnv[r4] + rr * hnv[r4]);
                    float o  = nn + zz * (h1f[rt][r4] - nn);
                    h1f[rt][r4] = o;
                    *(u16*)(wr1 + row * 256 + ((2 * c) ^ ((row & 7) << 4))) = f2bf_c(o);
                }
                if (doA) {
#pragma unroll
                    for (int r4 = 0; r4 < 4; ++r4) {
                        int row = rt * 16 + quad * 4 + r4;
                        float rr = sigmoid2_(bf2f((u16)xlo[rt][r4]) + ag[0][r4]);
                        float zz = sigmoid2_(bf2f((u16)(xlo[rt][r4] >> 16)) + ag[1][r4]);
                        float nn = tanh2_(bf2f((u16)xhi[rt][r4]) + rr * ag[2][r4]);
                        float o  = nn + zz * (h0f[rt][r4] - nn);
                        h0f[rt][r4] = o;
                        *(u16*)(wr0 + row * 256 + ((2 * c) ^ ((row & 7) << 4))) = f2bf_c(o);
                    }
                }
            }
        }
        __syncthreads();
    }

    for (int i = tid; i < 32 * 128; i += 448) {
        int row = i >> 7, cc = i & 127;
        int gm = m0 + row;
        if (gm < M) {
            int off = (2 * cc) ^ ((row & 7) << 4);
            P.hout[(size_t)gm * 128 + cc] = *(const u16*)((const char*)&H1[0][0] + row * 256 + off);
        }
    }
}

// ---------------------------------------------------------------------------
// bf16 MFMA GEMM (GAT feature GEMMs) with FUSED es/ed attention dots.
// If es != nullptr: es[row*heads+h] += sum_col feat[row][col]*asrc[h][col%C]
// (and ed likewise) accumulated from the fp32 tile accumulators via 16-lane
// shfl reduction + one atomicAdd per (row, head, tile). es/ed pre-zeroed.
// ---------------------------------------------------------------------------
#define LDST 40
__global__ __launch_bounds__(256) void gemm_mfma(
    const u16* __restrict__ A, const u16* __restrict__ B,
    float* __restrict__ Cf, u16* __restrict__ Cb,
    int M, int N, int Kt, int lda, int ldw, int ldc,
    const float* __restrict__ asrc, const float* __restrict__ adst,
    float* __restrict__ es, float* __restrict__ ed, int heads, int Cc)
{
    const int m0 = blockIdx.x * 64;
    if (m0 >= M) return;
    const int n0 = blockIdx.y * 64;

    __shared__ u16 Als[64 * LDST];
    __shared__ u16 Wls[64 * LDST];

    const int tid  = threadIdx.x;
    const int wave = tid >> 6, lane = tid & 63;
    const int row  = tid >> 2, part = (tid & 3) * 8;
    const int fr   = lane & 15, quad = lane >> 4;

    floatx4 acc[4];
#pragma unroll
    for (int t = 0; t < 4; ++t) acc[t] = (floatx4){0.f, 0.f, 0.f, 0.f};

    const int am = m0 + row;  const bool aok = am < M;
    const int wn = n0 + row;  const bool wok = wn < N;
    const uint4 z4 = {0u, 0u, 0u, 0u};

    for (int kk = 0; kk < Kt; ++kk) {
        uint4 av = aok ? *(const uint4*)(A + (size_t)am * lda + kk * 32 + part) : z4;
        uint4 wv = wok ? *(const uint4*)(B + (size_t)wn * ldw + kk * 32 + part) : z4;
        __syncthreads();
        *(uint4*)&Als[row * LDST + part] = av;
        *(uint4*)&Wls[row * LDST + part] = wv;
        __syncthreads();
        short8 af = *(const short8*)&Als[((wave << 4) + fr) * LDST + quad * 8];
#pragma unroll
        for (int t = 0; t < 4; ++t) {
            short8 bf = *(const short8*)&Wls[((t << 4) + fr) * LDST + quad * 8];
            acc[t] = __builtin_amdgcn_mfma_f32_16x16x32_bf16(af, bf, acc[t], 0, 0, 0);
        }
    }

    const int orow0 = m0 + (wave << 4) + quad * 4;
#pragma unroll
    for (int t = 0; t < 4; ++t) {
        int col = n0 + (t << 4) + fr;
        if (col >= N) continue;
#pragma unroll
        for (int r = 0; r < 4; ++r) {
            int mr = orow0 + r;
            if (mr >= M) continue;
            float v = acc[t][r];
            if (Cf) Cf[(size_t)mr * ldc + col] = v;
            if (Cb) Cb[(size_t)mr * ldc + col] = f2bf(v);
        }
    }

    // ---- fused es/ed partial dots ----
    if (es) {
        const int hA = n0 / Cc;
        int hB = (n0 + 63) / Cc; if (hB > heads - 1) hB = heads - 1;
        float pse[2][4], psd[2][4];
#pragma unroll
        for (int s = 0; s < 2; ++s)
#pragma unroll
        for (int r = 0; r < 4; ++r) { pse[s][r] = 0.f; psd[s][r] = 0.f; }
#pragma unroll
        for (int t = 0; t < 4; ++t) {
            int col = n0 + (t << 4) + fr;
            if (col >= N) continue;
            int h = col / Cc;
            int slot = (h != hA);
            float as = asrc[h * Cc + (col - h * Cc)];
            float ad = adst[h * Cc + (col - h * Cc)];
#pragma unroll
            for (int r = 0; r < 4; ++r) {
                pse[slot][r] += acc[t][r] * as;
                psd[slot][r] += acc[t][r] * ad;
            }
        }
        // reduce across the 16 fr-lanes (same quad)
#pragma unroll
        for (int o = 1; o < 16; o <<= 1) {
#pragma unroll
            for (int s = 0; s < 2; ++s)
#pragma unroll
            for (int r = 0; r < 4; ++r) {
                pse[s][r] += __shfl_xor(pse[s][r], o);
                psd[s][r] += __shfl_xor(psd[s][r], o);
            }
        }
        if (fr == 0) {
#pragma unroll
            for (int r = 0; r < 4; ++r) {
                int mr = orow0 + r;
                if (mr >= M) continue;
                atomicAdd(&es[(size_t)mr * heads + hA], pse[0][r]);
                atomicAdd(&ed[(size_t)mr * heads + hA], psd[0][r]);
                if (hB != hA) {
                    atomicAdd(&es[(size_t)mr * heads + hB], pse[1][r]);
                    atomicAdd(&ed[(size_t)mr * heads + hB], psd[1][r]);
                }
            }
        }
    }
}

// Dual Etab build: z selects (W,C). W rows pre-ordered (r,z,n,pad)-interleaved.
__global__ __launch_bounds__(256) void gemm_etab(
    const u16* __restrict__ A, const u16* __restrict__ W0, const u16* __restrict__ W1,
    u16* __restrict__ C0, u16* __restrict__ C1)
{
    const int m0 = blockIdx.x * 64;
    const int n0 = blockIdx.y * 64;
    const u16* B = blockIdx.z ? W1 : W0;
    u16* Cb = blockIdx.z ? C1 : C0;
    const int N = 400;

    __shared__ u16 Als[64 * LDST];
    __shared__ u16 Wls[64 * LDST];

    const int tid  = threadIdx.x;
    const int wave = tid >> 6, lane = tid & 63;
    const int row  = tid >> 2, part = (tid & 3) * 8;
    const int fr   = lane & 15, quad = lane >> 4;

    floatx4 acc[4];
#pragma unroll
    for (int t = 0; t < 4; ++t) acc[t] = (floatx4){0.f, 0.f, 0.f, 0.f};

    const int am = m0 + row;
    const int wn = n0 + row;  const bool wok = wn < N;
    const uint4 z4 = {0u, 0u, 0u, 0u};

    for (int kk = 0; kk < 4; ++kk) {
        uint4 av = *(const uint4*)(A + (size_t)am * 128 + kk * 32 + part);
        uint4 wv = wok ? *(const uint4*)(B + (size_t)wn * 128 + kk * 32 + part) : z4;
        __syncthreads();
        *(uint4*)&Als[row * LDST + part] = av;
        *(uint4*)&Wls[row * LDST + part] = wv;
        __syncthreads();
        short8 af = *(const short8*)&Als[((wave << 4) + fr) * LDST + quad * 8];
#pragma unroll
        for (int t = 0; t < 4; ++t) {
            short8 bf = *(const short8*)&Wls[((t << 4) + fr) * LDST + quad * 8];
            acc[t] = __builtin_amdgcn_mfma_f32_16x16x32_bf16(af, bf, acc[t], 0, 0, 0);
        }
    }

    const int orow0 = m0 + (wave << 4) + quad * 4;
#pragma unroll
    for (int t = 0; t < 4; ++t) {
        int col = n0 + (t << 4) + fr;
        if (col >= N) continue;
#pragma unroll
        for (int r = 0; r < 4; ++r)
            Cb[(size_t)(orow0 + r) * ESTR2 + col] = f2bf(acc[t][r]);
    }
}

// ---------------------------------------------------------------------------
// fp32 tiled GEMM (user-embed MLP layer 2 only)
// ---------------------------------------------------------------------------
__global__ __launch_bounds__(256) void gemm_nt(
    const float* __restrict__ A, const float* __restrict__ W,
    const float* __restrict__ bias, float* __restrict__ C,
    int M, int N, int K, int relu)
{
    const int m0 = blockIdx.x * 64;
    const int n0 = blockIdx.y * 64;
    __shared__ float As[20][68];
    __shared__ float Ws[20][68];
    const int tid = threadIdx.x;
    const int r0 = (tid >> 4) * 4;
    const int c0 = (tid & 15) * 4;
    int sr[5], sk[5];
#pragma unroll
    for (int it = 0; it < 5; ++it) {
        int idx = tid + it * 256;
        sr[it] = idx / 20; sk[it] = idx - sr[it] * 20;
    }
    float acc[4][4];
#pragma unroll
    for (int i = 0; i < 4; ++i)
#pragma unroll
        for (int j = 0; j < 4; ++j) acc[i][j] = 0.f;
    const int nch = (K + 19) / 20;
    for (int ch = 0; ch < nch; ++ch) {
        const int k0 = ch * 20;
#pragma unroll
        for (int it = 0; it < 5; ++it) {
            int m = m0 + sr[it], k = k0 + sk[it];
            float va = 0.f, vw = 0.f;
            if (k < K) {
                if (m < M) va = A[(size_t)m * K + k];
                int n = n0 + sr[it];
                if (n < N) vw = W[(size_t)n * K + k];
            }
            As[sk[it]][sr[it]] = va;
            Ws[sk[it]][sr[it]] = vw;
        }
        __syncthreads();
#pragma unroll
        for (int kkk = 0; kkk < 20; ++kkk) {
            float4 a = *(const float4*)&As[kkk][r0];
            float4 w = *(const float4*)&Ws[kkk][c0];
            float av[4] = {a.x, a.y, a.z, a.w};
            float wv[4] = {w.x, w.y, w.z, w.w};
#pragma unroll
            for (int i = 0; i < 4; ++i)
#pragma unroll
                for (int j = 0; j < 4; ++j)
                    acc[i][j] = fmaf(av[i], wv[j], acc[i][j]);
        }
        __syncthreads();
    }
#pragma unroll
    for (int i = 0; i < 4; ++i) {
        int m = m0 + r0 + i;
        if (m >= M) continue;
#pragma unroll
        for (int j = 0; j < 4; ++j) {
            int n = n0 + c0 + j;
            if (n >= N) continue;
            float v = acc[i][j] + (bias ? bias[n] : 0.f);
            if (relu) v = fmaxf(v, 0.f);
            C[(size_t)m * N + n] = v;
        }
    }
}

// MLP layer 1: K=9, one thread per output, relu. (gemm_nt overkill for K=9.)
__global__ void mlp1(const float* __restrict__ uf, const float* __restrict__ W,
                     const float* __restrict__ b, float* __restrict__ out)
{
    int t = blockIdx.x * blockDim.x + threadIdx.x;
    if (t >= NU * HD) return;
    int n = t / HD, j = t - n * HD;
    const float* ur = uf + (size_t)n * 9;
    const float* wr = W + (size_t)j * 9;
    float acc = b[j];
#pragma unroll
    for (int k = 0; k < 9; ++k) acc = fmaf(ur[k], wr[k], acc);
    out[t] = fmaxf(acc, 0.f);
}

// ---------------------------------------------------------------------------
// ONE convert kernel for everything weight/table-shaped.
// ---------------------------------------------------------------------------
struct CvtAll {
    const float* temb;  u16* tembB;
    const float* gsrc[6]; const float* gbias[6]; u16* gdst[6];
    const float* is[2];   const float* ib[2];    u16* id_[2];
    const float* wsrc[4]; u16* wdst[4];
    int wK[4]; int wLdk[4]; int wTot[4];
};
#define CB_TEMB 25000
#define CB_GRUW 168
#define CB_IH0  224
#define CB_WTOT 1169   // 256 + 200 + 400 + 313

__global__ void convert_all(CvtAll P)
{
    int b = blockIdx.x;
    const int tid = threadIdx.x;
    if (b < CB_TEMB) {
        int t = b * 256 + tid;
        int n = t >> 7, c = t & 127;
        u16 o = 0;
        if (c < 100) o = f2bf(P.temb[(size_t)n * 100 + c]);
        else if (c == 100) o = 0x3F80;
        P.tembB[t] = o;
        return;
    }
    b -= CB_TEMB;
    if (b < 6 * CB_GRUW) {
        int mat = b / CB_GRUW;
        int t = (b - mat * CB_GRUW) * 256 + tid;
        int rr = t >> 7, cc = t & 127;
        int g = rr / 112, r2 = rr - g * 112;
        u16 o = 0;
        if (r2 < 100) {
            float sc = (g == 2) ? LOG2E2 : LOG2E;
            int sr = g * 100 + r2;
            if (cc < 100) o = f2bf(P.gsrc[mat][(size_t)sr * 100 + cc] * sc);
            else if (cc == 100) o = f2bf(P.gbias[mat][sr] * sc);
        }
        P.gdst[mat][t] = o;
        return;
    }
    b -= 6 * CB_GRUW;
    if (b < 2 * CB_IH0) {
        int which = b / CB_IH0;
        int t = (b - which * CB_IH0) * 256 + tid;
        int j = t >> 7, kc = t & 127;
        int cc = j >> 2, g = j & 3;
        u16 o = 0;
        if (g < 3 && cc < 100) {
            float sc = (g == 2) ? LOG2E2 : LOG2E;
            int sr = g * 100 + cc;
            if (kc < 100) o = f2bf(P.is[which][(size_t)sr * 100 + kc] * sc);
            else if (kc == 100) o = f2bf(P.ib[which][sr] * sc);
        }
        P.id_[which][t] = o;
        return;
    }
    b -= 2 * CB_IH0;
    int seg, t;
    if (b < 256)      { seg = 0; t = b * 256 + tid; }
    else if (b < 456) { seg = 1; t = (b - 256) * 256 + tid; }
    else if (b < 856) { seg = 2; t = (b - 456) * 256 + tid; }
    else              { seg = 3; t = (b - 856) * 256 + tid; }
    if (t >= P.wTot[seg]) return;
    int K = P.wK[seg], ldk = P.wLdk[seg];
    int n = t / ldk, c = t - n * ldk;
    u16 o = (c < K) ? f2bf(P.wsrc[seg][(size_t)n * K + c]) : (u16)0;
    P.wdst[seg][t] = o;
}

// xg (bf16 [NG][128]) = concat(hg[:128], ue, hg[128:])
__global__ void build_xg_bf(const u16* __restrict__ hgb, const float* __restrict__ ue,
                            u16* __restrict__ xgb)
{
    int t = blockIdx.x * blockDim.x + threadIdx.x;
    if (t >= NG * 128) return;
    int n = t >> 7, c = t & 127;
    u16 o = 0;
    if (n < NB)           o = hgb[n * 128 + c];
    else if (n < NB + NU) { if (c < HD) o = f2bf(ue[(size_t)(n - NB) * HD + c]); }
    else                  o = hgb[(size_t)(n - NU) * 128 + c];
    xgb[t] = o;
}

__global__ void set_roots(const float* __restrict__ src, u16* __restrict__ hb)
{
    int t = blockIdx.x * blockDim.x + threadIdx.x;
    if (t >= NB * HD) return;
    int n = t / HD, c = t - n * HD;
    hb[(size_t)n * 128 + c] = f2bf(src[t]);
}

// ---------------------------------------------------------------------------
// CSR build — graph + tree + tree->batch map fused per phase
// ---------------------------------------------------------------------------
__global__ void csr_count2(const int* __restrict__ gei, const int* __restrict__ tei,
                           const int* __restrict__ bmap,
                           int* __restrict__ gcnt, int* __restrict__ tcnt,
                           int* __restrict__ bcnt)
{
    int e = blockIdx.x * blockDim.x + threadIdx.x;
    const int GE = EG + NG, TE = ET + NTREE;
    if (e < GE) {
        int dst = (e < EG) ? gei[EG + e] : e - EG;
        atomicAdd(&gcnt[dst], 1);
    } else if (e < GE + TE) {
        int e2 = e - GE;
        int dst = (e2 < ET) ? tei[ET + e2] : e2 - ET;
        atomicAdd(&tcnt[dst], 1);
    } else {
        int e3 = e - GE - TE;
        if (e3 >= NTREE) return;
        atomicAdd(&bcnt[bmap[e3]], 1);
    }
}

__global__ void csr_scan2(int* __restrict__ gcnt, int* __restrict__ goff, int* __restrict__ gcur,
                          int* __restrict__ tcnt, int* __restrict__ toff, int* __restrict__ tcur,
                          int* __restrict__ bcnt, int* __restrict__ boff, int* __restrict__ bcur)
{
    const int* cnt; int* off; int* cur; int N;
    if (blockIdx.x == 0)      { cnt = gcnt; off = goff; cur = gcur; N = NG; }
    else if (blockIdx.x == 1) { cnt = tcnt; off = toff; cur = tcur; N = NTREE; }
    else                      { cnt = bcnt; off = boff; cur = bcur; N = NB; }
    __shared__ int part[256];
    const int tid = threadIdx.x;
    const int per = (N + 255) / 256;
    const int i0 = tid * per;
    const int i1 = min(i0 + per, N);
    int s = 0;
    for (int i = i0; i < i1; ++i) s += cnt[i];
    part[tid] = s;
    __syncthreads();
    for (int o = 1; o < 256; o <<= 1) {
        int u = (tid >= o) ? part[tid - o] : 0;
        __syncthreads();
        part[tid] += u;
        __syncthreads();
    }
    int base = part[tid] - s;
    for (int i = i0; i < i1; ++i) {
        off[i] = base; cur[i] = base;
        base += cnt[i];
    }
    if (tid == 255) off[N] = part[255];
}

__global__ void csr_scatter2(const int* __restrict__ gei, const int* __restrict__ tei,
                             const int* __restrict__ bmap,
                             int* __restrict__ gcur, int* __restrict__ tcur,
                             int* __restrict__ bcur,
                             int* __restrict__ geidx, int* __restrict__ teidx,
                             int* __restrict__ bidx)
{
    int e = blockIdx.x * blockDim.x + threadIdx.x;
    const int GE = EG + NG, TE = ET + NTREE;
    if (e < GE) {
        int dst = (e < EG) ? gei[EG + e] : e - EG;
        int pos = atomicAdd(&gcur[dst], 1);
        geidx[pos] = e;
    } else if (e < GE + TE) {
        int e2 = e - GE;
        int dst = (e2 < ET) ? tei[ET + e2] : e2 - ET;
        int pos = atomicAdd(&tcur[dst], 1);
        teidx[pos] = e2;
    } else {
        int e3 = e - GE - TE;
        if (e3 >= NTREE) return;
        int pos = atomicAdd(&bcur[bmap[e3]], 1);
        bidx[pos] = e3;
    }
}

// ---------------------------------------------------------------------------
// Fused per-dst softmax + accumulate (es/ed come pre-computed from the GEMM).
// ---------------------------------------------------------------------------
template<int C, int VEC, int HEADS, int NCHUNK>
__global__ __launch_bounds__(256) void gat_fused(
    const int* __restrict__ off, const int* __restrict__ eidx,
    const int* __restrict__ ei, int E,
    const float* __restrict__ es, const float* __restrict__ ed,
    const u16* __restrict__ feat, const float* __restrict__ bias,
    float* __restrict__ outf, u16* __restrict__ outb,
    int N, int HC)
{
    int gt = blockIdx.x * blockDim.x + threadIdx.x;
    int wid = gt >> 6, lane = gt & 63;
    int dst = wid / NCHUNK, chunk = wid - dst * NCHUNK;
    if (dst >= N) return;
    const int e0 = off[dst], e1 = off[dst + 1];

    const int hd  = lane & (HEADS - 1);
    const int esl = lane / HEADS;
    const int EPI = 64 / HEADS;
    float edv = ed[(size_t)dst * HEADS + hd];

    float mymax = -3.4e38f;
    for (int p = e0 + esl; p < e1; p += EPI) {
        int j = eidx[p];
        int src = (j < E) ? ei[j] : (j - E);
        float e = es[(size_t)src * HEADS + hd] + edv;
        e = e > 0.f ? e : 0.2f * e;
        mymax = fmaxf(mymax, e);
    }
#pragma unroll
    for (int o = HEADS; o < 64; o <<= 1)
        mymax = fmaxf(mymax, __shfl_xor(mymax, o));

    float ssum = 0.f;
    for (int p = e0 + esl; p < e1; p += EPI) {
        int j = eidx[p];
        int src = (j < E) ? ei[j] : (j - E);
        float e = es[(size_t)src * HEADS + hd] + edv;
        e = e > 0.f ? e : 0.2f * e;
        ssum += __expf(e - mymax);
    }
#pragma unroll
    for (int o = HEADS; o < 64; o <<= 1)
        ssum += __shfl_xor(ssum, o);
    float sinv = __fdividef(1.f, ssum);

    // per-lane column range; at most 2 heads straddled
    int c0 = chunk * 64 * VEC + lane * VEC;
    int split = (c0 / C + 1) * C - c0;          // first v belonging to hhi
    int hlo = c0 / C;              if (hlo > HEADS - 1) hlo = HEADS - 1;
    int hhi = (c0 + VEC - 1) / C;  if (hhi > HEADS - 1) hhi = HEADS - 1;
    float maxlo = __shfl(mymax, hlo), sinvlo = __shfl(sinv, hlo), edlo = __shfl(edv, hlo);
    float maxhi = __shfl(mymax, hhi), sinvhi = __shfl(sinv, hhi), edhi = __shfl(edv, hhi);

    if (c0 >= HC) return;
    float acc[VEC];
#pragma unroll
    for (int v = 0; v < VEC; ++v) acc[v] = 0.f;

    for (int p = e0; p < e1; ++p) {
        int j = eidx[p];
        int src = (j < E) ? ei[j] : (j - E);
        float elo = es[(size_t)src * HEADS + hlo] + edlo;
        elo = elo > 0.f ? elo : 0.2f * elo;
        float alo = __expf(elo - maxlo) * sinvlo;
        float ahi = alo;
        if (hhi != hlo) {
            float ehi = es[(size_t)src * HEADS + hhi] + edhi;
            ehi = ehi > 0.f ? ehi : 0.2f * ehi;
            ahi = __expf(ehi - maxhi) * sinvhi;
        }
        const u16* frp = feat + (size_t)src * HC + c0;
        float fv[VEC];
        if (VEC == 8) {
            uint4 pk = *(const uint4*)frp;
            fv[0] = bf2f((u16)(pk.x & 0xffff)); fv[1] = bf2f((u16)(pk.x >> 16));
            fv[2] = bf2f((u16)(pk.y & 0xffff)); fv[3] = bf2f((u16)(pk.y >> 16));
            fv[4] = bf2f((u16)(pk.z & 0xffff)); fv[5] = bf2f((u16)(pk.z >> 16));
            fv[6] = bf2f((u16)(pk.w & 0xffff)); fv[7] = bf2f((u16)(pk.w >> 16));
        } else {
            u32 pk = *(const u32*)frp;
            fv[0] = bf2f((u16)(pk & 0xffff)); fv[1] = bf2f((u16)(pk >> 16));
        }
#pragma unroll
        for (int v = 0; v < VEC; ++v) {
            float a = (v < split) ? alo : ahi;
            acc[v] += fv[v] * a;
        }
    }
#pragma unroll
    for (int v = 0; v < VEC; ++v) {
        int c = c0 + v;
        if (c >= HC) continue;
        float o = fmaxf(acc[v] + bias[c], 0.f);
        if (outf) outf[(size_t)dst * HC + c] = o;
        if (outb) outb[(size_t)dst * HC + c] = f2bf(o);
    }
}

// Batch-CSR scatter-mean: 1 block per batch, no atomics, no memsets.
__global__ void scatter_mean_csr(const int* __restrict__ boff, const int* __restrict__ bidx,
                                 const float* __restrict__ x, float* __restrict__ meanb)
{
    int b = blockIdx.x;                  // NB blocks, 256 threads
    int tid = threadIdx.x;
    int c = tid & 127, half = tid >> 7;
    __shared__ float partial[256];
    int i0 = boff[b], i1 = boff[b + 1];
    float acc = 0.f;
    if (c < HD) {
        for (int i = i0 + half; i < i1; i += 2)
            acc += x[(size_t)bidx[i] * HD + c];
    }
    partial[tid] = acc;
    __syncthreads();
    if (half == 0 && c < HD) {
        float tot = partial[tid] + partial[tid + 128];
        float cnt = (float)(i1 - i0);
        meanb[b * HD + c] = tot * __fdividef(1.f, fmaxf(cnt, 1.f));
    }
}

__global__ void fc_out2(const float* __restrict__ meanb, const float* __restrict__ W,
                        const float* __restrict__ b, float* __restrict__ out)
{
    int t = threadIdx.x;                 // 512 threads
    int bb = t >> 2, j = t & 3;
    float acc = b[j];
    for (int k = 0; k < HD; ++k) acc += meanb[bb * HD + k] * W[j * HD + k];
    out[t] = acc;
}

// ---------------------------------------------------------------------------
// Host launcher
// ---------------------------------------------------------------------------
extern "C" void kernel_launch(void* const* d_in, const int* in_sizes, int n_in,
                              void* d_out, int out_size, void* d_ws, size_t ws_size,
                              hipStream_t stream)
{
    const float* user_feats = (const float*)d_in[1];
    const int*   gnf        = (const int*)d_in[2];
    const int*   gei        = (const int*)d_in[3];
    const int*   tnf        = (const int*)d_in[4];
    const int*   tei        = (const int*)d_in[5];
    const int*   indices    = (const int*)d_in[6];
    const float* h0g        = (const float*)d_in[7];
    const float* h0t        = (const float*)d_in[8];
    const float* temb       = (const float*)d_in[9];
    const float* gW[2][4] = {{(const float*)d_in[10], (const float*)d_in[11], (const float*)d_in[12], (const float*)d_in[13]},
                             {(const float*)d_in[14], (const float*)d_in[15], (const float*)d_in[16], (const float*)d_in[17]}};
    const float* tW[2][4] = {{(const float*)d_in[18], (const float*)d_in[19], (const float*)d_in[20], (const float*)d_in[21]},
                             {(const float*)d_in[22], (const float*)d_in[23], (const float*)d_in[24], (const float*)d_in[25]}};
    const float* uW1 = (const float*)d_in[26]; const float* ub1 = (const float*)d_in[27];
    const float* uW2 = (const float*)d_in[28]; const float* ub2 = (const float*)d_in[29];
    const float* gc1W = (const float*)d_in[30]; const float* gc1as = (const float*)d_in[31];
    const float* gc1ad = (const float*)d_in[32]; const float* gc1b = (const float*)d_in[33];
    const float* gc2W = (const float*)d_in[34]; const float* gc2as = (const float*)d_in[35];
    const float* gc2ad = (const float*)d_in[36]; const float* gc2b = (const float*)d_in[37];
    const float* tc1W = (const float*)d_in[38]; const float* tc1as = (const float*)d_in[39];
    const float* tc1ad = (const float*)d_in[40]; const float* tc1b = (const float*)d_in[41];
    const float* tc2W = (const float*)d_in[42]; const float* tc2as = (const float*)d_in[43];
    const float* tc2ad = (const float*)d_in[44]; const float* tc2b = (const float*)d_in[45];
    const float* fcW = (const float*)d_in[46]; const float* fcb = (const float*)d_in[47];
    float* out = (float*)d_out;

    char* ws = (char*)d_ws;
    const size_t NEED = 226500000;
    if (ws_size < NEED) return;

    // ---- workspace layout (decimal byte offsets, overlays noted) ----
    float* XGF    = (float*)(ws + 0);            // 12 MB [NG][100] fp32
    u16*   TEMB_B = (u16*)(ws + 12000000);       // 12.8 MB [VOC][128]
    u16*   ETAB_G = (u16*)(ws + 25000000);       // 44.8 MB [VOC][448] interleaved
    u16*   ETAB_T = (u16*)(ws + 70000000);       // 44.8 MB -> 114.8
    u16*   GH1B   = (u16*)(ws + 115000000);      // 2.56 MB [NTG][128]
    u16*   TH1B   = (u16*)(ws + 117600000);      // 7.68 MB [NTREE][128]
    float* UE     = (float*)(ws + 125300000);    // 8 MB
    float* HID    = (float*)(ws + 133400000);    // 8 MB
    u16*   WARENA = (u16*)(ws + 141500000);      // GRU weight arena
    int*   GOFF   = (int*)(ws + 142700000);
    int*   GCUR   = (int*)(ws + 142900000);
    int*   GCNT   = (int*)(ws + 143100000);      // NG ints
    int*   TCNT   = (int*)(ws + 143220000);      // NTREE ints
    int*   BCNT   = (int*)(ws + 143340000);      // NB ints
    int*   GEIDX  = (int*)(ws + 143400000);      // 0.92 MB
    int*   TOFF   = (int*)(ws + 144400000);
    int*   TCUR   = (int*)(ws + 144600000);
    int*   TEIDX  = (int*)(ws + 144800000);      // 0.36 MB -> 145160000
    int*   BOFF   = (int*)(ws + 145160000);
    int*   BCUR   = (int*)(ws + 145170000);
    int*   BIDX   = (int*)(ws + 145180000);      // 0.12 MB -> 145300000
    // es/ed buffer pairs per GAT layer (all zeroed by the one big memset)
    float* ES1    = (float*)(ws + 145300000);    // NG*8
    float* ED1    = (float*)(ws + 146300000);    // NG*8
    float* ES2    = (float*)(ws + 147300000);    // NG*1
    float* ED2    = (float*)(ws + 147450000);
    float* ES3    = (float*)(ws + 147600000);    // NTREE*8
    float* ED3    = (float*)(ws + 148600000);
    float* ES4    = (float*)(ws + 149600000);    // NTREE*1
    float* ED4    = (float*)(ws + 149750000);    // -> 149870000
    float* MEANB  = (float*)(ws + 156700000);    // [NB][100] fp32
    u16*   XG_B   = (u16*)(ws + 157000000);      // 7.68 MB [NG][128]
    u16*   GFEAT1 = (u16*)(ws + 165000000);      // 30.72 MB [NG][512] -> 195.72
    // GAT weight arena (persistent; converted once up front)
    u16*   W_G1a  = (u16*)(ws + 196000000);      // [512][128]
    u16*   W_G2a  = (u16*)(ws + 196131072);      // [100][512]
    u16*   W_G1b  = (u16*)(ws + 196233472);      // [800][128]
    u16*   W_G2b  = (u16*)(ws + 196438272);      // [100][800] -> 196598272
    // overlays (regions dead by the time they're written):
    u16*   GOUT1B = (u16*)(ws + 25000000);       // 30.72 MB (over ETAB_G, dead after GRU)
    u16*   GFEAT2 = (u16*)(ws + 56000000);       // 6 MB [NG][100]
    u16*   TFEAT1 = (u16*)(ws + 25000000);       // 48 MB [NTREE][800] (after graph GATs)
    u16*   TOUT1B = (u16*)(ws + 74000000);       // 48 MB (over ETAB_T/GH1B tail, dead)
    u16*   TFEAT2 = (u16*)(ws + 123000000);      // 6 MB (over TH1B-tail/UE, dead)
    float* XOUT2  = (float*)(ws + 157000000);    // 12 MB (over XG_B/GFEAT1-head, dead)

    // GRU weight arena slots (u16 element offsets)
    u16* gWHH0  = WARENA + 0;        // 6 x [336][128]
    u16* gWIH1  = WARENA + 43008;
    u16* gWHH1  = WARENA + 86016;
    u16* tWHH0  = WARENA + 129024;
    u16* tWIH1  = WARENA + 172032;
    u16* tWHH1  = WARENA + 215040;
    u16* W_IH0A = WARENA + 258048;   // [448][128] interleaved-row Etab weights
    u16* W_IH0B = WARENA + 315392;

    auto mfma = [&](const u16* A, int lda, const u16* W, int ldw,
                    float* Cf, u16* Cb, int ldc, int M, int N, int Kt,
                    const float* as = nullptr, const float* ad = nullptr,
                    float* es = nullptr, float* ed = nullptr,
                    int heads = 1, int Cc = 1) {
        dim3 grid((M + 63) / 64, (N + 63) / 64, 1);
        gemm_mfma<<<grid, 256, 0, stream>>>(A, W, Cf, Cb, M, N, Kt, lda, ldw, ldc,
                                            as, ad, es, ed, heads, Cc);
    };

    // ---- 1. ALL converts in one launch ----
    {
        CvtAll P;
        P.temb = temb; P.tembB = TEMB_B;
        P.gsrc[0] = gW[0][1]; P.gbias[0] = gW[0][3]; P.gdst[0] = gWHH0;
        P.gsrc[1] = gW[1][0]; P.gbias[1] = gW[1][2]; P.gdst[1] = gWIH1;
        P.gsrc[2] = gW[1][1]; P.gbias[2] = gW[1][3]; P.gdst[2] = gWHH1;
        P.gsrc[3] = tW[0][1]; P.gbias[3] = tW[0][3]; P.gdst[3] = tWHH0;
        P.gsrc[4] = tW[1][0]; P.gbias[4] = tW[1][2]; P.gdst[4] = tWIH1;
        P.gsrc[5] = tW[1][1]; P.gbias[5] = tW[1][3]; P.gdst[5] = tWHH1;
        P.is[0] = gW[0][0]; P.ib[0] = gW[0][2]; P.id_[0] = W_IH0A;
        P.is[1] = tW[0][0]; P.ib[1] = tW[0][2]; P.id_[1] = W_IH0B;
        P.wsrc[0] = gc1W; P.wdst[0] = W_G1a; P.wK[0] = 100; P.wLdk[0] = 128; P.wTot[0] = 512 * 128;
        P.wsrc[1] = gc2W; P.wdst[1] = W_G2a; P.wK[1] = 512; P.wLdk[1] = 512; P.wTot[1] = 100 * 512;
        P.wsrc[2] = tc1W; P.wdst[2] = W_G1b; P.wK[2] = 100; P.wLdk[2] = 128; P.wTot[2] = 800 * 128;
        P.wsrc[3] = tc2W; P.wdst[3] = W_G2b; P.wK[3] = 800; P.wLdk[3] = 800; P.wTot[3] = 100 * 800;
        int grid = CB_TEMB + 6 * CB_GRUW + 2 * CB_IH0 + CB_WTOT;   // 27625
        convert_all<<<grid, 256, 0, stream>>>(P);
    }

    // ---- 2. Etab build (both branches, one launch) ----
    {
        dim3 ge((VOC + 63) / 64, 7, 2);
        gemm_etab<<<ge, 256, 0, stream>>>(TEMB_B, W_IH0A, W_IH0B, ETAB_G, ETAB_T);
    }

    // ---- 3. one memset: CSR cnt buffers + all es/ed buffers ----
    // range 142700000..149870000: OFF/CUR/EIDX regions are fully rewritten by
    // scan/scatter before being read, so blanket-zeroing them is harmless.
    hipMemsetAsync(GOFF, 0, 149870000 - 142700000, stream);
    {
        int tot = (EG + NG) + (ET + NTREE) + NTREE;
        csr_count2<<<(tot + 255) / 256, 256, 0, stream>>>(gei, tei, indices, GCNT, TCNT, BCNT);
        csr_scan2<<<3, 256, 0, stream>>>(GCNT, GOFF, GCUR, TCNT, TOFF, TCUR, BCNT, BOFF, BCUR);
        csr_scatter2<<<(tot + 255) / 256, 256, 0, stream>>>(gei, tei, indices,
                                                            GCUR, TCUR, BCUR, GEIDX, TEIDX, BIDX);
    }

    // ---- 4. user embed: mlp1 (K=9, pointwise) + gemm_nt (K=100) ----
    mlp1<<<(NU * HD + 255) / 256, 256, 0, stream>>>(user_feats, uW1, ub1, HID);
    {
        dim3 g1((NU + 63) / 64, (HD + 63) / 64, 1);
        gemm_nt<<<g1, 256, 0, stream>>>(HID, uW2, ub2, UE, NU, HD, HD, 0);
    }

    // ---- 5. combined GRU (both branches, one launch, 32 rows/block) ----
    {
        GruProb Pg = { ETAB_G, gnf, h0g, gWHH0, gWIH1, gWHH1, GH1B, NTG };
        GruProb Pt = { ETAB_T, tnf, h0t, tWHH0, tWIH1, tWHH1, TH1B, NTREE };
        int gblk = (NTG + 31) / 32;      // 313
        int tblk = (NTREE + 31) / 32;    // 938
        gru_fused10<<<gblk + tblk, 448, 0, stream>>>(Pg, Pt, gblk);
    }

    // ---- 6. graph GAT chain ----
    build_xg_bf<<<(NG * 128 + 255) / 256, 256, 0, stream>>>(GH1B, UE, XG_B);
    {   // graph GAT1: 8 heads x 64 (es/ed fused into GEMM epilogue)
        mfma(XG_B, 128, W_G1a, 128, nullptr, GFEAT1, 512, NG, 512, 4,
             gc1as, gc1ad, ES1, ED1, 8, 64);
        gat_fused<64, 8, 8, 1><<<(NG + 3) / 4, 256, 0, stream>>>(
            GOFF, GEIDX, gei, EG, ES1, ED1, GFEAT1, gc1b, nullptr, GOUT1B, NG, 512);
    }
    {   // graph GAT2: 1 head x 100
        mfma(GOUT1B, 512, W_G2a, 512, nullptr, GFEAT2, 100, NG, 100, 16,
             gc2as, gc2ad, ES2, ED2, 1, 100);
        gat_fused<100, 2, 1, 1><<<(NG + 3) / 4, 256, 0, stream>>>(
            GOFF, GEIDX, gei, EG, ES2, ED2, GFEAT2, gc2b, XGF, nullptr, NG, 100);
    }

    // ---- 7. tree GAT chain ----
    set_roots<<<(NB * HD + 255) / 256, 256, 0, stream>>>(XGF, TH1B);
    {   // tree GAT1: 8 heads x 100
        mfma(TH1B, 128, W_G1b, 128, nullptr, TFEAT1, 800, NTREE, 800, 4,
             tc1as, tc1ad, ES3, ED3, 8, 100);
        gat_fused<100, 8, 8, 2><<<(NTREE * 2 + 3) / 4, 256, 0, stream>>>(
            TOFF, TEIDX, tei, ET, ES3, ED3, TFEAT1, tc1b, nullptr, TOUT1B, NTREE, 800);
    }
    {   // tree GAT2: 1 head x 100
        mfma(TOUT1B, 800, W_G2b, 800, nullptr, TFEAT2, 100, NTREE, 100, 25,
             tc2as, tc2ad, ES4, ED4, 1, 100);
        gat_fused<100, 2, 1, 1><<<(NTREE + 3) / 4, 256, 0, stream>>>(
            TOFF, TEIDX, tei, ET, ES4, ED4, TFEAT2, tc2b, XOUT2, nullptr, NTREE, 100);
    }

    // ---- 8. batch-CSR scatter-mean + classifier ----
    scatter_mean_csr<<<NB, 256, 0, stream>>>(BOFF, BIDX, XOUT2, MEANB);
    fc_out2<<<1, 512, 0, stream>>>(MEANB, fcW, fcb, out);
}

// Round 10
// 1400.072 us; speedup vs baseline: 1.3000x; 1.0169x over previous
//
#include <hip/hip_runtime.h>

// ---------------------------------------------------------------------------
// Problem constants
// ---------------------------------------------------------------------------
#define NB    128
#define HD    100
#define NU    20000
#define NTG   10000
#define NTREE 30000
#define NG    30000
#define TT    20
#define EG    200000
#define ET    60000
#define VOC   50000

#define ESTR2 448   // interleaved Etab row stride in u16: [112 cols][4] (r,z,n,pad)
#define LOG2E  1.4426950408889634f
#define LOG2E2 2.8853900817779268f

typedef unsigned short u16;
typedef unsigned int   u32;
typedef __attribute__((ext_vector_type(8))) short short8;
typedef __attribute__((ext_vector_type(4))) float floatx4;

// gate pre-activations arrive PRE-SCALED by log2e (r,z) / 2log2e (n)
__device__ __forceinline__ float sigmoid2_(float y) {
    return __fdividef(1.f, 1.f + __builtin_amdgcn_exp2f(-y));
}
__device__ __forceinline__ float tanh2_(float y) {
    return 1.f - __fdividef(2.f, __builtin_amdgcn_exp2f(y) + 1.f);
}
__device__ __forceinline__ u16 f2bf(float f) {
    u32 u = __float_as_uint(f);
    u32 r = (u + 0x7fffu + ((u >> 16) & 1u)) >> 16;
    return (u16)r;
}
__device__ __forceinline__ u16 f2bf_c(float f) {
    u32 r;
    asm("v_cvt_pk_bf16_f32 %0, %1, %2" : "=v"(r) : "v"(f), "v"(f));
    return (u16)r;
}
__device__ __forceinline__ float bf2f(u16 h) {
    return __uint_as_float(((u32)h) << 16);
}

// ---------------------------------------------------------------------------
// Fused 2-layer GRU v12 — PERSISTENT blocks: 256 blocks (1/CU), each loops
// over ~5 tiles of 32 rows with register-resident weights loaded ONCE.
// vs v10 (588 µs): removes 3.9x redundant per-block setup (258 KB weight
// fragment reload, 32 KB LDS zeroing) + inter-round launch skew. Inner step
// structure byte-identical to the proven v10. 64-row tiles spill — do not retry.
// Per-tile re-init: only NID + h0 (combines rewrite cols 0..99 every step;
// cols 100..127 / bias slot written once, never touched after).
// ---------------------------------------------------------------------------
struct GruProb {
    const u16*   Etab;     // [VOC][112][4] interleaved, pre-scaled
    const int*   nodes;    // [M][TT]
    const float* h0;       // [2][M][100] fp32
    const u16*   Whh0;     // [336][128] gate-padded, scaled (col100 = bhh0)
    const u16*   Wih1;
    const u16*   Whh1;
    u16*         hout;     // [M][128]
    int          M;
};

__global__ __launch_bounds__(448, 2) void gru_fused12(GruProb Pg, GruProb Pt, int gB)
{
    const bool isg = (int)blockIdx.x < gB;
    const GruProb P = isg ? Pg : Pt;
    const int nb = isg ? gB : ((int)gridDim.x - gB);   // blocks in my branch
    const int bl = isg ? (int)blockIdx.x : (int)blockIdx.x - gB;
    const int M  = P.M;
    const int ntiles = (M + 31) / 32;

    __shared__ u16 H0[2][32 * 128];
    __shared__ u16 H1[2][32 * 128];
    __shared__ int NID[TT * 32];

    const int tid  = threadIdx.x;
    const int w    = tid >> 6, lane = tid & 63;
    const int fr   = lane & 15, quad = lane >> 4;
    const int c    = w * 16 + fr;
    const bool cok = (c < HD);

    // ---- weights: loaded ONCE per persistent block ----
    short8 Bh0[3][4], Bx1[3][4], Bh1[3][4];
#pragma unroll
    for (int g = 0; g < 3; ++g) {
        const size_t rb = (size_t)((g * 7 + w) * 16 + fr) * 128 + quad * 8;
#pragma unroll
        for (int kk = 0; kk < 4; ++kk) {
            Bh0[g][kk] = *(const short8*)(P.Whh0 + rb + kk * 32);
            Bx1[g][kk] = *(const short8*)(P.Wih1 + rb + kk * 32);
            Bh1[g][kk] = *(const short8*)(P.Whh1 + rb + kk * 32);
        }
    }

    // ---- zero H mirrors + bias slots ONCE ----
    for (int i = tid; i < 32 * 128; i += 448) {
        H0[0][i] = 0; H0[1][i] = 0; H1[0][i] = 0; H1[1][i] = 0;
    }
    __syncthreads();
    if (tid < 32) {
        int off = 200 ^ ((tid & 7) << 4);
        *(u16*)((char*)&H0[0][0] + tid * 256 + off) = 0x3F80;
        *(u16*)((char*)&H0[1][0] + tid * 256 + off) = 0x3F80;
        *(u16*)((char*)&H1[0][0] + tid * 256 + off) = 0x3F80;
        *(u16*)((char*)&H1[1][0] + tid * 256 + off) = 0x3F80;
    }
    __syncthreads();

    for (int tile = bl; tile < ntiles; tile += nb) {
        const int m0 = tile * 32;

        // ---- per-tile: stage node ids ----
        for (int i = tid; i < 32 * TT; i += 448) {
            int row = i / TT, t = i - row * TT;
            int gm = m0 + row;
            NID[t * 32 + row] = (gm < M) ? P.nodes[(size_t)gm * TT + t] : 0;
        }

        // ---- per-tile: h carry + LDS mirrors (overwrites cols 0..99) ----
        float h0f[2][4] = {{0.f,0.f,0.f,0.f},{0.f,0.f,0.f,0.f}};
        float h1f[2][4] = {{0.f,0.f,0.f,0.f},{0.f,0.f,0.f,0.f}};
        if (cok) {
#pragma unroll
            for (int rt = 0; rt < 2; ++rt)
#pragma unroll
            for (int r = 0; r < 4; ++r) {
                int row = rt * 16 + quad * 4 + r;
                int gm  = m0 + row;
                float v0 = 0.f, v1 = 0.f;
                if (gm < M) {
                    v0 = P.h0[(size_t)gm * HD + c];
                    v1 = P.h0[(size_t)(M + gm) * HD + c];
                }
                h0f[rt][r] = v0; h1f[rt][r] = v1;
                int off = (2 * c) ^ ((row & 7) << 4);
                *(u16*)((char*)&H0[0][0] + row * 256 + off) = f2bf_c(v0);
                *(u16*)((char*)&H1[0][0] + row * 256 + off) = f2bf_c(v1);
            }
        }

        u32 xlo[2][4], xhi[2][4];
        auto xpref = [&](int tn) {
            if (cok) {
#pragma unroll
                for (int rt = 0; rt < 2; ++rt)
#pragma unroll
                for (int r = 0; r < 4; ++r) {
                    int row = rt * 16 + quad * 4 + r;
                    int nd  = NID[tn * 32 + row];
                    uint2 v = *(const uint2*)(P.Etab + (size_t)nd * ESTR2 + c * 4);
                    xlo[rt][r] = v.x; xhi[rt][r] = v.y;
                }
            }
        };
        __syncthreads();      // NID + H mirrors visible
        xpref(0);

        // ---- prologue: A(0) ----
#pragma unroll
        for (int rt = 0; rt < 2; ++rt) {
            short8 a[4];
#pragma unroll
            for (int kk = 0; kk < 4; ++kk) {
                int row = rt * 16 + fr;
                int off = (kk * 64 + quad * 16) ^ ((row & 7) << 4);
                a[kk] = *(const short8*)((const char*)&H0[0][0] + row * 256 + off);
            }
            floatx4 ag[3];
#pragma unroll
            for (int g = 0; g < 3; ++g) ag[g] = (floatx4){0.f, 0.f, 0.f, 0.f};
#pragma unroll
            for (int g = 0; g < 3; ++g)
#pragma unroll
                for (int kk = 0; kk < 4; ++kk)
                    ag[g] = __builtin_amdgcn_mfma_f32_16x16x32_bf16(a[kk], Bh0[g][kk], ag[g], 0, 0, 0);
            if (cok) {
#pragma unroll
                for (int r = 0; r < 4; ++r) {
                    int row = rt * 16 + quad * 4 + r;
                    float rr = sigmoid2_(bf2f((u16)xlo[rt][r]) + ag[0][r]);
                    float zz = sigmoid2_(bf2f((u16)(xlo[rt][r] >> 16)) + ag[1][r]);
                    float nn = tanh2_(bf2f((u16)xhi[rt][r]) + rr * ag[2][r]);
                    float o  = nn + zz * (h0f[rt][r] - nn);
                    h0f[rt][r] = o;
                    *(u16*)((char*)&H0[1][0] + row * 256 + ((2 * c) ^ ((row & 7) << 4))) = f2bf_c(o);
                }
            }
        }
        __syncthreads();

        // ---- regions r = 0..TT-1: B(r) + A(r+1) ----
        for (int r = 0; r < TT; ++r) {
            const bool doA = (r + 1 < TT);
            if (doA) xpref(r + 1);

            const char* rd0 = (const char*)&H0[(r + 1) & 1][0];
            const char* rd1 = (const char*)&H1[r & 1][0];
            char*       wr0 = (char*)&H0[r & 1][0];
            char*       wr1 = (char*)&H1[(r + 1) & 1][0];

#pragma unroll
            for (int rt = 0; rt < 2; ++rt) {
                short8 a0[4], a1[4];
#pragma unroll
                for (int kk = 0; kk < 4; ++kk) {
                    int row = rt * 16 + fr;
                    int off = (kk * 64 + quad * 16) ^ ((row & 7) << 4);
                    a0[kk] = *(const short8*)(rd0 + row * 256 + off);
                    a1[kk] = *(const short8*)(rd1 + row * 256 + off);
                }
                floatx4 rz0 = {0.f,0.f,0.f,0.f}, rz1 = {0.f,0.f,0.f,0.f};
                floatx4 xnv = {0.f,0.f,0.f,0.f}, hnv = {0.f,0.f,0.f,0.f};
#pragma unroll
                for (int kk = 0; kk < 4; ++kk)
                    rz0 = __builtin_amdgcn_mfma_f32_16x16x32_bf16(a0[kk], Bx1[0][kk], rz0, 0, 0, 0);
#pragma unroll
                for (int kk = 0; kk < 4; ++kk)
                    rz0 = __builtin_amdgcn_mfma_f32_16x16x32_bf16(a1[kk], Bh1[0][kk], rz0, 0, 0, 0);
#pragma unroll
                for (int kk = 0; kk < 4; ++kk)
                    rz1 = __builtin_amdgcn_mfma_f32_16x16x32_bf16(a0[kk], Bx1[1][kk], rz1, 0, 0, 0);
#pragma unroll
                for (int kk = 0; kk < 4; ++kk)
                    rz1 = __builtin_amdgcn_mfma_f32_16x16x32_bf16(a1[kk], Bh1[1][kk], rz1, 0, 0, 0);
#pragma unroll
                for (int kk = 0; kk < 4; ++kk)
                    xnv = __builtin_amdgcn_mfma_f32_16x16x32_bf16(a0[kk], Bx1[2][kk], xnv, 0, 0, 0);
#pragma unroll
                for (int kk = 0; kk < 4; ++kk)
                    hnv = __builtin_amdgcn_mfma_f32_16x16x32_bf16(a1[kk], Bh1[2][kk], hnv, 0, 0, 0);
                floatx4 ag[3];
#pragma unroll
                for (int g = 0; g < 3; ++g) ag[g] = (floatx4){0.f, 0.f, 0.f, 0.f};
                if (doA) {
#pragma unroll
                    for (int g = 0; g < 3; ++g)
#pragma unroll
                        for (int kk = 0; kk < 4; ++kk)
                            ag[g] = __builtin_amdgcn_mfma_f32_16x16x32_bf16(a0[kk], Bh0[g][kk], ag[g], 0, 0, 0);
                }
                if (cok) {
#pragma unroll
                    for (int r4 = 0; r4 < 4; ++r4) {
                        int row = rt * 16 + quad * 4 + r4;
                        float rr = sigmoid2_(rz0[r4]);
                        float zz = sigmoid2_(rz1[r4]);
                        float nn = tanh2_(xnv[r4] + rr * hnv[r4]);
                        float o  = nn + zz * (h1f[rt][r4] - nn);
                        h1f[rt][r4] = o;
                        *(u16*)(wr1 + row * 256 + ((2 * c) ^ ((row & 7) << 4))) = f2bf_c(o);
                    }
                    if (doA) {
#pragma unroll
                        for (int r4 = 0; r4 < 4; ++r4) {
                            int row = rt * 16 + quad * 4 + r4;
                            float rr = sigmoid2_(bf2f((u16)xlo[rt][r4]) + ag[0][r4]);
                            float zz = sigmoid2_(bf2f((u16)(xlo[rt][r4] >> 16)) + ag[1][r4]);
                            float nn = tanh2_(bf2f((u16)xhi[rt][r4]) + rr * ag[2][r4]);
                            float o  = nn + zz * (h0f[rt][r4] - nn);
                            h0f[rt][r4] = o;
                            *(u16*)(wr0 + row * 256 + ((2 * c) ^ ((row & 7) << 4))) = f2bf_c(o);
                        }
                    }
                }
            }
            __syncthreads();
        }

        // ---- epilogue: write h1(TT-1) from H1[0] ----
        for (int i = tid; i < 32 * 128; i += 448) {
            int row = i >> 7, cc = i & 127;
            int gm = m0 + row;
            if (gm < M) {
                int off = (2 * cc) ^ ((row & 7) << 4);
                P.hout[(size_t)gm * 128 + cc] = *(const u16*)((const char*)&H1[0][0] + row * 256 + off);
            }
        }
        __syncthreads();   // protect H buffers vs next tile's init
    }
}

// ---------------------------------------------------------------------------
// bf16 MFMA GEMM (GAT feature GEMMs) with FUSED es/ed attention dots.
// ---------------------------------------------------------------------------
#define LDST 40
__global__ __launch_bounds__(256) void gemm_mfma(
    const u16* __restrict__ A, const u16* __restrict__ B,
    float* __restrict__ Cf, u16* __restrict__ Cb,
    int M, int N, int Kt, int lda, int ldw, int ldc,
    const float* __restrict__ asrc, const float* __restrict__ adst,
    float* __restrict__ es, float* __restrict__ ed, int heads, int Cc)
{
    const int m0 = blockIdx.x * 64;
    if (m0 >= M) return;
    const int n0 = blockIdx.y * 64;

    __shared__ u16 Als[64 * LDST];
    __shared__ u16 Wls[64 * LDST];

    const int tid  = threadIdx.x;
    const int wave = tid >> 6, lane = tid & 63;
    const int row  = tid >> 2, part = (tid & 3) * 8;
    const int fr   = lane & 15, quad = lane >> 4;

    floatx4 acc[4];
#pragma unroll
    for (int t = 0; t < 4; ++t) acc[t] = (floatx4){0.f, 0.f, 0.f, 0.f};

    const int am = m0 + row;  const bool aok = am < M;
    const int wn = n0 + row;  const bool wok = wn < N;
    const uint4 z4 = {0u, 0u, 0u, 0u};

    for (int kk = 0; kk < Kt; ++kk) {
        uint4 av = aok ? *(const uint4*)(A + (size_t)am * lda + kk * 32 + part) : z4;
        uint4 wv = wok ? *(const uint4*)(B + (size_t)wn * ldw + kk * 32 + part) : z4;
        __syncthreads();
        *(uint4*)&Als[row * LDST + part] = av;
        *(uint4*)&Wls[row * LDST + part] = wv;
        __syncthreads();
        short8 af = *(const short8*)&Als[((wave << 4) + fr) * LDST + quad * 8];
#pragma unroll
        for (int t = 0; t < 4; ++t) {
            short8 bf = *(const short8*)&Wls[((t << 4) + fr) * LDST + quad * 8];
            acc[t] = __builtin_amdgcn_mfma_f32_16x16x32_bf16(af, bf, acc[t], 0, 0, 0);
        }
    }

    const int orow0 = m0 + (wave << 4) + quad * 4;
#pragma unroll
    for (int t = 0; t < 4; ++t) {
        int col = n0 + (t << 4) + fr;
        if (col >= N) continue;
#pragma unroll
        for (int r = 0; r < 4; ++r) {
            int mr = orow0 + r;
            if (mr >= M) continue;
            float v = acc[t][r];
            if (Cf) Cf[(size_t)mr * ldc + col] = v;
            if (Cb) Cb[(size_t)mr * ldc + col] = f2bf(v);
        }
    }

    // ---- fused es/ed partial dots ----
    if (es) {
        const int hA = n0 / Cc;
        int hB = (n0 + 63) / Cc; if (hB > heads - 1) hB = heads - 1;
        float pse[2][4], psd[2][4];
#pragma unroll
        for (int s = 0; s < 2; ++s)
#pragma unroll
        for (int r = 0; r < 4; ++r) { pse[s][r] = 0.f; psd[s][r] = 0.f; }
#pragma unroll
        for (int t = 0; t < 4; ++t) {
            int col = n0 + (t << 4) + fr;
            if (col >= N) continue;
            int h = col / Cc;
            int slot = (h != hA);
            float as = asrc[h * Cc + (col - h * Cc)];
            float ad = adst[h * Cc + (col - h * Cc)];
#pragma unroll
            for (int r = 0; r < 4; ++r) {
                pse[slot][r] += acc[t][r] * as;
                psd[slot][r] += acc[t][r] * ad;
            }
        }
#pragma unroll
        for (int o = 1; o < 16; o <<= 1) {
#pragma unroll
            for (int s = 0; s < 2; ++s)
#pragma unroll
            for (int r = 0; r < 4; ++r) {
                pse[s][r] += __shfl_xor(pse[s][r], o);
                psd[s][r] += __shfl_xor(psd[s][r], o);
            }
        }
        if (fr == 0) {
#pragma unroll
            for (int r = 0; r < 4; ++r) {
                int mr = orow0 + r;
                if (mr >= M) continue;
                atomicAdd(&es[(size_t)mr * heads + hA], pse[0][r]);
                atomicAdd(&ed[(size_t)mr * heads + hA], psd[0][r]);
                if (hB != hA) {
                    atomicAdd(&es[(size_t)mr * heads + hB], pse[1][r]);
                    atomicAdd(&ed[(size_t)mr * heads + hB], psd[1][r]);
                }
            }
        }
    }
}

// Dual Etab build: z selects (W,C). W rows pre-ordered (r,z,n,pad)-interleaved.
__global__ __launch_bounds__(256) void gemm_etab(
    const u16* __restrict__ A, const u16* __restrict__ W0, const u16* __restrict__ W1,
    u16* __restrict__ C0, u16* __restrict__ C1)
{
    const int m0 = blockIdx.x * 64;
    const int n0 = blockIdx.y * 64;
    const u16* B = blockIdx.z ? W1 : W0;
    u16* Cb = blockIdx.z ? C1 : C0;
    const int N = 400;

    __shared__ u16 Als[64 * LDST];
    __shared__ u16 Wls[64 * LDST];

    const int tid  = threadIdx.x;
    const int wave = tid >> 6, lane = tid & 63;
    const int row  = tid >> 2, part = (tid & 3) * 8;
    const int fr   = lane & 15, quad = lane >> 4;

    floatx4 acc[4];
#pragma unroll
    for (int t = 0; t < 4; ++t) acc[t] = (floatx4){0.f, 0.f, 0.f, 0.f};

    const int am = m0 + row;
    const int wn = n0 + row;  const bool wok = wn < N;
    const uint4 z4 = {0u, 0u, 0u, 0u};

    for (int kk = 0; kk < 4; ++kk) {
        uint4 av = *(const uint4*)(A + (size_t)am * 128 + kk * 32 + part);
        uint4 wv = wok ? *(const uint4*)(B + (size_t)wn * 128 + kk * 32 + part) : z4;
        __syncthreads();
        *(uint4*)&Als[row * LDST + part] = av;
        *(uint4*)&Wls[row * LDST + part] = wv;
        __syncthreads();
        short8 af = *(const short8*)&Als[((wave << 4) + fr) * LDST + quad * 8];
#pragma unroll
        for (int t = 0; t < 4; ++t) {
            short8 bf = *(const short8*)&Wls[((t << 4) + fr) * LDST + quad * 8];
            acc[t] = __builtin_amdgcn_mfma_f32_16x16x32_bf16(af, bf, acc[t], 0, 0, 0);
        }
    }

    const int orow0 = m0 + (wave << 4) + quad * 4;
#pragma unroll
    for (int t = 0; t < 4; ++t) {
        int col = n0 + (t << 4) + fr;
        if (col >= N) continue;
#pragma unroll
        for (int r = 0; r < 4; ++r)
            Cb[(size_t)(orow0 + r) * ESTR2 + col] = f2bf(acc[t][r]);
    }
}

// ---------------------------------------------------------------------------
// fp32 tiled GEMM (user-embed MLP layer 2 only)
// ---------------------------------------------------------------------------
__global__ __launch_bounds__(256) void gemm_nt(
    const float* __restrict__ A, const float* __restrict__ W,
    const float* __restrict__ bias, float* __restrict__ C,
    int M, int N, int K, int relu)
{
    const int m0 = blockIdx.x * 64;
    const int n0 = blockIdx.y * 64;
    __shared__ float As[20][68];
    __shared__ float Ws[20][68];
    const int tid = threadIdx.x;
    const int r0 = (tid >> 4) * 4;
    const int c0 = (tid & 15) * 4;
    int sr[5], sk[5];
#pragma unroll
    for (int it = 0; it < 5; ++it) {
        int idx = tid + it * 256;
        sr[it] = idx / 20; sk[it] = idx - sr[it] * 20;
    }
    float acc[4][4];
#pragma unroll
    for (int i = 0; i < 4; ++i)
#pragma unroll
        for (int j = 0; j < 4; ++j) acc[i][j] = 0.f;
    const int nch = (K + 19) / 20;
    for (int ch = 0; ch < nch; ++ch) {
        const int k0 = ch * 20;
#pragma unroll
        for (int it = 0; it < 5; ++it) {
            int m = m0 + sr[it], k = k0 + sk[it];
            float va = 0.f, vw = 0.f;
            if (k < K) {
                if (m < M) va = A[(size_t)m * K + k];
                int n = n0 + sr[it];
                if (n < N) vw = W[(size_t)n * K + k];
            }
            As[sk[it]][sr[it]] = va;
            Ws[sk[it]][sr[it]] = vw;
        }
        __syncthreads();
#pragma unroll
        for (int kkk = 0; kkk < 20; ++kkk) {
            float4 a = *(const float4*)&As[kkk][r0];
            float4 w = *(const float4*)&Ws[kkk][c0];
            float av[4] = {a.x, a.y, a.z, a.w};
            float wv[4] = {w.x, w.y, w.z, w.w};
#pragma unroll
            for (int i = 0; i < 4; ++i)
#pragma unroll
                for (int j = 0; j < 4; ++j)
                    acc[i][j] = fmaf(av[i], wv[j], acc[i][j]);
        }
        __syncthreads();
    }
#pragma unroll
    for (int i = 0; i < 4; ++i) {
        int m = m0 + r0 + i;
        if (m >= M) continue;
#pragma unroll
        for (int j = 0; j < 4; ++j) {
            int n = n0 + c0 + j;
            if (n >= N) continue;
            float v = acc[i][j] + (bias ? bias[n] : 0.f);
            if (relu) v = fmaxf(v, 0.f);
            C[(size_t)m * N + n] = v;
        }
    }
}

// MLP layer 1: K=9, one thread per output, relu.
__global__ void mlp1(const float* __restrict__ uf, const float* __restrict__ W,
                     const float* __restrict__ b, float* __restrict__ out)
{
    int t = blockIdx.x * blockDim.x + threadIdx.x;
    if (t >= NU * HD) return;
    int n = t / HD, j = t - n * HD;
    const float* ur = uf + (size_t)n * 9;
    const float* wr = W + (size_t)j * 9;
    float acc = b[j];
#pragma unroll
    for (int k = 0; k < 9; ++k) acc = fmaf(ur[k], wr[k], acc);
    out[t] = fmaxf(acc, 0.f);
}

// ---------------------------------------------------------------------------
// ONE convert kernel for everything weight/table-shaped.
// ---------------------------------------------------------------------------
struct CvtAll {
    const float* temb;  u16* tembB;
    const float* gsrc[6]; const float* gbias[6]; u16* gdst[6];
    const float* is[2];   const float* ib[2];    u16* id_[2];
    const float* wsrc[4]; u16* wdst[4];
    int wK[4]; int wLdk[4]; int wTot[4];
};
#define CB_TEMB 25000
#define CB_GRUW 168
#define CB_IH0  224
#define CB_WTOT 1169   // 256 + 200 + 400 + 313

__global__ void convert_all(CvtAll P)
{
    int b = blockIdx.x;
    const int tid = threadIdx.x;
    if (b < CB_TEMB) {
        int t = b * 256 + tid;
        int n = t >> 7, c = t & 127;
        u16 o = 0;
        if (c < 100) o = f2bf(P.temb[(size_t)n * 100 + c]);
        else if (c == 100) o = 0x3F80;
        P.tembB[t] = o;
        return;
    }
    b -= CB_TEMB;
    if (b < 6 * CB_GRUW) {
        int mat = b / CB_GRUW;
        int t = (b - mat * CB_GRUW) * 256 + tid;
        int rr = t >> 7, cc = t & 127;
        int g = rr / 112, r2 = rr - g * 112;
        u16 o = 0;
        if (r2 < 100) {
            float sc = (g == 2) ? LOG2E2 : LOG2E;
            int sr = g * 100 + r2;
            if (cc < 100) o = f2bf(P.gsrc[mat][(size_t)sr * 100 + cc] * sc);
            else if (cc == 100) o = f2bf(P.gbias[mat][sr] * sc);
        }
        P.gdst[mat][t] = o;
        return;
    }
    b -= 6 * CB_GRUW;
    if (b < 2 * CB_IH0) {
        int which = b / CB_IH0;
        int t = (b - which * CB_IH0) * 256 + tid;
        int j = t >> 7, kc = t & 127;
        int cc = j >> 2, g = j & 3;
        u16 o = 0;
        if (g < 3 && cc < 100) {
            float sc = (g == 2) ? LOG2E2 : LOG2E;
            int sr = g * 100 + cc;
            if (kc < 100) o = f2bf(P.is[which][(size_t)sr * 100 + kc] * sc);
            else if (kc == 100) o = f2bf(P.ib[which][sr] * sc);
        }
        P.id_[which][t] = o;
        return;
    }
    b -= 2 * CB_IH0;
    int seg, t;
    if (b < 256)      { seg = 0; t = b * 256 + tid; }
    else if (b < 456) { seg = 1; t = (b - 256) * 256 + tid; }
    else if (b < 856) { seg = 2; t = (b - 456) * 256 + tid; }
    else              { seg = 3; t = (b - 856) * 256 + tid; }
    if (t >= P.wTot[seg]) return;
    int K = P.wK[seg], ldk = P.wLdk[seg];
    int n = t / ldk, c = t - n * ldk;
    u16 o = (c < K) ? f2bf(P.wsrc[seg][(size_t)n * K + c]) : (u16)0;
    P.wdst[seg][t] = o;
}

// xg (bf16 [NG][128]) = concat(hg[:128], ue, hg[128:])
__global__ void build_xg_bf(const u16* __restrict__ hgb, const float* __restrict__ ue,
                            u16* __restrict__ xgb)
{
    int t = blockIdx.x * blockDim.x + threadIdx.x;
    if (t >= NG * 128) return;
    int n = t >> 7, c = t & 127;
    u16 o = 0;
    if (n < NB)           o = hgb[n * 128 + c];
    else if (n < NB + NU) { if (c < HD) o = f2bf(ue[(size_t)(n - NB) * HD + c]); }
    else                  o = hgb[(size_t)(n - NU) * 128 + c];
    xgb[t] = o;
}

__global__ void set_roots(const float* __restrict__ src, u16* __restrict__ hb)
{
    int t = blockIdx.x * blockDim.x + threadIdx.x;
    if (t >= NB * HD) return;
    int n = t / HD, c = t - n * HD;
    hb[(size_t)n * 128 + c] = f2bf(src[t]);
}

// ---------------------------------------------------------------------------
// CSR build — graph + tree + tree->batch map fused per phase
// ---------------------------------------------------------------------------
__global__ void csr_count2(const int* __restrict__ gei, const int* __restrict__ tei,
                           const int* __restrict__ bmap,
                           int* __restrict__ gcnt, int* __restrict__ tcnt,
                           int* __restrict__ bcnt)
{
    int e = blockIdx.x * blockDim.x + threadIdx.x;
    const int GE = EG + NG, TE = ET + NTREE;
    if (e < GE) {
        int dst = (e < EG) ? gei[EG + e] : e - EG;
        atomicAdd(&gcnt[dst], 1);
    } else if (e < GE + TE) {
        int e2 = e - GE;
        int dst = (e2 < ET) ? tei[ET + e2] : e2 - ET;
        atomicAdd(&tcnt[dst], 1);
    } else {
        int e3 = e - GE - TE;
        if (e3 >= NTREE) return;
        atomicAdd(&bcnt[bmap[e3]], 1);
    }
}

__global__ void csr_scan2(int* __restrict__ gcnt, int* __restrict__ goff, int* __restrict__ gcur,
                          int* __restrict__ tcnt, int* __restrict__ toff, int* __restrict__ tcur,
                          int* __restrict__ bcnt, int* __restrict__ boff, int* __restrict__ bcur)
{
    const int* cnt; int* off; int* cur; int N;
    if (blockIdx.x == 0)      { cnt = gcnt; off = goff; cur = gcur; N = NG; }
    else if (blockIdx.x == 1) { cnt = tcnt; off = toff; cur = tcur; N = NTREE; }
    else                      { cnt = bcnt; off = boff; cur = bcur; N = NB; }
    __shared__ int part[256];
    const int tid = threadIdx.x;
    const int per = (N + 255) / 256;
    const int i0 = tid * per;
    const int i1 = min(i0 + per, N);
    int s = 0;
    for (int i = i0; i < i1; ++i) s += cnt[i];
    part[tid] = s;
    __syncthreads();
    for (int o = 1; o < 256; o <<= 1) {
        int u = (tid >= o) ? part[tid - o] : 0;
        __syncthreads();
        part[tid] += u;
        __syncthreads();
    }
    int base = part[tid] - s;
    for (int i = i0; i < i1; ++i) {
        off[i] = base; cur[i] = base;
        base += cnt[i];
    }
    if (tid == 255) off[N] = part[255];
}

__global__ void csr_scatter2(const int* __restrict__ gei, const int* __restrict__ tei,
                             const int* __restrict__ bmap,
                             int* __restrict__ gcur, int* __restrict__ tcur,
                             int* __restrict__ bcur,
                             int* __restrict__ geidx, int* __restrict__ teidx,
                             int* __restrict__ bidx)
{
    int e = blockIdx.x * blockDim.x + threadIdx.x;
    const int GE = EG + NG, TE = ET + NTREE;
    if (e < GE) {
        int dst = (e < EG) ? gei[EG + e] : e - EG;
        int pos = atomicAdd(&gcur[dst], 1);
        geidx[pos] = e;
    } else if (e < GE + TE) {
        int e2 = e - GE;
        int dst = (e2 < ET) ? tei[ET + e2] : e2 - ET;
        int pos = atomicAdd(&tcur[dst], 1);
        teidx[pos] = e2;
    } else {
        int e3 = e - GE - TE;
        if (e3 >= NTREE) return;
        int pos = atomicAdd(&bcur[bmap[e3]], 1);
        bidx[pos] = e3;
    }
}

// ---------------------------------------------------------------------------
// Fused per-dst softmax + accumulate (es/ed come pre-computed from the GEMM).
// ---------------------------------------------------------------------------
template<int C, int VEC, int HEADS, int NCHUNK>
__global__ __launch_bounds__(256) void gat_fused(
    const int* __restrict__ off, const int* __restrict__ eidx,
    const int* __restrict__ ei, int E,
    const float* __restrict__ es, const float* __restrict__ ed,
    const u16* __restrict__ feat, const float* __restrict__ bias,
    float* __restrict__ outf, u16* __restrict__ outb,
    int N, int HC)
{
    int gt = blockIdx.x * blockDim.x + threadIdx.x;
    int wid = gt >> 6, lane = gt & 63;
    int dst = wid / NCHUNK, chunk = wid - dst * NCHUNK;
    if (dst >= N) return;
    const int e0 = off[dst], e1 = off[dst + 1];

    const int hd  = lane & (HEADS - 1);
    const int esl = lane / HEADS;
    const int EPI = 64 / HEADS;
    float edv = ed[(size_t)dst * HEADS + hd];

    float mymax = -3.4e38f;
    for (int p = e0 + esl; p < e1; p += EPI) {
        int j = eidx[p];
        int src = (j < E) ? ei[j] : (j - E);
        float e = es[(size_t)src * HEADS + hd] + edv;
        e = e > 0.f ? e : 0.2f * e;
        mymax = fmaxf(mymax, e);
    }
#pragma unroll
    for (int o = HEADS; o < 64; o <<= 1)
        mymax = fmaxf(mymax, __shfl_xor(mymax, o));

    float ssum = 0.f;
    for (int p = e0 + esl; p < e1; p += EPI) {
        int j = eidx[p];
        int src = (j < E) ? ei[j] : (j - E);
        float e = es[(size_t)src * HEADS + hd] + edv;
        e = e > 0.f ? e : 0.2f * e;
        ssum += __expf(e - mymax);
    }
#pragma unroll
    for (int o = HEADS; o < 64; o <<= 1)
        ssum += __shfl_xor(ssum, o);
    float sinv = __fdividef(1.f, ssum);

    int c0 = chunk * 64 * VEC + lane * VEC;
    int split = (c0 / C + 1) * C - c0;          // first v belonging to hhi
    int hlo = c0 / C;              if (hlo > HEADS - 1) hlo = HEADS - 1;
    int hhi = (c0 + VEC - 1) / C;  if (hhi > HEADS - 1) hhi = HEADS - 1;
    float maxlo = __shfl(mymax, hlo), sinvlo = __shfl(sinv, hlo), edlo = __shfl(edv, hlo);
    float maxhi = __shfl(mymax, hhi), sinvhi = __shfl(sinv, hhi), edhi = __shfl(edv, hhi);

    if (c0 >= HC) return;
    float acc[VEC];
#pragma unroll
    for (int v = 0; v < VEC; ++v) acc[v] = 0.f;

    for (int p = e0; p < e1; ++p) {
        int j = eidx[p];
        int src = (j < E) ? ei[j] : (j - E);
        float elo = es[(size_t)src * HEADS + hlo] + edlo;
        elo = elo > 0.f ? elo : 0.2f * elo;
        float alo = __expf(elo - maxlo) * sinvlo;
        float ahi = alo;
        if (hhi != hlo) {
            float ehi = es[(size_t)src * HEADS + hhi] + edhi;
            ehi = ehi > 0.f ? ehi : 0.2f * ehi;
            ahi = __expf(ehi - maxhi) * sinvhi;
        }
        const u16* frp = feat + (size_t)src * HC + c0;
        float fv[VEC];
        if (VEC == 8) {
            uint4 pk = *(const uint4*)frp;
            fv[0] = bf2f((u16)(pk.x & 0xffff)); fv[1] = bf2f((u16)(pk.x >> 16));
            fv[2] = bf2f((u16)(pk.y & 0xffff)); fv[3] = bf2f((u16)(pk.y >> 16));
            fv[4] = bf2f((u16)(pk.z & 0xffff)); fv[5] = bf2f((u16)(pk.z >> 16));
            fv[6] = bf2f((u16)(pk.w & 0xffff)); fv[7] = bf2f((u16)(pk.w >> 16));
        } else {
            u32 pk = *(const u32*)frp;
            fv[0] = bf2f((u16)(pk & 0xffff)); fv[1] = bf2f((u16)(pk >> 16));
        }
#pragma unroll
        for (int v = 0; v < VEC; ++v) {
            float a = (v < split) ? alo : ahi;
            acc[v] += fv[v] * a;
        }
    }
#pragma unroll
    for (int v = 0; v < VEC; ++v) {
        int c = c0 + v;
        if (c >= HC) continue;
        float o = fmaxf(acc[v] + bias[c], 0.f);
        if (outf) outf[(size_t)dst * HC + c] = o;
        if (outb) outb[(size_t)dst * HC + c] = f2bf(o);
    }
}

// Batch-CSR scatter-mean: 1 block per batch, no atomics, no memsets.
__global__ void scatter_mean_csr(const int* __restrict__ boff, const int* __restrict__ bidx,
                                 const float* __restrict__ x, float* __restrict__ meanb)
{
    int b = blockIdx.x;                  // NB blocks, 256 threads
    int tid = threadIdx.x;
    int c = tid & 127, half = tid >> 7;
    __shared__ float partial[256];
    int i0 = boff[b], i1 = boff[b + 1];
    float acc = 0.f;
    if (c < HD) {
        for (int i = i0 + half; i < i1; i += 2)
            acc += x[(size_t)bidx[i] * HD + c];
    }
    partial[tid] = acc;
    __syncthreads();
    if (half == 0 && c < HD) {
        float tot = partial[tid] + partial[tid + 128];
        float cnt = (float)(i1 - i0);
        meanb[b * HD + c] = tot * __fdividef(1.f, fmaxf(cnt, 1.f));
    }
}

__global__ void fc_out2(const float* __restrict__ meanb, const float* __restrict__ W,
                        const float* __restrict__ b, float* __restrict__ out)
{
    int t = threadIdx.x;                 // 512 threads
    int bb = t >> 2, j = t & 3;
    float acc = b[j];
    for (int k = 0; k < HD; ++k) acc += meanb[bb * HD + k] * W[j * HD + k];
    out[t] = acc;
}

// ---------------------------------------------------------------------------
// Host launcher
// ---------------------------------------------------------------------------
extern "C" void kernel_launch(void* const* d_in, const int* in_sizes, int n_in,
                              void* d_out, int out_size, void* d_ws, size_t ws_size,
                              hipStream_t stream)
{
    const float* user_feats = (const float*)d_in[1];
    const int*   gnf        = (const int*)d_in[2];
    const int*   gei        = (const int*)d_in[3];
    const int*   tnf        = (const int*)d_in[4];
    const int*   tei        = (const int*)d_in[5];
    const int*   indices    = (const int*)d_in[6];
    const float* h0g        = (const float*)d_in[7];
    const float* h0t        = (const float*)d_in[8];
    const float* temb       = (const float*)d_in[9];
    const float* gW[2][4] = {{(const float*)d_in[10], (const float*)d_in[11], (const float*)d_in[12], (const float*)d_in[13]},
                             {(const float*)d_in[14], (const float*)d_in[15], (const float*)d_in[16], (const float*)d_in[17]}};
    const float* tW[2][4] = {{(const float*)d_in[18], (const float*)d_in[19], (const float*)d_in[20], (const float*)d_in[21]},
                             {(const float*)d_in[22], (const float*)d_in[23], (const float*)d_in[24], (const float*)d_in[25]}};
    const float* uW1 = (const float*)d_in[26]; const float* ub1 = (const float*)d_in[27];
    const float* uW2 = (const float*)d_in[28]; const float* ub2 = (const float*)d_in[29];
    const float* gc1W = (const float*)d_in[30]; const float* gc1as = (const float*)d_in[31];
    const float* gc1ad = (const float*)d_in[32]; const float* gc1b = (const float*)d_in[33];
    const float* gc2W = (const float*)d_in[34]; const float* gc2as = (const float*)d_in[35];
    const float* gc2ad = (const float*)d_in[36]; const float* gc2b = (const float*)d_in[37];
    const float* tc1W = (const float*)d_in[38]; const float* tc1as = (const float*)d_in[39];
    const float* tc1ad = (const float*)d_in[40]; const float* tc1b = (const float*)d_in[41];
    const float* tc2W = (const float*)d_in[42]; const float* tc2as = (const float*)d_in[43];
    const float* tc2ad = (const float*)d_in[44]; const float* tc2b = (const float*)d_in[45];
    const float* fcW = (const float*)d_in[46]; const float* fcb = (const float*)d_in[47];
    float* out = (float*)d_out;

    char* ws = (char*)d_ws;
    const size_t NEED = 226500000;
    if (ws_size < NEED) return;

    // ---- workspace layout (decimal byte offsets, overlays noted) ----
    float* XGF    = (float*)(ws + 0);            // 12 MB [NG][100] fp32
    u16*   TEMB_B = (u16*)(ws + 12000000);       // 12.8 MB [VOC][128]
    u16*   ETAB_G = (u16*)(ws + 25000000);       // 44.8 MB [VOC][448] interleaved
    u16*   ETAB_T = (u16*)(ws + 70000000);       // 44.8 MB -> 114.8
    u16*   GH1B   = (u16*)(ws + 115000000);      // 2.56 MB [NTG][128]
    u16*   TH1B   = (u16*)(ws + 117600000);      // 7.68 MB [NTREE][128]
    float* UE     = (float*)(ws + 125300000);    // 8 MB
    float* HID    = (float*)(ws + 133400000);    // 8 MB
    u16*   WARENA = (u16*)(ws + 141500000);      // GRU weight arena
    int*   GOFF   = (int*)(ws + 142700000);
    int*   GCUR   = (int*)(ws + 142900000);
    int*   GCNT   = (int*)(ws + 143100000);      // NG ints
    int*   TCNT   = (int*)(ws + 143220000);      // NTREE ints
    int*   BCNT   = (int*)(ws + 143340000);      // NB ints
    int*   GEIDX  = (int*)(ws + 143400000);      // 0.92 MB
    int*   TOFF   = (int*)(ws + 144400000);
    int*   TCUR   = (int*)(ws + 144600000);
    int*   TEIDX  = (int*)(ws + 144800000);      // 0.36 MB -> 145160000
    int*   BOFF   = (int*)(ws + 145160000);
    int*   BCUR   = (int*)(ws + 145170000);
    int*   BIDX   = (int*)(ws + 145180000);      // 0.12 MB -> 145300000
    // es/ed buffer pairs per GAT layer (all zeroed by the one big memset)
    float* ES1    = (float*)(ws + 145300000);    // NG*8
    float* ED1    = (float*)(ws + 146300000);    // NG*8
    float* ES2    = (float*)(ws + 147300000);    // NG*1
    float* ED2    = (float*)(ws + 147450000);
    float* ES3    = (float*)(ws + 147600000);    // NTREE*8
    float* ED3    = (float*)(ws + 148600000);
    float* ES4    = (float*)(ws + 149600000);    // NTREE*1
    float* ED4    = (float*)(ws + 149750000);    // -> 149870000
    float* MEANB  = (float*)(ws + 156700000);    // [NB][100] fp32
    u16*   XG_B   = (u16*)(ws + 157000000);      // 7.68 MB [NG][128]
    u16*   GFEAT1 = (u16*)(ws + 165000000);      // 30.72 MB [NG][512] -> 195.72
    // GAT weight arena (persistent; converted once up front)
    u16*   W_G1a  = (u16*)(ws + 196000000);      // [512][128]
    u16*   W_G2a  = (u16*)(ws + 196131072);      // [100][512]
    u16*   W_G1b  = (u16*)(ws + 196233472);      // [800][128]
    u16*   W_G2b  = (u16*)(ws + 196438272);      // [100][800] -> 196598272
    // overlays (regions dead by the time they're written):
    u16*   GOUT1B = (u16*)(ws + 25000000);       // 30.72 MB (over ETAB_G, dead after GRU)
    u16*   GFEAT2 = (u16*)(ws + 56000000);       // 6 MB [NG][100]
    u16*   TFEAT1 = (u16*)(ws + 25000000);       // 48 MB [NTREE][800] (after graph GATs)
    u16*   TOUT1B = (u16*)(ws + 74000000);       // 48 MB (over ETAB_T/GH1B tail, dead)
    u16*   TFEAT2 = (u16*)(ws + 123000000);      // 6 MB (over TH1B-tail/UE, dead)
    float* XOUT2  = (float*)(ws + 157000000);    // 12 MB (over XG_B/GFEAT1-head, dead)

    // GRU weight arena slots (u16 element offsets)
    u16* gWHH0  = WARENA + 0;        // 6 x [336][128]
    u16* gWIH1  = WARENA + 43008;
    u16* gWHH1  = WARENA + 86016;
    u16* tWHH0  = WARENA + 129024;
    u16* tWIH1  = WARENA + 172032;
    u16* tWHH1  = WARENA + 215040;
    u16* W_IH0A = WARENA + 258048;   // [448][128] interleaved-row Etab weights
    u16* W_IH0B = WARENA + 315392;

    auto mfma = [&](const u16* A, int lda, const u16* W, int ldw,
                    float* Cf, u16* Cb, int ldc, int M, int N, int Kt,
                    const float* as = nullptr, const float* ad = nullptr,
                    float* es = nullptr, float* ed = nullptr,
                    int heads = 1, int Cc = 1) {
        dim3 grid((M + 63) / 64, (N + 63) / 64, 1);
        gemm_mfma<<<grid, 256, 0, stream>>>(A, W, Cf, Cb, M, N, Kt, lda, ldw, ldc,
                                            as, ad, es, ed, heads, Cc);
    };

    // ---- 1. ALL converts in one launch ----
    {
        CvtAll P;
        P.temb = temb; P.tembB = TEMB_B;
        P.gsrc[0] = gW[0][1]; P.gbias[0] = gW[0][3]; P.gdst[0] = gWHH0;
        P.gsrc[1] = gW[1][0]; P.gbias[1] = gW[1][2]; P.gdst[1] = gWIH1;
        P.gsrc[2] = gW[1][1]; P.gbias[2] = gW[1][3]; P.gdst[2] = gWHH1;
        P.gsrc[3] = tW[0][1]; P.gbias[3] = tW[0][3]; P.gdst[3] = tWHH0;
        P.gsrc[4] = tW[1][0]; P.gbias[4] = tW[1][2]; P.gdst[4] = tWIH1;
        P.gsrc[5] = tW[1][1]; P.gbias[5] = tW[1][3]; P.gdst[5] = tWHH1;
        P.is[0] = gW[0][0]; P.ib[0] = gW[0][2]; P.id_[0] = W_IH0A;
        P.is[1] = tW[0][0]; P.ib[1] = tW[0][2]; P.id_[1] = W_IH0B;
        P.wsrc[0] = gc1W; P.wdst[0] = W_G1a; P.wK[0] = 100; P.wLdk[0] = 128; P.wTot[0] = 512 * 128;
        P.wsrc[1] = gc2W; P.wdst[1] = W_G2a; P.wK[1] = 512; P.wLdk[1] = 512; P.wTot[1] = 100 * 512;
        P.wsrc[2] = tc1W; P.wdst[2] = W_G1b; P.wK[2] = 100; P.wLdk[2] = 128; P.wTot[2] = 800 * 128;
        P.wsrc[3] = tc2W; P.wdst[3] = W_G2b; P.wK[3] = 800; P.wLdk[3] = 800; P.wTot[3] = 100 * 800;
        int grid = CB_TEMB + 6 * CB_GRUW + 2 * CB_IH0 + CB_WTOT;   // 27625
        convert_all<<<grid, 256, 0, stream>>>(P);
    }

    // ---- 2. Etab build (both branches, one launch) ----
    {
        dim3 ge((VOC + 63) / 64, 7, 2);
        gemm_etab<<<ge, 256, 0, stream>>>(TEMB_B, W_IH0A, W_IH0B, ETAB_G, ETAB_T);
    }

    // ---- 3. one memset: CSR cnt buffers + all es/ed buffers ----
    hipMemsetAsync(GOFF, 0, 149870000 - 142700000, stream);
    {
        int tot = (EG + NG) + (ET + NTREE) + NTREE;
        csr_count2<<<(tot + 255) / 256, 256, 0, stream>>>(gei, tei, indices, GCNT, TCNT, BCNT);
        csr_scan2<<<3, 256, 0, stream>>>(GCNT, GOFF, GCUR, TCNT, TOFF, TCUR, BCNT, BOFF, BCUR);
        csr_scatter2<<<(tot + 255) / 256, 256, 0, stream>>>(gei, tei, indices,
                                                            GCUR, TCUR, BCUR, GEIDX, TEIDX, BIDX);
    }

    // ---- 4. user embed: mlp1 (K=9, pointwise) + gemm_nt (K=100) ----
    mlp1<<<(NU * HD + 255) / 256, 256, 0, stream>>>(user_feats, uW1, ub1, HID);
    {
        dim3 g1((NU + 63) / 64, (HD + 63) / 64, 1);
        gemm_nt<<<g1, 256, 0, stream>>>(HID, uW2, ub2, UE, NU, HD, HD, 0);
    }

    // ---- 5. combined GRU: PERSISTENT 256 blocks (1/CU), weights loaded once ----
    {
        GruProb Pg = { ETAB_G, gnf, h0g, gWHH0, gWIH1, gWHH1, GH1B, NTG };
        GruProb Pt = { ETAB_T, tnf, h0t, tWHH0, tWIH1, tWHH1, TH1B, NTREE };
        const int gtiles = (NTG + 31) / 32;      // 313
        const int ttiles = (NTREE + 31) / 32;    // 938
        const int NBLK = 256;
        int GB = (NBLK * gtiles + (gtiles + ttiles) / 2) / (gtiles + ttiles);  // ~64
        if (GB < 1) GB = 1;
        if (GB > NBLK - 1) GB = NBLK - 1;
        gru_fused12<<<NBLK, 448, 0, stream>>>(Pg, Pt, GB);
    }

    // ---- 6. graph GAT chain ----
    build_xg_bf<<<(NG * 128 + 255) / 256, 256, 0, stream>>>(GH1B, UE, XG_B);
    {   // graph GAT1: 8 heads x 64 (es/ed fused into GEMM epilogue)
        mfma(XG_B, 128, W_G1a, 128, nullptr, GFEAT1, 512, NG, 512, 4,
             gc1as, gc1ad, ES1, ED1, 8, 64);
        gat_fused<64, 8, 8, 1><<<(NG + 3) / 4, 256, 0, stream>>>(
            GOFF, GEIDX, gei, EG, ES1, ED1, GFEAT1, gc1b, nullptr, GOUT1B, NG, 512);
    }
    {   // graph GAT2: 1 head x 100
        mfma(GOUT1B, 512, W_G2a, 512, nullptr, GFEAT2, 100, NG, 100, 16,
             gc2as, gc2ad, ES2, ED2, 1, 100);
        gat_fused<100, 2, 1, 1><<<(NG + 3) / 4, 256, 0, stream>>>(
            GOFF, GEIDX, gei, EG, ES2, ED2, GFEAT2, gc2b, XGF, nullptr, NG, 100);
    }

    // ---- 7. tree GAT chain ----
    set_roots<<<(NB * HD + 255) / 256, 256, 0, stream>>>(XGF, TH1B);
    {   // tree GAT1: 8 heads x 100
        mfma(TH1B, 128, W_G1b, 128, nullptr, TFEAT1, 800, NTREE, 800, 4,
             tc1as, tc1ad, ES3, ED3, 8, 100);
        gat_fused<100, 8, 8, 2><<<(NTREE * 2 + 3) / 4, 256, 0, stream>>>(
            TOFF, TEIDX, tei, ET, ES3, ED3, TFEAT1, tc1b, nullptr, TOUT1B, NTREE, 800);
    }
    {   // tree GAT2: 1 head x 100
        mfma(TOUT1B, 800, W_G2b, 800, nullptr, TFEAT2, 100, NTREE, 100, 25,
             tc2as, tc2ad, ES4, ED4, 1, 100);
        gat_fused<100, 2, 1, 1><<<(NTREE + 3) / 4, 256, 0, stream>>>(
            TOFF, TEIDX, tei, ET, ES4, ED4, TFEAT2, tc2b, XOUT2, nullptr, NTREE, 100);
    }

    // ---- 8. batch-CSR scatter-mean + classifier ----
    scatter_mean_csr<<<NB, 256, 0, stream>>>(BOFF, BIDX, XOUT2, MEANB);
    fc_out2<<<1, 512, 0, stream>>>(MEANB, fcW, fcb, out);
}

// Round 11
// 1387.539 us; speedup vs baseline: 1.3117x; 1.0090x over previous
//
#include <hip/hip_runtime.h>

// ---------------------------------------------------------------------------
// Problem constants
// ---------------------------------------------------------------------------
#define NB    128
#define HD    100
#define NU    20000
#define NTG   10000
#define NTREE 30000
#define NG    30000
#define TT    20
#define EG    200000
#define ET    60000
#define VOC   50000

#define ESTR2 448   // interleaved Etab row stride in u16: [112 cols][4] (r,z,n,pad)
#define LOG2E  1.4426950408889634f
#define LOG2E2 2.8853900817779268f

typedef unsigned short u16;
typedef unsigned int   u32;
typedef __attribute__((ext_vector_type(8))) short short8;
typedef __attribute__((ext_vector_type(4))) float floatx4;

// gate pre-activations arrive PRE-SCALED by log2e (r,z) / 2log2e (n)
__device__ __forceinline__ float sigmoid2_(float y) {
    return __fdividef(1.f, 1.f + __builtin_amdgcn_exp2f(-y));
}
__device__ __forceinline__ float tanh2_(float y) {
    return 1.f - __fdividef(2.f, __builtin_amdgcn_exp2f(y) + 1.f);
}
__device__ __forceinline__ u16 f2bf(float f) {
    u32 u = __float_as_uint(f);
    u32 r = (u + 0x7fffu + ((u >> 16) & 1u)) >> 16;
    return (u16)r;
}
__device__ __forceinline__ u16 f2bf_c(float f) {
    u32 r;
    asm("v_cvt_pk_bf16_f32 %0, %1, %2" : "=v"(r) : "v"(f), "v"(f));
    return (u16)r;
}
__device__ __forceinline__ float bf2f(u16 h) {
    return __uint_as_float(((u32)h) << 16);
}

// ---------------------------------------------------------------------------
// Fused 2-layer GRU v12b — PERSISTENT blocks (proven 569 µs steady), with
// hout row-remap: graph branch writes DIRECTLY into XG_B (concat layout:
// rows<128 -> row, rows>=128 -> row+padrows). Deletes build_xg_bf + GH1B.
// 64-row tiles spill — do not retry.
// ---------------------------------------------------------------------------
struct GruProb {
    const u16*   Etab;     // [VOC][112][4] interleaved, pre-scaled
    const int*   nodes;    // [M][TT]
    const float* h0;       // [2][M][100] fp32
    const u16*   Whh0;     // [336][128] gate-padded, scaled (col100 = bhh0)
    const u16*   Wih1;
    const u16*   Whh1;
    u16*         hout;     // bf16, row (gm<128 ? gm : gm+padrows) * 128
    int          M;
    int          padrows;  // NU for graph branch, 0 for tree
};

__global__ __launch_bounds__(448, 2) void gru_fused12(GruProb Pg, GruProb Pt, int gB)
{
    const bool isg = (int)blockIdx.x < gB;
    const GruProb P = isg ? Pg : Pt;
    const int nb = isg ? gB : ((int)gridDim.x - gB);
    const int bl = isg ? (int)blockIdx.x : (int)blockIdx.x - gB;
    const int M  = P.M;
    const int ntiles = (M + 31) / 32;

    __shared__ u16 H0[2][32 * 128];
    __shared__ u16 H1[2][32 * 128];
    __shared__ int NID[TT * 32];

    const int tid  = threadIdx.x;
    const int w    = tid >> 6, lane = tid & 63;
    const int fr   = lane & 15, quad = lane >> 4;
    const int c    = w * 16 + fr;
    const bool cok = (c < HD);

    // ---- weights: loaded ONCE per persistent block ----
    short8 Bh0[3][4], Bx1[3][4], Bh1[3][4];
#pragma unroll
    for (int g = 0; g < 3; ++g) {
        const size_t rb = (size_t)((g * 7 + w) * 16 + fr) * 128 + quad * 8;
#pragma unroll
        for (int kk = 0; kk < 4; ++kk) {
            Bh0[g][kk] = *(const short8*)(P.Whh0 + rb + kk * 32);
            Bx1[g][kk] = *(const short8*)(P.Wih1 + rb + kk * 32);
            Bh1[g][kk] = *(const short8*)(P.Whh1 + rb + kk * 32);
        }
    }

    // ---- zero H mirrors + bias slots ONCE ----
    for (int i = tid; i < 32 * 128; i += 448) {
        H0[0][i] = 0; H0[1][i] = 0; H1[0][i] = 0; H1[1][i] = 0;
    }
    __syncthreads();
    if (tid < 32) {
        int off = 200 ^ ((tid & 7) << 4);
        *(u16*)((char*)&H0[0][0] + tid * 256 + off) = 0x3F80;
        *(u16*)((char*)&H0[1][0] + tid * 256 + off) = 0x3F80;
        *(u16*)((char*)&H1[0][0] + tid * 256 + off) = 0x3F80;
        *(u16*)((char*)&H1[1][0] + tid * 256 + off) = 0x3F80;
    }
    __syncthreads();

    for (int tile = bl; tile < ntiles; tile += nb) {
        const int m0 = tile * 32;

        for (int i = tid; i < 32 * TT; i += 448) {
            int row = i / TT, t = i - row * TT;
            int gm = m0 + row;
            NID[t * 32 + row] = (gm < M) ? P.nodes[(size_t)gm * TT + t] : 0;
        }

        float h0f[2][4] = {{0.f,0.f,0.f,0.f},{0.f,0.f,0.f,0.f}};
        float h1f[2][4] = {{0.f,0.f,0.f,0.f},{0.f,0.f,0.f,0.f}};
        if (cok) {
#pragma unroll
            for (int rt = 0; rt < 2; ++rt)
#pragma unroll
            for (int r = 0; r < 4; ++r) {
                int row = rt * 16 + quad * 4 + r;
                int gm  = m0 + row;
                float v0 = 0.f, v1 = 0.f;
                if (gm < M) {
                    v0 = P.h0[(size_t)gm * HD + c];
                    v1 = P.h0[(size_t)(M + gm) * HD + c];
                }
                h0f[rt][r] = v0; h1f[rt][r] = v1;
                int off = (2 * c) ^ ((row & 7) << 4);
                *(u16*)((char*)&H0[0][0] + row * 256 + off) = f2bf_c(v0);
                *(u16*)((char*)&H1[0][0] + row * 256 + off) = f2bf_c(v1);
            }
        }

        u32 xlo[2][4], xhi[2][4];
        auto xpref = [&](int tn) {
            if (cok) {
#pragma unroll
                for (int rt = 0; rt < 2; ++rt)
#pragma unroll
                for (int r = 0; r < 4; ++r) {
                    int row = rt * 16 + quad * 4 + r;
                    int nd  = NID[tn * 32 + row];
                    uint2 v = *(const uint2*)(P.Etab + (size_t)nd * ESTR2 + c * 4);
                    xlo[rt][r] = v.x; xhi[rt][r] = v.y;
                }
            }
        };
        __syncthreads();
        xpref(0);

        // ---- prologue: A(0) ----
#pragma unroll
        for (int rt = 0; rt < 2; ++rt) {
            short8 a[4];
#pragma unroll
            for (int kk = 0; kk < 4; ++kk) {
                int row = rt * 16 + fr;
                int off = (kk * 64 + quad * 16) ^ ((row & 7) << 4);
                a[kk] = *(const short8*)((const char*)&H0[0][0] + row * 256 + off);
            }
            floatx4 ag[3];
#pragma unroll
            for (int g = 0; g < 3; ++g) ag[g] = (floatx4){0.f, 0.f, 0.f, 0.f};
#pragma unroll
            for (int g = 0; g < 3; ++g)
#pragma unroll
                for (int kk = 0; kk < 4; ++kk)
                    ag[g] = __builtin_amdgcn_mfma_f32_16x16x32_bf16(a[kk], Bh0[g][kk], ag[g], 0, 0, 0);
            if (cok) {
#pragma unroll
                for (int r = 0; r < 4; ++r) {
                    int row = rt * 16 + quad * 4 + r;
                    float rr = sigmoid2_(bf2f((u16)xlo[rt][r]) + ag[0][r]);
                    float zz = sigmoid2_(bf2f((u16)(xlo[rt][r] >> 16)) + ag[1][r]);
                    float nn = tanh2_(bf2f((u16)xhi[rt][r]) + rr * ag[2][r]);
                    float o  = nn + zz * (h0f[rt][r] - nn);
                    h0f[rt][r] = o;
                    *(u16*)((char*)&H0[1][0] + row * 256 + ((2 * c) ^ ((row & 7) << 4))) = f2bf_c(o);
                }
            }
        }
        __syncthreads();

        // ---- regions r = 0..TT-1: B(r) + A(r+1) ----
        for (int r = 0; r < TT; ++r) {
            const bool doA = (r + 1 < TT);
            if (doA) xpref(r + 1);

            const char* rd0 = (const char*)&H0[(r + 1) & 1][0];
            const char* rd1 = (const char*)&H1[r & 1][0];
            char*       wr0 = (char*)&H0[r & 1][0];
            char*       wr1 = (char*)&H1[(r + 1) & 1][0];

#pragma unroll
            for (int rt = 0; rt < 2; ++rt) {
                short8 a0[4], a1[4];
#pragma unroll
                for (int kk = 0; kk < 4; ++kk) {
                    int row = rt * 16 + fr;
                    int off = (kk * 64 + quad * 16) ^ ((row & 7) << 4);
                    a0[kk] = *(const short8*)(rd0 + row * 256 + off);
                    a1[kk] = *(const short8*)(rd1 + row * 256 + off);
                }
                floatx4 rz0 = {0.f,0.f,0.f,0.f}, rz1 = {0.f,0.f,0.f,0.f};
                floatx4 xnv = {0.f,0.f,0.f,0.f}, hnv = {0.f,0.f,0.f,0.f};
#pragma unroll
                for (int kk = 0; kk < 4; ++kk)
                    rz0 = __builtin_amdgcn_mfma_f32_16x16x32_bf16(a0[kk], Bx1[0][kk], rz0, 0, 0, 0);
#pragma unroll
                for (int kk = 0; kk < 4; ++kk)
                    rz0 = __builtin_amdgcn_mfma_f32_16x16x32_bf16(a1[kk], Bh1[0][kk], rz0, 0, 0, 0);
#pragma unroll
                for (int kk = 0; kk < 4; ++kk)
                    rz1 = __builtin_amdgcn_mfma_f32_16x16x32_bf16(a0[kk], Bx1[1][kk], rz1, 0, 0, 0);
#pragma unroll
                for (int kk = 0; kk < 4; ++kk)
                    rz1 = __builtin_amdgcn_mfma_f32_16x16x32_bf16(a1[kk], Bh1[1][kk], rz1, 0, 0, 0);
#pragma unroll
                for (int kk = 0; kk < 4; ++kk)
                    xnv = __builtin_amdgcn_mfma_f32_16x16x32_bf16(a0[kk], Bx1[2][kk], xnv, 0, 0, 0);
#pragma unroll
                for (int kk = 0; kk < 4; ++kk)
                    hnv = __builtin_amdgcn_mfma_f32_16x16x32_bf16(a1[kk], Bh1[2][kk], hnv, 0, 0, 0);
                floatx4 ag[3];
#pragma unroll
                for (int g = 0; g < 3; ++g) ag[g] = (floatx4){0.f, 0.f, 0.f, 0.f};
                if (doA) {
#pragma unroll
                    for (int g = 0; g < 3; ++g)
#pragma unroll
                        for (int kk = 0; kk < 4; ++kk)
                            ag[g] = __builtin_amdgcn_mfma_f32_16x16x32_bf16(a0[kk], Bh0[g][kk], ag[g], 0, 0, 0);
                }
                if (cok) {
#pragma unroll
                    for (int r4 = 0; r4 < 4; ++r4) {
                        int row = rt * 16 + quad * 4 + r4;
                        float rr = sigmoid2_(rz0[r4]);
                        float zz = sigmoid2_(rz1[r4]);
                        float nn = tanh2_(xnv[r4] + rr * hnv[r4]);
                        float o  = nn + zz * (h1f[rt][r4] - nn);
                        h1f[rt][r4] = o;
                        *(u16*)(wr1 + row * 256 + ((2 * c) ^ ((row & 7) << 4))) = f2bf_c(o);
                    }
                    if (doA) {
#pragma unroll
                        for (int r4 = 0; r4 < 4; ++r4) {
                            int row = rt * 16 + quad * 4 + r4;
                            float rr = sigmoid2_(bf2f((u16)xlo[rt][r4]) + ag[0][r4]);
                            float zz = sigmoid2_(bf2f((u16)(xlo[rt][r4] >> 16)) + ag[1][r4]);
                            float nn = tanh2_(bf2f((u16)xhi[rt][r4]) + rr * ag[2][r4]);
                            float o  = nn + zz * (h0f[rt][r4] - nn);
                            h0f[rt][r4] = o;
                            *(u16*)(wr0 + row * 256 + ((2 * c) ^ ((row & 7) << 4))) = f2bf_c(o);
                        }
                    }
                }
            }
            __syncthreads();
        }

        // ---- epilogue: write h1(TT-1) with concat row-remap ----
        for (int i = tid; i < 32 * 128; i += 448) {
            int row = i >> 7, cc = i & 127;
            int gm = m0 + row;
            if (gm < M) {
                int orow = (gm < NB) ? gm : gm + P.padrows;
                int off = (2 * cc) ^ ((row & 7) << 4);
                P.hout[(size_t)orow * 128 + cc] = *(const u16*)((const char*)&H1[0][0] + row * 256 + off);
            }
        }
        __syncthreads();
    }
}

// ---------------------------------------------------------------------------
// bf16 MFMA GEMM (GAT feature GEMMs) with FUSED es/ed attention dots.
// ---------------------------------------------------------------------------
#define LDST 40
__global__ __launch_bounds__(256) void gemm_mfma(
    const u16* __restrict__ A, const u16* __restrict__ B,
    float* __restrict__ Cf, u16* __restrict__ Cb,
    int M, int N, int Kt, int lda, int ldw, int ldc,
    const float* __restrict__ asrc, const float* __restrict__ adst,
    float* __restrict__ es, float* __restrict__ ed, int heads, int Cc)
{
    const int m0 = blockIdx.x * 64;
    if (m0 >= M) return;
    const int n0 = blockIdx.y * 64;

    __shared__ u16 Als[64 * LDST];
    __shared__ u16 Wls[64 * LDST];

    const int tid  = threadIdx.x;
    const int wave = tid >> 6, lane = tid & 63;
    const int row  = tid >> 2, part = (tid & 3) * 8;
    const int fr   = lane & 15, quad = lane >> 4;

    floatx4 acc[4];
#pragma unroll
    for (int t = 0; t < 4; ++t) acc[t] = (floatx4){0.f, 0.f, 0.f, 0.f};

    const int am = m0 + row;  const bool aok = am < M;
    const int wn = n0 + row;  const bool wok = wn < N;
    const uint4 z4 = {0u, 0u, 0u, 0u};

    for (int kk = 0; kk < Kt; ++kk) {
        uint4 av = aok ? *(const uint4*)(A + (size_t)am * lda + kk * 32 + part) : z4;
        uint4 wv = wok ? *(const uint4*)(B + (size_t)wn * ldw + kk * 32 + part) : z4;
        __syncthreads();
        *(uint4*)&Als[row * LDST + part] = av;
        *(uint4*)&Wls[row * LDST + part] = wv;
        __syncthreads();
        short8 af = *(const short8*)&Als[((wave << 4) + fr) * LDST + quad * 8];
#pragma unroll
        for (int t = 0; t < 4; ++t) {
            short8 bf = *(const short8*)&Wls[((t << 4) + fr) * LDST + quad * 8];
            acc[t] = __builtin_amdgcn_mfma_f32_16x16x32_bf16(af, bf, acc[t], 0, 0, 0);
        }
    }

    const int orow0 = m0 + (wave << 4) + quad * 4;
#pragma unroll
    for (int t = 0; t < 4; ++t) {
        int col = n0 + (t << 4) + fr;
        if (col >= N) continue;
#pragma unroll
        for (int r = 0; r < 4; ++r) {
            int mr = orow0 + r;
            if (mr >= M) continue;
            float v = acc[t][r];
            if (Cf) Cf[(size_t)mr * ldc + col] = v;
            if (Cb) Cb[(size_t)mr * ldc + col] = f2bf(v);
        }
    }

    // ---- fused es/ed partial dots ----
    if (es) {
        const int hA = n0 / Cc;
        int hB = (n0 + 63) / Cc; if (hB > heads - 1) hB = heads - 1;
        float pse[2][4], psd[2][4];
#pragma unroll
        for (int s = 0; s < 2; ++s)
#pragma unroll
        for (int r = 0; r < 4; ++r) { pse[s][r] = 0.f; psd[s][r] = 0.f; }
#pragma unroll
        for (int t = 0; t < 4; ++t) {
            int col = n0 + (t << 4) + fr;
            if (col >= N) continue;
            int h = col / Cc;
            int slot = (h != hA);
            float as = asrc[h * Cc + (col - h * Cc)];
            float ad = adst[h * Cc + (col - h * Cc)];
#pragma unroll
            for (int r = 0; r < 4; ++r) {
                pse[slot][r] += acc[t][r] * as;
                psd[slot][r] += acc[t][r] * ad;
            }
        }
#pragma unroll
        for (int o = 1; o < 16; o <<= 1) {
#pragma unroll
            for (int s = 0; s < 2; ++s)
#pragma unroll
            for (int r = 0; r < 4; ++r) {
                pse[s][r] += __shfl_xor(pse[s][r], o);
                psd[s][r] += __shfl_xor(psd[s][r], o);
            }
        }
        if (fr == 0) {
#pragma unroll
            for (int r = 0; r < 4; ++r) {
                int mr = orow0 + r;
                if (mr >= M) continue;
                atomicAdd(&es[(size_t)mr * heads + hA], pse[0][r]);
                atomicAdd(&ed[(size_t)mr * heads + hA], psd[0][r]);
                if (hB != hA) {
                    atomicAdd(&es[(size_t)mr * heads + hB], pse[1][r]);
                    atomicAdd(&ed[(size_t)mr * heads + hB], psd[1][r]);
                }
            }
        }
    }
}

// Dual Etab build: z selects (W,C). W rows pre-ordered (r,z,n,pad)-interleaved.
__global__ __launch_bounds__(256) void gemm_etab(
    const u16* __restrict__ A, const u16* __restrict__ W0, const u16* __restrict__ W1,
    u16* __restrict__ C0, u16* __restrict__ C1)
{
    const int m0 = blockIdx.x * 64;
    const int n0 = blockIdx.y * 64;
    const u16* B = blockIdx.z ? W1 : W0;
    u16* Cb = blockIdx.z ? C1 : C0;
    const int N = 400;

    __shared__ u16 Als[64 * LDST];
    __shared__ u16 Wls[64 * LDST];

    const int tid  = threadIdx.x;
    const int wave = tid >> 6, lane = tid & 63;
    const int row  = tid >> 2, part = (tid & 3) * 8;
    const int fr   = lane & 15, quad = lane >> 4;

    floatx4 acc[4];
#pragma unroll
    for (int t = 0; t < 4; ++t) acc[t] = (floatx4){0.f, 0.f, 0.f, 0.f};

    const int am = m0 + row;
    const int wn = n0 + row;  const bool wok = wn < N;
    const uint4 z4 = {0u, 0u, 0u, 0u};

    for (int kk = 0; kk < 4; ++kk) {
        uint4 av = *(const uint4*)(A + (size_t)am * 128 + kk * 32 + part);
        uint4 wv = wok ? *(const uint4*)(B + (size_t)wn * 128 + kk * 32 + part) : z4;
        __syncthreads();
        *(uint4*)&Als[row * LDST + part] = av;
        *(uint4*)&Wls[row * LDST + part] = wv;
        __syncthreads();
        short8 af = *(const short8*)&Als[((wave << 4) + fr) * LDST + quad * 8];
#pragma unroll
        for (int t = 0; t < 4; ++t) {
            short8 bf = *(const short8*)&Wls[((t << 4) + fr) * LDST + quad * 8];
            acc[t] = __builtin_amdgcn_mfma_f32_16x16x32_bf16(af, bf, acc[t], 0, 0, 0);
        }
    }

    const int orow0 = m0 + (wave << 4) + quad * 4;
#pragma unroll
    for (int t = 0; t < 4; ++t) {
        int col = n0 + (t << 4) + fr;
        if (col >= N) continue;
#pragma unroll
        for (int r = 0; r < 4; ++r)
            Cb[(size_t)(orow0 + r) * ESTR2 + col] = f2bf(acc[t][r]);
    }
}

// ---------------------------------------------------------------------------
// fp32 tiled GEMM (user-embed MLP layer 2): fp32 compute, optional direct
// bf16 store into XG_B rows (rowoff applied) — numerics identical to the
// old gemm_nt + build_xg_bf path.
// ---------------------------------------------------------------------------
__global__ __launch_bounds__(256) void gemm_nt(
    const float* __restrict__ A, const float* __restrict__ W,
    const float* __restrict__ bias, float* __restrict__ C,
    u16* __restrict__ Cb16, int rowoff,
    int M, int N, int K, int relu)
{
    const int m0 = blockIdx.x * 64;
    const int n0 = blockIdx.y * 64;
    __shared__ float As[20][68];
    __shared__ float Ws[20][68];
    const int tid = threadIdx.x;
    const int r0 = (tid >> 4) * 4;
    const int c0 = (tid & 15) * 4;
    int sr[5], sk[5];
#pragma unroll
    for (int it = 0; it < 5; ++it) {
        int idx = tid + it * 256;
        sr[it] = idx / 20; sk[it] = idx - sr[it] * 20;
    }
    float acc[4][4];
#pragma unroll
    for (int i = 0; i < 4; ++i)
#pragma unroll
        for (int j = 0; j < 4; ++j) acc[i][j] = 0.f;
    const int nch = (K + 19) / 20;
    for (int ch = 0; ch < nch; ++ch) {
        const int k0 = ch * 20;
#pragma unroll
        for (int it = 0; it < 5; ++it) {
            int m = m0 + sr[it], k = k0 + sk[it];
            float va = 0.f, vw = 0.f;
            if (k < K) {
                if (m < M) va = A[(size_t)m * K + k];
                int n = n0 + sr[it];
                if (n < N) vw = W[(size_t)n * K + k];
            }
            As[sk[it]][sr[it]] = va;
            Ws[sk[it]][sr[it]] = vw;
        }
        __syncthreads();
#pragma unroll
        for (int kkk = 0; kkk < 20; ++kkk) {
            float4 a = *(const float4*)&As[kkk][r0];
            float4 w = *(const float4*)&Ws[kkk][c0];
            float av[4] = {a.x, a.y, a.z, a.w};
            float wv[4] = {w.x, w.y, w.z, w.w};
#pragma unroll
            for (int i = 0; i < 4; ++i)
#pragma unroll
                for (int j = 0; j < 4; ++j)
                    acc[i][j] = fmaf(av[i], wv[j], acc[i][j]);
        }
        __syncthreads();
    }
#pragma unroll
    for (int i = 0; i < 4; ++i) {
        int m = m0 + r0 + i;
        if (m >= M) continue;
#pragma unroll
        for (int j = 0; j < 4; ++j) {
            int n = n0 + c0 + j;
            if (n >= N) continue;
            float v = acc[i][j] + (bias ? bias[n] : 0.f);
            if (relu) v = fmaxf(v, 0.f);
            if (C)    C[(size_t)m * N + n] = v;
            if (Cb16) Cb16[(size_t)(m + rowoff) * 128 + n] = f2bf(v);
        }
    }
}

// MLP layer 1: K=9, one thread per output, relu. Also zero-fills XG_B pad
// cols 100..127 for the UE row range (rows 128..128+NU).
__global__ void mlp1(const float* __restrict__ uf, const float* __restrict__ W,
                     const float* __restrict__ b, float* __restrict__ out,
                     u16* __restrict__ xgb)
{
    int t = blockIdx.x * blockDim.x + threadIdx.x;
    if (t >= NU * HD) return;
    int n = t / HD, j = t - n * HD;
    const float* ur = uf + (size_t)n * 9;
    const float* wr = W + (size_t)j * 9;
    float acc = b[j];
#pragma unroll
    for (int k = 0; k < 9; ++k) acc = fmaf(ur[k], wr[k], acc);
    out[t] = fmaxf(acc, 0.f);
    if (j < 28) xgb[(size_t)(NB + n) * 128 + 100 + j] = 0;
}

// ---------------------------------------------------------------------------
// ONE convert kernel for everything weight/table-shaped.
// ---------------------------------------------------------------------------
struct CvtAll {
    const float* temb;  u16* tembB;
    const float* gsrc[6]; const float* gbias[6]; u16* gdst[6];
    const float* is[2];   const float* ib[2];    u16* id_[2];
    const float* wsrc[4]; u16* wdst[4];
    int wK[4]; int wLdk[4]; int wTot[4];
};
#define CB_TEMB 25000
#define CB_GRUW 168
#define CB_IH0  224
#define CB_WTOT 1169   // 256 + 200 + 400 + 313

__global__ void convert_all(CvtAll P)
{
    int b = blockIdx.x;
    const int tid = threadIdx.x;
    if (b < CB_TEMB) {
        int t = b * 256 + tid;
        int n = t >> 7, c = t & 127;
        u16 o = 0;
        if (c < 100) o = f2bf(P.temb[(size_t)n * 100 + c]);
        else if (c == 100) o = 0x3F80;
        P.tembB[t] = o;
        return;
    }
    b -= CB_TEMB;
    if (b < 6 * CB_GRUW) {
        int mat = b / CB_GRUW;
        int t = (b - mat * CB_GRUW) * 256 + tid;
        int rr = t >> 7, cc = t & 127;
        int g = rr / 112, r2 = rr - g * 112;
        u16 o = 0;
        if (r2 < 100) {
            float sc = (g == 2) ? LOG2E2 : LOG2E;
            int sr = g * 100 + r2;
            if (cc < 100) o = f2bf(P.gsrc[mat][(size_t)sr * 100 + cc] * sc);
            else if (cc == 100) o = f2bf(P.gbias[mat][sr] * sc);
        }
        P.gdst[mat][t] = o;
        return;
    }
    b -= 6 * CB_GRUW;
    if (b < 2 * CB_IH0) {
        int which = b / CB_IH0;
        int t = (b - which * CB_IH0) * 256 + tid;
        int j = t >> 7, kc = t & 127;
        int cc = j >> 2, g = j & 3;
        u16 o = 0;
        if (g < 3 && cc < 100) {
            float sc = (g == 2) ? LOG2E2 : LOG2E;
            int sr = g * 100 + cc;
            if (kc < 100) o = f2bf(P.is[which][(size_t)sr * 100 + kc] * sc);
            else if (kc == 100) o = f2bf(P.ib[which][sr] * sc);
        }
        P.id_[which][t] = o;
        return;
    }
    b -= 2 * CB_IH0;
    int seg, t;
    if (b < 256)      { seg = 0; t = b * 256 + tid; }
    else if (b < 456) { seg = 1; t = (b - 256) * 256 + tid; }
    else if (b < 856) { seg = 2; t = (b - 456) * 256 + tid; }
    else              { seg = 3; t = (b - 856) * 256 + tid; }
    if (t >= P.wTot[seg]) return;
    int K = P.wK[seg], ldk = P.wLdk[seg];
    int n = t / ldk, c = t - n * ldk;
    u16 o = (c < K) ? f2bf(P.wsrc[seg][(size_t)n * K + c]) : (u16)0;
    P.wdst[seg][t] = o;
}

// ---------------------------------------------------------------------------
// CSR build — graph + tree + tree->batch map fused per phase
// ---------------------------------------------------------------------------
__global__ void csr_count2(const int* __restrict__ gei, const int* __restrict__ tei,
                           const int* __restrict__ bmap,
                           int* __restrict__ gcnt, int* __restrict__ tcnt,
                           int* __restrict__ bcnt)
{
    int e = blockIdx.x * blockDim.x + threadIdx.x;
    const int GE = EG + NG, TE = ET + NTREE;
    if (e < GE) {
        int dst = (e < EG) ? gei[EG + e] : e - EG;
        atomicAdd(&gcnt[dst], 1);
    } else if (e < GE + TE) {
        int e2 = e - GE;
        int dst = (e2 < ET) ? tei[ET + e2] : e2 - ET;
        atomicAdd(&tcnt[dst], 1);
    } else {
        int e3 = e - GE - TE;
        if (e3 >= NTREE) return;
        atomicAdd(&bcnt[bmap[e3]], 1);
    }
}

__global__ void csr_scan2(int* __restrict__ gcnt, int* __restrict__ goff, int* __restrict__ gcur,
                          int* __restrict__ tcnt, int* __restrict__ toff, int* __restrict__ tcur,
                          int* __restrict__ bcnt, int* __restrict__ boff, int* __restrict__ bcur)
{
    const int* cnt; int* off; int* cur; int N;
    if (blockIdx.x == 0)      { cnt = gcnt; off = goff; cur = gcur; N = NG; }
    else if (blockIdx.x == 1) { cnt = tcnt; off = toff; cur = tcur; N = NTREE; }
    else                      { cnt = bcnt; off = boff; cur = bcur; N = NB; }
    __shared__ int part[256];
    const int tid = threadIdx.x;
    const int per = (N + 255) / 256;
    const int i0 = tid * per;
    const int i1 = min(i0 + per, N);
    int s = 0;
    for (int i = i0; i < i1; ++i) s += cnt[i];
    part[tid] = s;
    __syncthreads();
    for (int o = 1; o < 256; o <<= 1) {
        int u = (tid >= o) ? part[tid - o] : 0;
        __syncthreads();
        part[tid] += u;
        __syncthreads();
    }
    int base = part[tid] - s;
    for (int i = i0; i < i1; ++i) {
        off[i] = base; cur[i] = base;
        base += cnt[i];
    }
    if (tid == 255) off[N] = part[255];
}

__global__ void csr_scatter2(const int* __restrict__ gei, const int* __restrict__ tei,
                             const int* __restrict__ bmap,
                             int* __restrict__ gcur, int* __restrict__ tcur,
                             int* __restrict__ bcur,
                             int* __restrict__ geidx, int* __restrict__ teidx,
                             int* __restrict__ bidx)
{
    int e = blockIdx.x * blockDim.x + threadIdx.x;
    const int GE = EG + NG, TE = ET + NTREE;
    if (e < GE) {
        int dst = (e < EG) ? gei[EG + e] : e - EG;
        int pos = atomicAdd(&gcur[dst], 1);
        geidx[pos] = e;
    } else if (e < GE + TE) {
        int e2 = e - GE;
        int dst = (e2 < ET) ? tei[ET + e2] : e2 - ET;
        int pos = atomicAdd(&tcur[dst], 1);
        teidx[pos] = e2;
    } else {
        int e3 = e - GE - TE;
        if (e3 >= NTREE) return;
        int pos = atomicAdd(&bcur[bmap[e3]], 1);
        bidx[pos] = e3;
    }
}

// ---------------------------------------------------------------------------
// Fused per-dst softmax + accumulate (es/ed come pre-computed from the GEMM).
// rootb (optional): for dst < NB also store bf16 output at rootb[dst*128+c]
// (replaces set_roots; graph GAT2 only).
// ---------------------------------------------------------------------------
template<int C, int VEC, int HEADS, int NCHUNK>
__global__ __launch_bounds__(256) void gat_fused(
    const int* __restrict__ off, const int* __restrict__ eidx,
    const int* __restrict__ ei, int E,
    const float* __restrict__ es, const float* __restrict__ ed,
    const u16* __restrict__ feat, const float* __restrict__ bias,
    float* __restrict__ outf, u16* __restrict__ outb,
    u16* __restrict__ rootb,
    int N, int HC)
{
    int gt = blockIdx.x * blockDim.x + threadIdx.x;
    int wid = gt >> 6, lane = gt & 63;
    int dst = wid / NCHUNK, chunk = wid - dst * NCHUNK;
    if (dst >= N) return;
    const int e0 = off[dst], e1 = off[dst + 1];

    const int hd  = lane & (HEADS - 1);
    const int esl = lane / HEADS;
    const int EPI = 64 / HEADS;
    float edv = ed[(size_t)dst * HEADS + hd];

    float mymax = -3.4e38f;
    for (int p = e0 + esl; p < e1; p += EPI) {
        int j = eidx[p];
        int src = (j < E) ? ei[j] : (j - E);
        float e = es[(size_t)src * HEADS + hd] + edv;
        e = e > 0.f ? e : 0.2f * e;
        mymax = fmaxf(mymax, e);
    }
#pragma unroll
    for (int o = HEADS; o < 64; o <<= 1)
        mymax = fmaxf(mymax, __shfl_xor(mymax, o));

    float ssum = 0.f;
    for (int p = e0 + esl; p < e1; p += EPI) {
        int j = eidx[p];
        int src = (j < E) ? ei[j] : (j - E);
        float e = es[(size_t)src * HEADS + hd] + edv;
        e = e > 0.f ? e : 0.2f * e;
        ssum += __expf(e - mymax);
    }
#pragma unroll
    for (int o = HEADS; o < 64; o <<= 1)
        ssum += __shfl_xor(ssum, o);
    float sinv = __fdividef(1.f, ssum);

    int c0 = chunk * 64 * VEC + lane * VEC;
    int split = (c0 / C + 1) * C - c0;          // first v belonging to hhi
    int hlo = c0 / C;              if (hlo > HEADS - 1) hlo = HEADS - 1;
    int hhi = (c0 + VEC - 1) / C;  if (hhi > HEADS - 1) hhi = HEADS - 1;
    float maxlo = __shfl(mymax, hlo), sinvlo = __shfl(sinv, hlo), edlo = __shfl(edv, hlo);
    float maxhi = __shfl(mymax, hhi), sinvhi = __shfl(sinv, hhi), edhi = __shfl(edv, hhi);

    if (c0 >= HC) return;
    float acc[VEC];
#pragma unroll
    for (int v = 0; v < VEC; ++v) acc[v] = 0.f;

    for (int p = e0; p < e1; ++p) {
        int j = eidx[p];
        int src = (j < E) ? ei[j] : (j - E);
        float elo = es[(size_t)src * HEADS + hlo] + edlo;
        elo = elo > 0.f ? elo : 0.2f * elo;
        float alo = __expf(elo - maxlo) * sinvlo;
        float ahi = alo;
        if (hhi != hlo) {
            float ehi = es[(size_t)src * HEADS + hhi] + edhi;
            ehi = ehi > 0.f ? ehi : 0.2f * ehi;
            ahi = __expf(ehi - maxhi) * sinvhi;
        }
        const u16* frp = feat + (size_t)src * HC + c0;
        float fv[VEC];
        if (VEC == 8) {
            uint4 pk = *(const uint4*)frp;
            fv[0] = bf2f((u16)(pk.x & 0xffff)); fv[1] = bf2f((u16)(pk.x >> 16));
            fv[2] = bf2f((u16)(pk.y & 0xffff)); fv[3] = bf2f((u16)(pk.y >> 16));
            fv[4] = bf2f((u16)(pk.z & 0xffff)); fv[5] = bf2f((u16)(pk.z >> 16));
            fv[6] = bf2f((u16)(pk.w & 0xffff)); fv[7] = bf2f((u16)(pk.w >> 16));
        } else {
            u32 pk = *(const u32*)frp;
            fv[0] = bf2f((u16)(pk & 0xffff)); fv[1] = bf2f((u16)(pk >> 16));
        }
#pragma unroll
        for (int v = 0; v < VEC; ++v) {
            float a = (v < split) ? alo : ahi;
            acc[v] += fv[v] * a;
        }
    }
#pragma unroll
    for (int v = 0; v < VEC; ++v) {
        int c = c0 + v;
        if (c >= HC) continue;
        float o = fmaxf(acc[v] + bias[c], 0.f);
        if (outf) outf[(size_t)dst * HC + c] = o;
        if (outb) outb[(size_t)dst * HC + c] = f2bf(o);
        if (rootb && dst < NB) rootb[(size_t)dst * 128 + c] = f2bf(o);
    }
}

// Batch-CSR scatter-mean: 1 block per batch, no atomics, no memsets.
__global__ void scatter_mean_csr(const int* __restrict__ boff, const int* __restrict__ bidx,
                                 const float* __restrict__ x, float* __restrict__ meanb)
{
    int b = blockIdx.x;                  // NB blocks, 256 threads
    int tid = threadIdx.x;
    int c = tid & 127, half = tid >> 7;
    __shared__ float partial[256];
    int i0 = boff[b], i1 = boff[b + 1];
    float acc = 0.f;
    if (c < HD) {
        for (int i = i0 + half; i < i1; i += 2)
            acc += x[(size_t)bidx[i] * HD + c];
    }
    partial[tid] = acc;
    __syncthreads();
    if (half == 0 && c < HD) {
        float tot = partial[tid] + partial[tid + 128];
        float cnt = (float)(i1 - i0);
        meanb[b * HD + c] = tot * __fdividef(1.f, fmaxf(cnt, 1.f));
    }
}

__global__ void fc_out2(const float* __restrict__ meanb, const float* __restrict__ W,
                        const float* __restrict__ b, float* __restrict__ out)
{
    int t = threadIdx.x;                 // 512 threads
    int bb = t >> 2, j = t & 3;
    float acc = b[j];
    for (int k = 0; k < HD; ++k) acc += meanb[bb * HD + k] * W[j * HD + k];
    out[t] = acc;
}

// ---------------------------------------------------------------------------
// Host launcher
// ---------------------------------------------------------------------------
extern "C" void kernel_launch(void* const* d_in, const int* in_sizes, int n_in,
                              void* d_out, int out_size, void* d_ws, size_t ws_size,
                              hipStream_t stream)
{
    const float* user_feats = (const float*)d_in[1];
    const int*   gnf        = (const int*)d_in[2];
    const int*   gei        = (const int*)d_in[3];
    const int*   tnf        = (const int*)d_in[4];
    const int*   tei        = (const int*)d_in[5];
    const int*   indices    = (const int*)d_in[6];
    const float* h0g        = (const float*)d_in[7];
    const float* h0t        = (const float*)d_in[8];
    const float* temb       = (const float*)d_in[9];
    const float* gW[2][4] = {{(const float*)d_in[10], (const float*)d_in[11], (const float*)d_in[12], (const float*)d_in[13]},
                             {(const float*)d_in[14], (const float*)d_in[15], (const float*)d_in[16], (const float*)d_in[17]}};
    const float* tW[2][4] = {{(const float*)d_in[18], (const float*)d_in[19], (const float*)d_in[20], (const float*)d_in[21]},
                             {(const float*)d_in[22], (const float*)d_in[23], (const float*)d_in[24], (const float*)d_in[25]}};
    const float* uW1 = (const float*)d_in[26]; const float* ub1 = (const float*)d_in[27];
    const float* uW2 = (const float*)d_in[28]; const float* ub2 = (const float*)d_in[29];
    const float* gc1W = (const float*)d_in[30]; const float* gc1as = (const float*)d_in[31];
    const float* gc1ad = (const float*)d_in[32]; const float* gc1b = (const float*)d_in[33];
    const float* gc2W = (const float*)d_in[34]; const float* gc2as = (const float*)d_in[35];
    const float* gc2ad = (const float*)d_in[36]; const float* gc2b = (const float*)d_in[37];
    const float* tc1W = (const float*)d_in[38]; const float* tc1as = (const float*)d_in[39];
    const float* tc1ad = (const float*)d_in[40]; const float* tc1b = (const float*)d_in[41];
    const float* tc2W = (const float*)d_in[42]; const float* tc2as = (const float*)d_in[43];
    const float* tc2ad = (const float*)d_in[44]; const float* tc2b = (const float*)d_in[45];
    const float* fcW = (const float*)d_in[46]; const float* fcb = (const float*)d_in[47];
    float* out = (float*)d_out;

    char* ws = (char*)d_ws;
    const size_t NEED = 226500000;
    if (ws_size < NEED) return;

    // ---- workspace layout (decimal byte offsets, overlays noted) ----
    u16*   TEMB_B = (u16*)(ws + 12000000);       // 12.8 MB [VOC][128]
    u16*   ETAB_G = (u16*)(ws + 25000000);       // 44.8 MB [VOC][448] interleaved
    u16*   ETAB_T = (u16*)(ws + 70000000);       // 44.8 MB -> 114.8
    u16*   TH1B   = (u16*)(ws + 117600000);      // 7.68 MB [NTREE][128]
    float* HID    = (float*)(ws + 133400000);    // 8 MB
    u16*   WARENA = (u16*)(ws + 141500000);      // GRU weight arena
    int*   GOFF   = (int*)(ws + 142700000);
    int*   GCUR   = (int*)(ws + 142900000);
    int*   GCNT   = (int*)(ws + 143100000);      // NG ints
    int*   TCNT   = (int*)(ws + 143220000);      // NTREE ints
    int*   BCNT   = (int*)(ws + 143340000);      // NB ints
    int*   GEIDX  = (int*)(ws + 143400000);      // 0.92 MB
    int*   TOFF   = (int*)(ws + 144400000);
    int*   TCUR   = (int*)(ws + 144600000);
    int*   TEIDX  = (int*)(ws + 144800000);      // 0.36 MB -> 145160000
    int*   BOFF   = (int*)(ws + 145160000);
    int*   BCUR   = (int*)(ws + 145170000);
    int*   BIDX   = (int*)(ws + 145180000);      // 0.12 MB -> 145300000
    // es/ed buffer pairs per GAT layer (all zeroed by the one big memset)
    float* ES1    = (float*)(ws + 145300000);    // NG*8
    float* ED1    = (float*)(ws + 146300000);    // NG*8
    float* ES2    = (float*)(ws + 147300000);    // NG*1
    float* ED2    = (float*)(ws + 147450000);
    float* ES3    = (float*)(ws + 147600000);    // NTREE*8
    float* ED3    = (float*)(ws + 148600000);
    float* ES4    = (float*)(ws + 149600000);    // NTREE*1
    float* ED4    = (float*)(ws + 149750000);    // -> 149870000
    float* MEANB  = (float*)(ws + 156700000);    // [NB][100] fp32
    u16*   XG_B   = (u16*)(ws + 157000000);      // 7.68 MB [NG][128]
    u16*   GFEAT1 = (u16*)(ws + 165000000);      // 30.72 MB [NG][512] -> 195.72
    // GAT weight arena (persistent; converted once up front)
    u16*   W_G1a  = (u16*)(ws + 196000000);      // [512][128]
    u16*   W_G2a  = (u16*)(ws + 196131072);      // [100][512]
    u16*   W_G1b  = (u16*)(ws + 196233472);      // [800][128]
    u16*   W_G2b  = (u16*)(ws + 196438272);      // [100][800] -> 196598272
    // overlays (regions dead by the time they're written):
    u16*   GOUT1B = (u16*)(ws + 25000000);       // 30.72 MB (over ETAB_G, dead after GRU)
    u16*   GFEAT2 = (u16*)(ws + 56000000);       // 6 MB [NG][100]
    u16*   TFEAT1 = (u16*)(ws + 25000000);       // 48 MB [NTREE][800] (after graph GATs)
    u16*   TOUT1B = (u16*)(ws + 74000000);       // 48 MB (over ETAB_T tail, dead)
    u16*   TFEAT2 = (u16*)(ws + 123000000);      // 6 MB (over TH1B-tail, dead)
    float* XOUT2  = (float*)(ws + 0);            // 12 MB (old XGF slot, free)

    // GRU weight arena slots (u16 element offsets)
    u16* gWHH0  = WARENA + 0;        // 6 x [336][128]
    u16* gWIH1  = WARENA + 43008;
    u16* gWHH1  = WARENA + 86016;
    u16* tWHH0  = WARENA + 129024;
    u16* tWIH1  = WARENA + 172032;
    u16* tWHH1  = WARENA + 215040;
    u16* W_IH0A = WARENA + 258048;   // [448][128] interleaved-row Etab weights
    u16* W_IH0B = WARENA + 315392;

    auto mfma = [&](const u16* A, int lda, const u16* W, int ldw,
                    float* Cf, u16* Cb, int ldc, int M, int N, int Kt,
                    const float* as = nullptr, const float* ad = nullptr,
                    float* es = nullptr, float* ed = nullptr,
                    int heads = 1, int Cc = 1) {
        dim3 grid((M + 63) / 64, (N + 63) / 64, 1);
        gemm_mfma<<<grid, 256, 0, stream>>>(A, W, Cf, Cb, M, N, Kt, lda, ldw, ldc,
                                            as, ad, es, ed, heads, Cc);
    };

    // ---- 1. ALL converts in one launch ----
    {
        CvtAll P;
        P.temb = temb; P.tembB = TEMB_B;
        P.gsrc[0] = gW[0][1]; P.gbias[0] = gW[0][3]; P.gdst[0] = gWHH0;
        P.gsrc[1] = gW[1][0]; P.gbias[1] = gW[1][2]; P.gdst[1] = gWIH1;
        P.gsrc[2] = gW[1][1]; P.gbias[2] = gW[1][3]; P.gdst[2] = gWHH1;
        P.gsrc[3] = tW[0][1]; P.gbias[3] = tW[0][3]; P.gdst[3] = tWHH0;
        P.gsrc[4] = tW[1][0]; P.gbias[4] = tW[1][2]; P.gdst[4] = tWIH1;
        P.gsrc[5] = tW[1][1]; P.gbias[5] = tW[1][3]; P.gdst[5] = tWHH1;
        P.is[0] = gW[0][0]; P.ib[0] = gW[0][2]; P.id_[0] = W_IH0A;
        P.is[1] = tW[0][0]; P.ib[1] = tW[0][2]; P.id_[1] = W_IH0B;
        P.wsrc[0] = gc1W; P.wdst[0] = W_G1a; P.wK[0] = 100; P.wLdk[0] = 128; P.wTot[0] = 512 * 128;
        P.wsrc[1] = gc2W; P.wdst[1] = W_G2a; P.wK[1] = 512; P.wLdk[1] = 512; P.wTot[1] = 100 * 512;
        P.wsrc[2] = tc1W; P.wdst[2] = W_G1b; P.wK[2] = 100; P.wLdk[2] = 128; P.wTot[2] = 800 * 128;
        P.wsrc[3] = tc2W; P.wdst[3] = W_G2b; P.wK[3] = 800; P.wLdk[3] = 800; P.wTot[3] = 100 * 800;
        int grid = CB_TEMB + 6 * CB_GRUW + 2 * CB_IH0 + CB_WTOT;   // 27625
        convert_all<<<grid, 256, 0, stream>>>(P);
    }

    // ---- 2. Etab build (both branches, one launch) ----
    {
        dim3 ge((VOC + 63) / 64, 7, 2);
        gemm_etab<<<ge, 256, 0, stream>>>(TEMB_B, W_IH0A, W_IH0B, ETAB_G, ETAB_T);
    }

    // ---- 3. one memset: CSR cnt buffers + all es/ed buffers ----
    hipMemsetAsync(GOFF, 0, 149870000 - 142700000, stream);
    {
        int tot = (EG + NG) + (ET + NTREE) + NTREE;
        csr_count2<<<(tot + 255) / 256, 256, 0, stream>>>(gei, tei, indices, GCNT, TCNT, BCNT);
        csr_scan2<<<3, 256, 0, stream>>>(GCNT, GOFF, GCUR, TCNT, TOFF, TCUR, BCNT, BOFF, BCUR);
        csr_scatter2<<<(tot + 255) / 256, 256, 0, stream>>>(gei, tei, indices,
                                                            GCUR, TCUR, BCUR, GEIDX, TEIDX, BIDX);
    }

    // ---- 4. user embed: mlp1 (+XG_B pad-zero) + mlp2 writing XG_B bf16 ----
    mlp1<<<(NU * HD + 255) / 256, 256, 0, stream>>>(user_feats, uW1, ub1, HID, XG_B);
    {
        dim3 g1((NU + 63) / 64, (HD + 63) / 64, 1);
        gemm_nt<<<g1, 256, 0, stream>>>(HID, uW2, ub2, nullptr, XG_B, NB, NU, HD, HD, 0);
    }

    // ---- 5. combined GRU: PERSISTENT; graph branch writes XG_B directly ----
    {
        GruProb Pg = { ETAB_G, gnf, h0g, gWHH0, gWIH1, gWHH1, XG_B, NTG, NU };
        GruProb Pt = { ETAB_T, tnf, h0t, tWHH0, tWIH1, tWHH1, TH1B, NTREE, 0 };
        const int gtiles = (NTG + 31) / 32;      // 313
        const int ttiles = (NTREE + 31) / 32;    // 938
        const int NBLK = 256;
        int GB = (NBLK * gtiles + (gtiles + ttiles) / 2) / (gtiles + ttiles);  // ~64
        if (GB < 1) GB = 1;
        if (GB > NBLK - 1) GB = NBLK - 1;
        gru_fused12<<<NBLK, 448, 0, stream>>>(Pg, Pt, GB);
    }

    // ---- 6. graph GAT chain ----
    {   // graph GAT1: 8 heads x 64 (es/ed fused into GEMM epilogue)
        mfma(XG_B, 128, W_G1a, 128, nullptr, GFEAT1, 512, NG, 512, 4,
             gc1as, gc1ad, ES1, ED1, 8, 64);
        gat_fused<64, 8, 8, 1><<<(NG + 3) / 4, 256, 0, stream>>>(
            GOFF, GEIDX, gei, EG, ES1, ED1, GFEAT1, gc1b, nullptr, GOUT1B, nullptr, NG, 512);
    }
    {   // graph GAT2: 1 head x 100; roots written straight into TH1B
        mfma(GOUT1B, 512, W_G2a, 512, nullptr, GFEAT2, 100, NG, 100, 16,
             gc2as, gc2ad, ES2, ED2, 1, 100);
        gat_fused<100, 2, 1, 1><<<(NG + 3) / 4, 256, 0, stream>>>(
            GOFF, GEIDX, gei, EG, ES2, ED2, GFEAT2, gc2b, nullptr, nullptr, TH1B, NG, 100);
    }

    // ---- 7. tree GAT chain ----
    {   // tree GAT1: 8 heads x 100
        mfma(TH1B, 128, W_G1b, 128, nullptr, TFEAT1, 800, NTREE, 800, 4,
             tc1as, tc1ad, ES3, ED3, 8, 100);
        gat_fused<100, 8, 8, 2><<<(NTREE * 2 + 3) / 4, 256, 0, stream>>>(
            TOFF, TEIDX, tei, ET, ES3, ED3, TFEAT1, tc1b, nullptr, TOUT1B, nullptr, NTREE, 800);
    }
    {   // tree GAT2: 1 head x 100
        mfma(TOUT1B, 800, W_G2b, 800, nullptr, TFEAT2, 100, NTREE, 100, 25,
             tc2as, tc2ad, ES4, ED4, 1, 100);
        gat_fused<100, 2, 1, 1><<<(NTREE + 3) / 4, 256, 0, stream>>>(
            TOFF, TEIDX, tei, ET, ES4, ED4, TFEAT2, tc2b, XOUT2, nullptr, nullptr, NTREE, 100);
    }

    // ---- 8. batch-CSR scatter-mean + classifier ----
    scatter_mean_csr<<<NB, 256, 0, stream>>>(BOFF, BIDX, XOUT2, MEANB);
    fc_out2<<<1, 512, 0, stream>>>(MEANB, fcW, fcb, out);
}